// Round 1
// baseline (9936.629 us; speedup 1.0000x reference)
//
#include <hip/hip_runtime.h>
#include <math.h>

#define N_   10000
#define E_   80000
#define O_   10
#define C_   64
#define B_   16
#define OUT_ 16

__device__ __forceinline__ float gelu_f(float x) {
    float x3 = x * x * x;
    return 0.5f * x * (1.0f + tanhf(0.7978845608028654f * (x + 0.044715f * x3)));
}

// ---------------------------------------------------------------------------
// Precompute: fibonacci sphere orientations, fkb = fiber basis MLP, fk[l] =
// fkb @ conv_fw[l].  One block.
// ---------------------------------------------------------------------------
__global__ __launch_bounds__(256) void k_small(
    const float* __restrict__ fw1, const float* __restrict__ fb1,
    const float* __restrict__ fw2, const float* __restrict__ fb2,
    const float* __restrict__ cfw,
    float* __restrict__ orig, float* __restrict__ fkg)
{
    __shared__ float sOri[32];
    __shared__ float sHid[6400];
    __shared__ float sFkb[6400];
    int tid = threadIdx.x;
    if (tid < O_) {
        float i = (float)tid + 0.5f;
        float phi = acosf(1.0f - 2.0f * i / (float)O_);
        float theta = 3.14159265358979323846f * (1.0f + 2.2360679774997896964f) * i;
        float sp = sinf(phi);
        float v0 = cosf(theta) * sp, v1 = sinf(theta) * sp, v2 = cosf(phi);
        sOri[tid * 3 + 0] = v0; sOri[tid * 3 + 1] = v1; sOri[tid * 3 + 2] = v2;
        orig[tid * 3 + 0] = v0; orig[tid * 3 + 1] = v1; orig[tid * 3 + 2] = v2;
    }
    __syncthreads();
    // hidden = gelu(poly(inv3) @ fw1 + fb1)   [100 pairs][64]
    for (int it = tid; it < 6400; it += 256) {
        int pr = it >> 6, c = it & 63;
        int i = pr / O_, j = pr % O_;
        float a = sOri[i*3+0]*sOri[j*3+0] + sOri[i*3+1]*sOri[j*3+1] + sOri[i*3+2]*sOri[j*3+2];
        float f1 = a, f2 = a*a, f3 = f2*a, f4 = f3*a;
        float v = fb1[c];
        v = fmaf(f1, fw1[0*64+c], v);
        v = fmaf(f2, fw1[1*64+c], v);
        v = fmaf(f3, fw1[2*64+c], v);
        v = fmaf(f4, fw1[3*64+c], v);
        sHid[it] = gelu_f(v);
    }
    __syncthreads();
    // fkb = gelu(hidden @ fw2 + fb2)
    for (int it = tid; it < 6400; it += 256) {
        int pr = it >> 6, c = it & 63;
        float v = fb2[c];
        for (int b = 0; b < 64; ++b) v = fmaf(sHid[pr*64+b], fw2[b*64+c], v);
        sFkb[it] = gelu_f(v);
    }
    __syncthreads();
    // fk[l][p][o][c] = sum_b fkb[p][o][b] * conv_fw[l][b][c]
    for (int l = 0; l < 2; ++l) {
        for (int it = tid; it < 6400; it += 256) {
            int pr = it >> 6, c = it & 63;
            float v = 0.0f;
            for (int b = 0; b < 64; ++b) v = fmaf(sFkb[pr*64+b], cfw[l*4096 + b*64 + c], v);
            fkg[l*6400 + it] = v;
        }
    }
}

// ---------------------------------------------------------------------------
// h[n][o][c] = (x @ embed_w)[n][c] broadcast over o
// ---------------------------------------------------------------------------
__global__ __launch_bounds__(256) void k_embed(
    const float* __restrict__ x, const float* __restrict__ ew, float* __restrict__ hg)
{
    int t = blockIdx.x * 256 + threadIdx.x;
    if (t >= N_ * 64) return;
    int n = t >> 6, c = t & 63;
    float v = 0.0f;
#pragma unroll
    for (int k = 0; k < 16; ++k) v = fmaf(x[n*16+k], ew[k*64+c], v);
    size_t base = (size_t)n * 640 + c;
#pragma unroll
    for (int o = 0; o < O_; ++o) hg[base + (size_t)o*64] = v;
}

// ---------------------------------------------------------------------------
// CSR build
// ---------------------------------------------------------------------------
__global__ __launch_bounds__(256) void k_hist(const int* __restrict__ ei, int* __restrict__ counts)
{
    int e = blockIdx.x * 256 + threadIdx.x;
    if (e < E_) atomicAdd(&counts[ei[E_ + e]], 1);
}

__global__ __launch_bounds__(1024) void k_scan(
    const int* __restrict__ counts, int* __restrict__ offs, int* __restrict__ cursor)
{
    __shared__ int part[1024];
    int t = threadIdx.x;
    const int CH = 10; // 1024*10 >= N_
    int base_i = t * CH;
    int s = 0;
#pragma unroll
    for (int i = 0; i < CH; ++i) { int idx = base_i + i; if (idx < N_) s += counts[idx]; }
    part[t] = s;
    __syncthreads();
    for (int off = 1; off < 1024; off <<= 1) {
        int v = (t >= off) ? part[t - off] : 0;
        __syncthreads();
        part[t] += v;
        __syncthreads();
    }
    int run = (t > 0) ? part[t - 1] : 0;
#pragma unroll
    for (int i = 0; i < CH; ++i) {
        int idx = base_i + i;
        if (idx < N_) { offs[idx] = run; cursor[idx] = run; run += counts[idx]; }
    }
    if (t == 1023) offs[N_] = run;
}

__global__ __launch_bounds__(256) void k_scatter(
    const int* __restrict__ ei, const float* __restrict__ pos,
    int* __restrict__ cursor, int* __restrict__ csend, float* __restrict__ crel)
{
    int e = blockIdx.x * 256 + threadIdx.x;
    if (e >= E_) return;
    int s = ei[e], r = ei[E_ + e];
    int slot = atomicAdd(&cursor[r], 1);
    csend[slot] = s;
    crel[slot*3+0] = pos[s*3+0] - pos[r*3+0];
    crel[slot*3+1] = pos[s*3+1] - pos[r*3+1];
    crel[slot*3+2] = pos[s*3+2] - pos[r*3+2];
}

// ---------------------------------------------------------------------------
// Message passing for one layer: on-the-fly kernel basis MLP + depthwise conv
// + gather(h[send]) + segment-sum into h1.  Block owns one recv node (CSR).
// Per (edge,o) item one wave computes the 64-wide pipeline; lane = channel.
// ---------------------------------------------------------------------------
__global__ __launch_bounds__(256) void k_msg(
    const float* __restrict__ hg, float* __restrict__ h1g,
    const int* __restrict__ offs, const int* __restrict__ csend,
    const float* __restrict__ crel, const float* __restrict__ orig,
    const float* __restrict__ bw1, const float* __restrict__ bb1,
    const float* __restrict__ bw2, const float* __restrict__ bb2,
    const float* __restrict__ ckw)
{
    __shared__ float sW1[30*64];
    __shared__ float sB1[64];
    __shared__ float sW2[64*64];
    __shared__ float sB2[64];
    __shared__ float sOri[32];
    __shared__ float sacc[640];
    int tid = threadIdx.x;
    for (int i = tid; i < 30*64; i += 256) sW1[i] = bw1[i];
    for (int i = tid; i < 64*64; i += 256) sW2[i] = bw2[i];
    if (tid < 64) { sB1[tid] = bb1[tid]; sB2[tid] = bb2[tid]; }
    if (tid < 30) sOri[tid] = orig[tid];
    __syncthreads();
    int lane = tid & 63, wv = tid >> 6;
    for (int n = blockIdx.x; n < N_; n += gridDim.x) {
        for (int i = tid; i < 640; i += 256) sacc[i] = 0.0f;
        __syncthreads();
        int beg = offs[n];
        int items = (offs[n+1] - beg) * O_;
        for (int t = wv; t < items; t += 4) {
            int e = t / O_;
            int o = t - e * O_;
            int slot = beg + e;
            int snd = csend[slot];
            float r0 = crel[slot*3+0], r1 = crel[slot*3+1], r2 = crel[slot*3+2];
            float o0 = sOri[o*3+0], o1 = sOri[o*3+1], o2 = sOri[o*3+2];
            float a = r0*o0 + r1*o1 + r2*o2;
            float p0 = r0 - a*o0, p1 = r1 - a*o1, p2 = r2 - a*o2;
            float b = sqrtf(p0*p0 + p1*p1 + p2*p2);
            // polynomial features (flattened outer products, degree 3)
            float f[30];
            f[0] = a; f[1] = b;
            f[2] = a*a; f[3] = a*b; f[4] = b*a; f[5] = b*b;
#pragma unroll
            for (int i = 0; i < 4; ++i) { f[6+2*i] = f[2+i]*a; f[7+2*i] = f[2+i]*b; }
#pragma unroll
            for (int i = 0; i < 8; ++i) { f[14+2*i] = f[6+i]*a; f[15+2*i] = f[6+i]*b; }
            // layer 1: 30 -> 64, gelu
            float hcur = sB1[lane];
#pragma unroll
            for (int p = 0; p < 30; ++p) hcur = fmaf(f[p], sW1[p*64+lane], hcur);
            hcur = gelu_f(hcur);
            // layer 2: 64 -> 64, gelu
            float k2 = sB2[lane];
#pragma unroll
            for (int bb = 0; bb < 64; ++bb) k2 = fmaf(__shfl(hcur, bb), sW2[bb*64+lane], k2);
            k2 = gelu_f(k2);
            // depthwise conv weight: kb @ conv_kw[l]
            float kc = 0.0f;
#pragma unroll
            for (int bb = 0; bb < 64; ++bb) kc = fmaf(__shfl(k2, bb), ckw[bb*64+lane], kc);
            // message = h[send][o][c] * kc, accumulate
            float m = hg[((size_t)snd*O_ + o)*64 + lane] * kc;
            atomicAdd(&sacc[o*64 + lane], m);
        }
        __syncthreads();
        for (int i = tid; i < 640; i += 256) h1g[(size_t)n*640 + i] = sacc[i];
        __syncthreads();
    }
}

// ---------------------------------------------------------------------------
// Per-node: fiber conv (einsum over o) + bias, LayerNorm, MLP 64->256->64,
// residual into h, readout accumulation.  Block owns one node; waves own rows.
// ---------------------------------------------------------------------------
__global__ __launch_bounds__(256) void k_node(
    const float* __restrict__ h1g, float* __restrict__ hg, float* __restrict__ racc,
    const float* __restrict__ fkg, const float* __restrict__ convb,
    const float* __restrict__ ns, const float* __restrict__ nb,
    const float* __restrict__ l1w, const float* __restrict__ l1b,
    const float* __restrict__ l2w, const float* __restrict__ l2b,
    const float* __restrict__ row, const float* __restrict__ rob)
{
    __shared__ float sFK[6400];
    __shared__ float sA[640];
    __shared__ float sH2[640];
    __shared__ float sHn[640];
    __shared__ float sRo[1024];
    __shared__ float sCb[64], sNs[64], sNb[64], sL1b[256], sL2b[64], sRb[16];
    __shared__ float sRacc[16];
    int tid = threadIdx.x;
    int lane = tid & 63, wv = tid >> 6;
    for (int i = tid; i < 6400; i += 256) sFK[i] = fkg[i];
    for (int i = tid; i < 1024; i += 256) sRo[i] = row[i];
    if (tid < 64) { sCb[tid] = convb[tid]; sNs[tid] = ns[tid]; sNb[tid] = nb[tid]; sL2b[tid] = l2b[tid]; }
    sL1b[tid] = l1b[tid];
    if (tid < 16) sRb[tid] = rob[tid];
    __syncthreads();
    for (int n = blockIdx.x; n < N_; n += gridDim.x) {
        for (int i = tid; i < 640; i += 256) sA[i] = h1g[(size_t)n*640 + i];
        if (tid < 16) sRacc[tid] = 0.0f;
        __syncthreads();
        // h2[p][c] = (sum_o h1[o][c] * fk[p][o][c]) / O + conv_b[c]
        for (int idx = tid; idx < 640; idx += 256) {
            int p = idx >> 6, c = idx & 63;
            float v = 0.0f;
#pragma unroll
            for (int o = 0; o < O_; ++o) v = fmaf(sA[o*64+c], sFK[(p*O_+o)*64+c], v);
            sH2[idx] = v * 0.1f + sCb[c];
        }
        __syncthreads();
        // per-row LN + MLP + residual
        for (int p = wv; p < O_; p += 4) {
            float xv = sH2[p*64 + lane];
            float s = xv;
#pragma unroll
            for (int d = 1; d < 64; d <<= 1) s += __shfl_xor(s, d);
            float mu = s * (1.0f/64.0f);
            float dv = xv - mu;
            float q = dv * dv;
#pragma unroll
            for (int d = 1; d < 64; d <<= 1) q += __shfl_xor(q, d);
            float var = q * (1.0f/64.0f);
            float y = dv * rsqrtf(var + 1e-6f) * sNs[lane] + sNb[lane];
            // hidden: cols lane + 64j
            float u0 = sL1b[lane], u1 = sL1b[lane+64], u2 = sL1b[lane+128], u3 = sL1b[lane+192];
            for (int c = 0; c < 64; ++c) {
                float yc = __shfl(y, c);
                const float* wr = &l1w[c*256];
                u0 = fmaf(yc, wr[lane      ], u0);
                u1 = fmaf(yc, wr[lane +  64], u1);
                u2 = fmaf(yc, wr[lane + 128], u2);
                u3 = fmaf(yc, wr[lane + 192], u3);
            }
            u0 = gelu_f(u0); u1 = gelu_f(u1); u2 = gelu_f(u2); u3 = gelu_f(u3);
            float ov = sL2b[lane];
            for (int s2 = 0; s2 < 64; ++s2) {
                float a0 = __shfl(u0, s2), a1 = __shfl(u1, s2), a2 = __shfl(u2, s2), a3 = __shfl(u3, s2);
                ov = fmaf(a0, l2w[(      s2)*64 + lane], ov);
                ov = fmaf(a1, l2w[( 64 + s2)*64 + lane], ov);
                ov = fmaf(a2, l2w[(128 + s2)*64 + lane], ov);
                ov = fmaf(a3, l2w[(192 + s2)*64 + lane], ov);
            }
            size_t hoff = ((size_t)n*O_ + p)*64 + lane;
            float hn = hg[hoff] + ov;
            hg[hoff] = hn;
            sHn[p*64 + lane] = hn;
        }
        __syncthreads();
        // readout: racc[n][j] += sum_p hn[p][:] @ ro_w[:,j]  (+ O*ro_b later)
        if (tid < 160) {
            int p = tid >> 4, jj = tid & 15;
            float s = 0.0f;
#pragma unroll
            for (int c = 0; c < 64; ++c) s = fmaf(sHn[p*64+c], sRo[c*16+jj], s);
            atomicAdd(&sRacc[jj], s);
        }
        __syncthreads();
        if (tid < 16) racc[(size_t)n*16 + tid] += sRacc[tid] + 10.0f * sRb[tid];
        __syncthreads();
    }
}

// ---------------------------------------------------------------------------
// Pool: out[batch[n]][j] += racc[n][j] / (L*O)
// ---------------------------------------------------------------------------
__global__ __launch_bounds__(256) void k_pool(
    const float* __restrict__ racc, const int* __restrict__ batch, float* __restrict__ out)
{
    int t = blockIdx.x * 256 + threadIdx.x;
    if (t >= N_ * 16) return;
    int n = t >> 4, j = t & 15;
    atomicAdd(&out[batch[n]*16 + j], racc[t] * (1.0f/20.0f));
}

// ---------------------------------------------------------------------------
extern "C" void kernel_launch(void* const* d_in, const int* in_sizes, int n_in,
                              void* d_out, int out_size, void* d_ws, size_t ws_size,
                              hipStream_t stream)
{
    const float* x    = (const float*)d_in[0];
    const float* pos  = (const float*)d_in[1];
    const float* bw1  = (const float*)d_in[2];
    const float* bb1  = (const float*)d_in[3];
    const float* bw2  = (const float*)d_in[4];
    const float* bb2  = (const float*)d_in[5];
    const float* fw1  = (const float*)d_in[6];
    const float* fb1  = (const float*)d_in[7];
    const float* fw2  = (const float*)d_in[8];
    const float* fb2  = (const float*)d_in[9];
    const float* embw = (const float*)d_in[10];
    const float* ckw  = (const float*)d_in[11];
    const float* cfw  = (const float*)d_in[12];
    const float* cb   = (const float*)d_in[13];
    const float* ns   = (const float*)d_in[14];
    const float* nb   = (const float*)d_in[15];
    const float* l1w  = (const float*)d_in[16];
    const float* l1b  = (const float*)d_in[17];
    const float* l2w  = (const float*)d_in[18];
    const float* l2b  = (const float*)d_in[19];
    const float* row  = (const float*)d_in[20];
    const float* rob  = (const float*)d_in[21];
    const int*   ei   = (const int*)d_in[22];
    const int*   batch= (const int*)d_in[23];
    float* out = (float*)d_out;

    char* w = (char*)d_ws;
    size_t off = 0;
    auto alloc = [&](size_t bytes) -> char* {
        char* p = w + off; off += (bytes + 255) / 256 * 256; return p;
    };
    float* ori   = (float*)alloc(32 * 4);
    float* fkg   = (float*)alloc(2 * 6400 * 4);
    float* h     = (float*)alloc((size_t)N_ * 640 * 4);
    float* h1    = (float*)alloc((size_t)N_ * 640 * 4);
    float* racc  = (float*)alloc((size_t)N_ * 16 * 4);
    float* crel  = (float*)alloc((size_t)E_ * 3 * 4);
    int*   counts= (int*)alloc((N_ + 1) * 4);
    int*   offs  = (int*)alloc((N_ + 1) * 4);
    int*   cursor= (int*)alloc((N_ + 1) * 4);
    int*   csend = (int*)alloc((size_t)E_ * 4);

    hipMemsetAsync(out, 0, (size_t)out_size * 4, stream);
    hipMemsetAsync(racc, 0, (size_t)N_ * 16 * 4, stream);
    hipMemsetAsync(counts, 0, (N_ + 1) * 4, stream);

    k_small<<<1, 256, 0, stream>>>(fw1, fb1, fw2, fb2, cfw, ori, fkg);
    k_embed<<<(N_ * 64 + 255) / 256, 256, 0, stream>>>(x, embw, h);
    k_hist<<<(E_ + 255) / 256, 256, 0, stream>>>(ei, counts);
    k_scan<<<1, 1024, 0, stream>>>(counts, offs, cursor);
    k_scatter<<<(E_ + 255) / 256, 256, 0, stream>>>(ei, pos, cursor, csend, crel);

    for (int l = 0; l < 2; ++l) {
        k_msg<<<2048, 256, 0, stream>>>(h, h1, offs, csend, crel, ori,
                                        bw1, bb1, bw2, bb2, ckw + l * 4096);
        k_node<<<2048, 256, 0, stream>>>(h1, h, racc,
                                         fkg + l * 6400, cb + l * 64, ns + l * 64, nb + l * 64,
                                         l1w + (size_t)l * 64 * 256, l1b + l * 256,
                                         l2w + (size_t)l * 256 * 64, l2b + l * 64,
                                         row + l * 64 * 16, rob + l * 16);
    }
    k_pool<<<(N_ * 16 + 255) / 256, 256, 0, stream>>>(racc, batch, out);
}

// Round 2
// 2005.651 us; speedup vs baseline: 4.9543x; 4.9543x over previous
//
#include <hip/hip_runtime.h>
#include <math.h>

#define N_   10000
#define E_   80000
#define O_   10
#define B_   16
#define OUT_ 16
#define NROW_ (N_*O_)   // 100000
#define NITEM_ (E_*O_)  // 800000
#define NPASS_ (NITEM_/64) // 12500

__device__ __forceinline__ float gelu_f(float x) {
    // 0.5x(1+tanh(0.79788456(x+0.044715x^3))), tanh via exp
    float g = 0.7978845608028654f * fmaf(0.044715f * x, x * x, x);
    float e = __expf(2.0f * g);
    float th = 1.0f - 2.0f / (e + 1.0f);
    return 0.5f * x * (1.0f + th);
}

// ---------------------------------------------------------------------------
// Precompute: orientations, folded basis_w1 (30 poly feats -> 14 monomials),
// fiber basis MLP fkb, fk[l] = fkb @ conv_fw[l].  One block.
// ---------------------------------------------------------------------------
__global__ __launch_bounds__(256) void k_small(
    const float* __restrict__ bw1,
    const float* __restrict__ fw1, const float* __restrict__ fb1,
    const float* __restrict__ fw2, const float* __restrict__ fb2,
    const float* __restrict__ cfw,
    float* __restrict__ orig, float* __restrict__ w1fg, float* __restrict__ fkg)
{
    __shared__ float sOri[32];
    __shared__ float sHid[6400];
    __shared__ float sFkb[6400];
    int tid = threadIdx.x;
    if (tid < O_) {
        float i = (float)tid + 0.5f;
        float phi = acosf(1.0f - 2.0f * i / (float)O_);
        float theta = 3.14159265358979323846f * (1.0f + 2.2360679774997896964f) * i;
        float sp = sinf(phi);
        float v0 = cosf(theta) * sp, v1 = sinf(theta) * sp, v2 = cosf(phi);
        sOri[tid * 3 + 0] = v0; sOri[tid * 3 + 1] = v1; sOri[tid * 3 + 2] = v2;
        orig[tid * 3 + 0] = v0; orig[tid * 3 + 1] = v1; orig[tid * 3 + 2] = v2;
    }
    // fold basis_w1: feature p -> monomial map (a^i b^j, deg 1..4, 14 monomials)
    {
        const int map[30] = {0,1, 2,3,3,4, 5,6,6,7,6,7,7,8,
                             9,10,10,11,10,11,11,12, 10,11,11,12, 11,12,12,13};
        for (int idx = tid; idx < 14 * 64; idx += 256) {
            int mono = idx >> 6, c = idx & 63;
            float s = 0.0f;
            for (int p = 0; p < 30; ++p) if (map[p] == mono) s += bw1[p * 64 + c];
            w1fg[idx] = s;
        }
    }
    __syncthreads();
    for (int it = tid; it < 6400; it += 256) {
        int pr = it >> 6, c = it & 63;
        int i = pr / O_, j = pr % O_;
        float a = sOri[i*3+0]*sOri[j*3+0] + sOri[i*3+1]*sOri[j*3+1] + sOri[i*3+2]*sOri[j*3+2];
        float f1 = a, f2 = a*a, f3 = f2*a, f4 = f3*a;
        float v = fb1[c];
        v = fmaf(f1, fw1[0*64+c], v);
        v = fmaf(f2, fw1[1*64+c], v);
        v = fmaf(f3, fw1[2*64+c], v);
        v = fmaf(f4, fw1[3*64+c], v);
        sHid[it] = gelu_f(v);
    }
    __syncthreads();
    for (int it = tid; it < 6400; it += 256) {
        int pr = it >> 6, c = it & 63;
        float v = fb2[c];
        for (int b = 0; b < 64; ++b) v = fmaf(sHid[pr*64+b], fw2[b*64+c], v);
        sFkb[it] = gelu_f(v);
    }
    __syncthreads();
    for (int l = 0; l < 2; ++l) {
        for (int it = tid; it < 6400; it += 256) {
            int pr = it >> 6, c = it & 63;
            float v = 0.0f;
            for (int b = 0; b < 64; ++b) v = fmaf(sFkb[pr*64+b], cfw[l*4096 + b*64 + c], v);
            fkg[l*6400 + it] = v;
        }
    }
}

// ---------------------------------------------------------------------------
// h[n][o][c] = (x @ embed_w)[n][c] broadcast over o
// ---------------------------------------------------------------------------
__global__ __launch_bounds__(256) void k_embed(
    const float* __restrict__ x, const float* __restrict__ ew, float* __restrict__ hg)
{
    int t = blockIdx.x * 256 + threadIdx.x;
    if (t >= N_ * 64) return;
    int n = t >> 6, c = t & 63;
    float v = 0.0f;
#pragma unroll
    for (int k = 0; k < 16; ++k) v = fmaf(x[n*16+k], ew[k*64+c], v);
    size_t base = (size_t)n * 640 + c;
#pragma unroll
    for (int o = 0; o < O_; ++o) hg[base + (size_t)o*64] = v;
}

// ---------------------------------------------------------------------------
// CSR build
// ---------------------------------------------------------------------------
__global__ __launch_bounds__(256) void k_hist(const int* __restrict__ ei, int* __restrict__ counts)
{
    int e = blockIdx.x * 256 + threadIdx.x;
    if (e < E_) atomicAdd(&counts[ei[E_ + e]], 1);
}

__global__ __launch_bounds__(1024) void k_scan(
    const int* __restrict__ counts, int* __restrict__ offs, int* __restrict__ cursor)
{
    __shared__ int part[1024];
    int t = threadIdx.x;
    const int CH = 10;
    int base_i = t * CH;
    int s = 0;
#pragma unroll
    for (int i = 0; i < CH; ++i) { int idx = base_i + i; if (idx < N_) s += counts[idx]; }
    part[t] = s;
    __syncthreads();
    for (int off = 1; off < 1024; off <<= 1) {
        int v = (t >= off) ? part[t - off] : 0;
        __syncthreads();
        part[t] += v;
        __syncthreads();
    }
    int run = (t > 0) ? part[t - 1] : 0;
#pragma unroll
    for (int i = 0; i < CH; ++i) {
        int idx = base_i + i;
        if (idx < N_) { offs[idx] = run; cursor[idx] = run; run += counts[idx]; }
    }
    if (t == 1023) offs[N_] = run;
}

__global__ __launch_bounds__(256) void k_scatter(
    const int* __restrict__ ei, const float* __restrict__ pos,
    int* __restrict__ cursor, int* __restrict__ csend, int* __restrict__ crecv,
    float* __restrict__ crel)
{
    int e = blockIdx.x * 256 + threadIdx.x;
    if (e >= E_) return;
    int s = ei[e], r = ei[E_ + e];
    int slot = atomicAdd(&cursor[r], 1);
    csend[slot] = s;
    crecv[slot] = r;
    crel[slot*3+0] = pos[s*3+0] - pos[r*3+0];
    crel[slot*3+1] = pos[s*3+1] - pos[r*3+1];
    crel[slot*3+2] = pos[s*3+2] - pos[r*3+2];
}

// ---------------------------------------------------------------------------
// Message passing, item-per-lane.  Item t = slot*10 + o (slot CSR recv-sorted).
// One 64-thread block = one wave = 64 items.  Per-item vector lives in LDS
// row [lane][65]; stage loops: acc[64] in regs += LDS-elem * s_load weight row.
// Then transpose-read kc column-wise, gather h[send], accumulate per-(recv,o)
// runs in 10 named registers, flush coalesced global atomics on recv change.
// ---------------------------------------------------------------------------
__global__ __launch_bounds__(64) void k_msg(
    const float* __restrict__ hg, float* __restrict__ h1g,
    const int* __restrict__ csend, const int* __restrict__ crecv,
    const float* __restrict__ crel, const float* __restrict__ orig,
    const float* __restrict__ w1f, const float* __restrict__ bb1,
    const float* __restrict__ bw2, const float* __restrict__ bb2,
    const float* __restrict__ ckw)
{
    __shared__ float sV[64 * 65];
    const int lane = threadIdx.x;
    const int t = blockIdx.x * 64 + lane;
    const int slot = t / O_;
    const int o = t - slot * O_;
    const int snd = csend[slot];
    const int rcv = crecv[slot];
    const float r0 = crel[slot*3+0], r1 = crel[slot*3+1], r2 = crel[slot*3+2];
    const float o0 = orig[o*3+0], o1 = orig[o*3+1], o2 = orig[o*3+2];
    float a = r0*o0 + r1*o1 + r2*o2;
    float p0 = fmaf(-a, o0, r0), p1 = fmaf(-a, o1, r1), p2 = fmaf(-a, o2, r2);
    float b = sqrtf(p0*p0 + p1*p1 + p2*p2);
    // 14 monomials a^i b^j, deg 1..4
    {
        float a2 = a*a, b2 = b*b, ab = a*b;
        float* m = &sV[lane * 65];
        m[0]=a; m[1]=b; m[2]=a2; m[3]=ab; m[4]=b2;
        m[5]=a2*a; m[6]=a2*b; m[7]=a*b2; m[8]=b2*b;
        m[9]=a2*a2; m[10]=a2*ab; m[11]=a2*b2; m[12]=ab*b2; m[13]=b2*b2;
    }
    float acc[64];
    // stage 1: 14 -> 64 (folded w1)
#pragma unroll
    for (int c = 0; c < 64; ++c) acc[c] = bb1[c];
    {
        float fp = sV[lane*65 + 0];
#pragma unroll 4
        for (int p = 0; p < 14; ++p) {
            float fpn = sV[lane*65 + p + 1];
            const float* wr = w1f + p*64;
#pragma unroll
            for (int c = 0; c < 64; ++c) acc[c] = fmaf(fp, wr[c], acc[c]);
            fp = fpn;
        }
    }
#pragma unroll
    for (int c = 0; c < 64; ++c) sV[lane*65 + c] = gelu_f(acc[c]);
    // stage 2: 64 -> 64 (bw2), gelu
#pragma unroll
    for (int c = 0; c < 64; ++c) acc[c] = bb2[c];
    {
        float fp = sV[lane*65 + 0];
#pragma unroll 4
        for (int p = 0; p < 64; ++p) {
            float fpn = sV[lane*65 + p + 1];
            const float* wr = bw2 + p*64;
#pragma unroll
            for (int c = 0; c < 64; ++c) acc[c] = fmaf(fp, wr[c], acc[c]);
            fp = fpn;
        }
    }
#pragma unroll
    for (int c = 0; c < 64; ++c) sV[lane*65 + c] = gelu_f(acc[c]);
    // stage 3: kc = k2 @ conv_kw[l]
#pragma unroll
    for (int c = 0; c < 64; ++c) acc[c] = 0.0f;
    {
        float fp = sV[lane*65 + 0];
#pragma unroll 4
        for (int p = 0; p < 64; ++p) {
            float fpn = sV[lane*65 + p + 1];
            const float* wr = ckw + p*64;
#pragma unroll
            for (int c = 0; c < 64; ++c) acc[c] = fmaf(fp, wr[c], acc[c]);
            fp = fpn;
        }
    }
#pragma unroll
    for (int c = 0; c < 64; ++c) sV[lane*65 + c] = acc[c];

    // scatter phase: lane = channel; iterate 64 items serially
    float a0=0,a1c=0,a2c=0,a3c=0,a4c=0,a5c=0,a6c=0,a7c=0,a8c=0,a9c=0;
    int cur = __builtin_amdgcn_readlane(rcv, 0);
#define FLUSH_RUN(R) { float* bp = h1g + (size_t)(R)*640 + lane; \
    atomicAdd(bp+0,a0); atomicAdd(bp+64,a1c); atomicAdd(bp+128,a2c); atomicAdd(bp+192,a3c); \
    atomicAdd(bp+256,a4c); atomicAdd(bp+320,a5c); atomicAdd(bp+384,a6c); atomicAdd(bp+448,a7c); \
    atomicAdd(bp+512,a8c); atomicAdd(bp+576,a9c); \
    a0=a1c=a2c=a3c=a4c=a5c=a6c=a7c=a8c=a9c=0.0f; }
    for (int i = 0; i < 64; ++i) {
        int rc = __builtin_amdgcn_readlane(rcv, i);
        if (rc != cur) { FLUSH_RUN(cur); cur = rc; }
        int sn = __builtin_amdgcn_readlane(snd, i);
        int oi = __builtin_amdgcn_readlane(o, i);
        float kc = sV[i*65 + lane];
        float hv = hg[((size_t)sn*O_ + oi)*64 + lane];
        float m = kc * hv;
        if      (oi == 0) a0  += m;
        else if (oi == 1) a1c += m;
        else if (oi == 2) a2c += m;
        else if (oi == 3) a3c += m;
        else if (oi == 4) a4c += m;
        else if (oi == 5) a5c += m;
        else if (oi == 6) a6c += m;
        else if (oi == 7) a7c += m;
        else if (oi == 8) a8c += m;
        else              a9c += m;
    }
    FLUSH_RUN(cur);
#undef FLUSH_RUN
}

// ---------------------------------------------------------------------------
// Fiber conv: h2[n,p,c] = (sum_o h1[n,o,c]*fk[p,o,c])/O + conv_b[c]
// ---------------------------------------------------------------------------
__global__ __launch_bounds__(256) void k_fiber(
    const float* __restrict__ h1, const float* __restrict__ fkg,
    const float* __restrict__ cb, float* __restrict__ h2)
{
    int t = blockIdx.x * 256 + threadIdx.x;
    if (t >= N_ * 640) return;
    int c = t & 63;
    int p = (t >> 6) % O_;
    int n = t / 640;
    const float* h1n = h1 + (size_t)n * 640;
    float v = 0.0f;
#pragma unroll
    for (int o = 0; o < O_; ++o) v = fmaf(h1n[o*64 + c], fkg[(p*O_ + o)*64 + c], v);
    h2[t] = v * 0.1f + cb[c];
}

// ---------------------------------------------------------------------------
// Per-row LN + MLP(64->256->64) + residual + readout.  Item-per-lane: lane
// owns row (n,p); row vector in LDS [lane][130] (y in 0..63, gelu-u in 64..127).
// ---------------------------------------------------------------------------
__global__ __launch_bounds__(64) void k_mlp(
    const float* __restrict__ h2, float* __restrict__ hg, float* __restrict__ racc,
    const float* __restrict__ ns, const float* __restrict__ nb,
    const float* __restrict__ l1w, const float* __restrict__ l1b,
    const float* __restrict__ l2w, const float* __restrict__ l2b,
    const float* __restrict__ row_w, const float* __restrict__ rob)
{
    __shared__ float sY[64 * 130];
    const int lane = threadIdx.x;
    const int rb = blockIdx.x * 64;
    // coalesced tile load -> transposed LDS
#pragma unroll 8
    for (int i = 0; i < 64; ++i) {
        int r = rb + i; if (r >= NROW_) r = NROW_ - 1;
        sY[i*130 + lane] = h2[(size_t)r*64 + lane];
    }
    // LN stats (per-lane over own row)
    float sum = 0.0f, sq = 0.0f;
#pragma unroll 8
    for (int k = 0; k < 64; ++k) {
        float v = sY[lane*130 + k];
        sum += v; sq = fmaf(v, v, sq);
    }
    float mu = sum * (1.0f/64.0f);
    float var = sq * (1.0f/64.0f) - mu*mu;
    float rs = rsqrtf(var + 1e-6f);
#pragma unroll 8
    for (int k = 0; k < 64; ++k) {
        float v = sY[lane*130 + k];
        sY[lane*130 + k] = (v - mu) * rs * ns[k] + nb[k];
    }
    // MLP
    float out[64];
#pragma unroll
    for (int d = 0; d < 64; ++d) out[d] = l2b[d];
    for (int jb = 0; jb < 4; ++jb) {
        float u[64];
#pragma unroll
        for (int j = 0; j < 64; ++j) u[j] = l1b[jb*64 + j];
        {
            float yc = sY[lane*130 + 0];
#pragma unroll 4
            for (int c = 0; c < 64; ++c) {
                float ycn = sY[lane*130 + c + 1];
                const float* wr = l1w + c*256 + jb*64;
#pragma unroll
                for (int j = 0; j < 64; ++j) u[j] = fmaf(yc, wr[j], u[j]);
                yc = ycn;
            }
        }
#pragma unroll
        for (int j = 0; j < 64; ++j) sY[lane*130 + 64 + j] = gelu_f(u[j]);
        {
            float gj = sY[lane*130 + 64];
#pragma unroll 4
            for (int j = 0; j < 64; ++j) {
                float gjn = sY[lane*130 + 64 + j + 1];
                const float* wr = l2w + (jb*64 + j)*64;
#pragma unroll
                for (int d = 0; d < 64; ++d) out[d] = fmaf(gj, wr[d], out[d]);
                gj = gjn;
            }
        }
    }
    // residual + stash hn
    const int row = rb + lane;
    const bool valid = row < NROW_;
    const size_t hoff = (size_t)(valid ? row : 0) * 64;
#pragma unroll
    for (int c = 0; c < 64; ++c) {
        float hv = hg[hoff + c];
        float hn = hv + out[c];
        if (valid) hg[hoff + c] = hn;
        sY[lane*130 + c] = hn;
    }
    // readout r[16] = hn @ ro_w + ro_b
    float r[16];
#pragma unroll
    for (int j = 0; j < 16; ++j) r[j] = rob[j];
    {
        float hc = sY[lane*130 + 0];
#pragma unroll 4
        for (int c = 0; c < 64; ++c) {
            float hcn = sY[lane*130 + c + 1];
            const float* wr = row_w + c*16;
#pragma unroll
            for (int j = 0; j < 16; ++j) r[j] = fmaf(hc, wr[j], r[j]);
            hc = hcn;
        }
    }
    if (valid) {
        int n = row / O_;
#pragma unroll
        for (int j = 0; j < 16; ++j) atomicAdd(&racc[n*16 + j], r[j]);
    }
}

// ---------------------------------------------------------------------------
__global__ __launch_bounds__(256) void k_pool(
    const float* __restrict__ racc, const int* __restrict__ batch, float* __restrict__ out)
{
    int t = blockIdx.x * 256 + threadIdx.x;
    if (t >= N_ * 16) return;
    int n = t >> 4, j = t & 15;
    atomicAdd(&out[batch[n]*16 + j], racc[t] * (1.0f/20.0f));
}

// ---------------------------------------------------------------------------
extern "C" void kernel_launch(void* const* d_in, const int* in_sizes, int n_in,
                              void* d_out, int out_size, void* d_ws, size_t ws_size,
                              hipStream_t stream)
{
    const float* x    = (const float*)d_in[0];
    const float* pos  = (const float*)d_in[1];
    const float* bw1  = (const float*)d_in[2];
    const float* bb1  = (const float*)d_in[3];
    const float* bw2  = (const float*)d_in[4];
    const float* bb2  = (const float*)d_in[5];
    const float* fw1  = (const float*)d_in[6];
    const float* fb1  = (const float*)d_in[7];
    const float* fw2  = (const float*)d_in[8];
    const float* fb2  = (const float*)d_in[9];
    const float* embw = (const float*)d_in[10];
    const float* ckw  = (const float*)d_in[11];
    const float* cfw  = (const float*)d_in[12];
    const float* cb   = (const float*)d_in[13];
    const float* ns   = (const float*)d_in[14];
    const float* nb   = (const float*)d_in[15];
    const float* l1w  = (const float*)d_in[16];
    const float* l1b  = (const float*)d_in[17];
    const float* l2w  = (const float*)d_in[18];
    const float* l2b  = (const float*)d_in[19];
    const float* row  = (const float*)d_in[20];
    const float* rob  = (const float*)d_in[21];
    const int*   ei   = (const int*)d_in[22];
    const int*   batch= (const int*)d_in[23];
    float* out = (float*)d_out;

    char* w = (char*)d_ws;
    size_t off = 0;
    auto alloc = [&](size_t bytes) -> char* {
        char* p = w + off; off += (bytes + 255) / 256 * 256; return p;
    };
    float* ori   = (float*)alloc(32 * 4);
    float* w1f   = (float*)alloc(14 * 64 * 4);
    float* fkg   = (float*)alloc(2 * 6400 * 4);
    float* h     = (float*)alloc((size_t)N_ * 640 * 4);
    float* h1    = (float*)alloc((size_t)N_ * 640 * 4);
    float* h2    = (float*)alloc((size_t)N_ * 640 * 4);
    float* racc  = (float*)alloc((size_t)N_ * 16 * 4);
    float* crel  = (float*)alloc((size_t)E_ * 3 * 4);
    int*   counts= (int*)alloc((N_ + 1) * 4);
    int*   offs  = (int*)alloc((N_ + 1) * 4);
    int*   cursor= (int*)alloc((N_ + 1) * 4);
    int*   csend = (int*)alloc((size_t)E_ * 4);
    int*   crecv = (int*)alloc((size_t)E_ * 4);

    hipMemsetAsync(out, 0, (size_t)out_size * 4, stream);
    hipMemsetAsync(racc, 0, (size_t)N_ * 16 * 4, stream);
    hipMemsetAsync(counts, 0, (N_ + 1) * 4, stream);

    k_small<<<1, 256, 0, stream>>>(bw1, fw1, fb1, fw2, fb2, cfw, ori, w1f, fkg);
    k_embed<<<(N_ * 64 + 255) / 256, 256, 0, stream>>>(x, embw, h);
    k_hist<<<(E_ + 255) / 256, 256, 0, stream>>>(ei, counts);
    k_scan<<<1, 1024, 0, stream>>>(counts, offs, cursor);
    k_scatter<<<(E_ + 255) / 256, 256, 0, stream>>>(ei, pos, cursor, csend, crecv, crel);

    for (int l = 0; l < 2; ++l) {
        hipMemsetAsync(h1, 0, (size_t)N_ * 640 * 4, stream);
        k_msg<<<NPASS_, 64, 0, stream>>>(h, h1, csend, crecv, crel, ori,
                                         w1f, bb1, bw2, bb2, ckw + l * 4096);
        k_fiber<<<(N_ * 640 + 255) / 256, 256, 0, stream>>>(h1, fkg + l * 6400, cb + l * 64, h2);
        k_mlp<<<(NROW_ + 63) / 64, 64, 0, stream>>>(h2, h, racc,
                                                    ns + l * 64, nb + l * 64,
                                                    l1w + (size_t)l * 64 * 256, l1b + l * 256,
                                                    l2w + (size_t)l * 256 * 64, l2b + l * 64,
                                                    row + l * 64 * 16, rob + l * 16);
    }
    k_pool<<<(N_ * 16 + 255) / 256, 256, 0, stream>>>(racc, batch, out);
}

// Round 3
// 900.949 us; speedup vs baseline: 11.0291x; 2.2262x over previous
//
#include <hip/hip_runtime.h>
#include <math.h>

#define N_   10000
#define E_   80000
#define O_   10
#define B_   16
#define OUT_ 16
#define NROW_ (N_*O_)    // 100000
#define NITEM_ (E_*O_)   // 800000

typedef __attribute__((ext_vector_type(8))) short bf16x8;
typedef __attribute__((ext_vector_type(4))) short bf16x4;
typedef __attribute__((ext_vector_type(4))) float f32x4;

#define MFMA16(a,b,c) __builtin_amdgcn_mfma_f32_16x16x32_bf16(a,b,c,0,0,0)

__device__ __forceinline__ float gelu_f(float x) {
    float g = 0.7978845608028654f * fmaf(0.044715f * x, x * x, x);
    float e = __expf(2.0f * g);
    float th = 1.0f - 2.0f / (e + 1.0f);
    return 0.5f * x * (1.0f + th);
}

__device__ __forceinline__ unsigned short f2bf(float f) {
    union { float f; unsigned int u; } v; v.f = f;
    unsigned int r = v.u + 0x7FFFu + ((v.u >> 16) & 1u);
    return (unsigned short)(r >> 16);
}
__device__ __forceinline__ float bf2f(unsigned short u) {
    union { unsigned int u; float f; } v; v.u = ((unsigned int)u) << 16;
    return v.f;
}

// ---------------------------------------------------------------------------
// Precompute (1 block): orientations, folded basis_w1, fiber MLP -> fk (fp32),
// and ALL bf16 transposed weight matrices for the MFMA kernels.
// ---------------------------------------------------------------------------
__global__ __launch_bounds__(256) void k_small(
    const float* __restrict__ bw1,
    const float* __restrict__ fw1, const float* __restrict__ fb1,
    const float* __restrict__ fw2, const float* __restrict__ fb2,
    const float* __restrict__ cfw,
    const float* __restrict__ bw2, const float* __restrict__ ckw,
    const float* __restrict__ l1w, const float* __restrict__ l2w,
    const float* __restrict__ row_w,
    float* __restrict__ orig, float* __restrict__ fkg,
    unsigned short* __restrict__ wW1T, unsigned short* __restrict__ wW2T,
    unsigned short* __restrict__ wCKT, unsigned short* __restrict__ wL1T,
    unsigned short* __restrict__ wL2T, unsigned short* __restrict__ wROT)
{
    __shared__ float sOri[32];
    __shared__ float sHid[6400];
    __shared__ float sFkb[6400];
    __shared__ float sW1f[14*64];
    int tid = threadIdx.x;
    if (tid < O_) {
        float i = (float)tid + 0.5f;
        float phi = acosf(1.0f - 2.0f * i / (float)O_);
        float theta = 3.14159265358979323846f * (1.0f + 2.2360679774997896964f) * i;
        float sp = sinf(phi);
        float v0 = cosf(theta) * sp, v1 = sinf(theta) * sp, v2 = cosf(phi);
        sOri[tid*3+0] = v0; sOri[tid*3+1] = v1; sOri[tid*3+2] = v2;
        orig[tid*3+0] = v0; orig[tid*3+1] = v1; orig[tid*3+2] = v2;
    }
    {
        const int map[30] = {0,1, 2,3,3,4, 5,6,6,7,6,7,7,8,
                             9,10,10,11,10,11,11,12, 10,11,11,12, 11,12,12,13};
        for (int idx = tid; idx < 14*64; idx += 256) {
            int mono = idx >> 6, c = idx & 63;
            float s = 0.0f;
            for (int p = 0; p < 30; ++p) if (map[p] == mono) s += bw1[p*64 + c];
            sW1f[idx] = s;
        }
    }
    __syncthreads();
    // bf16 transposed weights
    for (int idx = tid; idx < 64*32; idx += 256) {      // wW1T[c][p]
        int c = idx >> 5, p = idx & 31;
        wW1T[idx] = f2bf(p < 14 ? sW1f[p*64 + c] : 0.0f);
    }
    for (int idx = tid; idx < 64*64; idx += 256) {      // wW2T[bd][c] = bw2[c][bd]
        int bd = idx >> 6, c = idx & 63;
        wW2T[idx] = f2bf(bw2[c*64 + bd]);
    }
    for (int idx = tid; idx < 2*64*64; idx += 256) {    // wCKT[l][c'][bd] = ckw[l][bd][c']
        int l = idx >> 12, rem = idx & 4095;
        int cp = rem >> 6, bd = rem & 63;
        wCKT[idx] = f2bf(ckw[l*4096 + bd*64 + cp]);
    }
    for (int idx = tid; idx < 2*256*64; idx += 256) {   // wL1T[l][hid][c] = l1w[l][c][hid]
        int l = idx >> 14, rem = idx & 16383;
        int hid = rem >> 6, c = rem & 63;
        wL1T[idx] = f2bf(l1w[l*16384 + c*256 + hid]);
    }
    for (int idx = tid; idx < 2*64*256; idx += 256) {   // wL2T[l][c][hid] = l2w[l][hid][c]
        int l = idx >> 14, rem = idx & 16383;
        int c = rem >> 8, hid = rem & 255;
        wL2T[idx] = f2bf(l2w[l*16384 + hid*64 + c]);
    }
    for (int idx = tid; idx < 2*16*64; idx += 256) {    // wROT[l][j][c] = ro[l][c][j]
        int l = idx >> 10, rem = idx & 1023;
        int j = rem >> 6, c = rem & 63;
        wROT[idx] = f2bf(row_w[l*1024 + c*16 + j]);
    }
    // fiber basis MLP -> fkg (fp32)
    for (int it = tid; it < 6400; it += 256) {
        int pr = it >> 6, c = it & 63;
        int i = pr / O_, j = pr % O_;
        float a = sOri[i*3+0]*sOri[j*3+0] + sOri[i*3+1]*sOri[j*3+1] + sOri[i*3+2]*sOri[j*3+2];
        float f1 = a, f2 = a*a, f3 = f2*a, f4 = f3*a;
        float v = fb1[c];
        v = fmaf(f1, fw1[0*64+c], v);
        v = fmaf(f2, fw1[1*64+c], v);
        v = fmaf(f3, fw1[2*64+c], v);
        v = fmaf(f4, fw1[3*64+c], v);
        sHid[it] = gelu_f(v);
    }
    __syncthreads();
    for (int it = tid; it < 6400; it += 256) {
        int pr = it >> 6, c = it & 63;
        float v = fb2[c];
        for (int b = 0; b < 64; ++b) v = fmaf(sHid[pr*64+b], fw2[b*64+c], v);
        sFkb[it] = gelu_f(v);
    }
    __syncthreads();
    for (int l = 0; l < 2; ++l)
        for (int it = tid; it < 6400; it += 256) {
            int pr = it >> 6, c = it & 63;
            float v = 0.0f;
            for (int b = 0; b < 64; ++b) v = fmaf(sFkb[pr*64+b], cfw[l*4096 + b*64 + c], v);
            fkg[l*6400 + it] = v;
        }
}

// ---------------------------------------------------------------------------
__global__ __launch_bounds__(256) void k_embed(
    const float* __restrict__ x, const float* __restrict__ ew, float* __restrict__ hg)
{
    int t = blockIdx.x * 256 + threadIdx.x;
    if (t >= N_ * 64) return;
    int n = t >> 6, c = t & 63;
    float v = 0.0f;
#pragma unroll
    for (int k = 0; k < 16; ++k) v = fmaf(x[n*16+k], ew[k*64+c], v);
    int base = n * 640 + c;
#pragma unroll
    for (int o = 0; o < O_; ++o) hg[base + o*64] = v;
}

// ---------------------------------------------------------------------------
__global__ __launch_bounds__(256) void k_hist(const int* __restrict__ ei, int* __restrict__ counts)
{
    int e = blockIdx.x * 256 + threadIdx.x;
    if (e < E_) atomicAdd(&counts[ei[E_ + e]], 1);
}

__global__ __launch_bounds__(1024) void k_scan(
    const int* __restrict__ counts, int* __restrict__ offs, int* __restrict__ cursor)
{
    __shared__ int part[1024];
    int t = threadIdx.x;
    const int CH = 10;
    int base_i = t * CH;
    int s = 0;
#pragma unroll
    for (int i = 0; i < CH; ++i) { int idx = base_i + i; if (idx < N_) s += counts[idx]; }
    part[t] = s;
    __syncthreads();
    for (int off = 1; off < 1024; off <<= 1) {
        int v = (t >= off) ? part[t - off] : 0;
        __syncthreads();
        part[t] += v;
        __syncthreads();
    }
    int run = (t > 0) ? part[t - 1] : 0;
#pragma unroll
    for (int i = 0; i < CH; ++i) {
        int idx = base_i + i;
        if (idx < N_) { offs[idx] = run; cursor[idx] = run; run += counts[idx]; }
    }
    if (t == 1023) offs[N_] = run;
}

__global__ __launch_bounds__(256) void k_scatter(
    const int* __restrict__ ei, const float* __restrict__ pos,
    int* __restrict__ cursor, int* __restrict__ csend, int* __restrict__ crecv,
    float* __restrict__ crel)
{
    int e = blockIdx.x * 256 + threadIdx.x;
    if (e >= E_) return;
    int s = ei[e], r = ei[E_ + e];
    int slot = atomicAdd(&cursor[r], 1);
    csend[slot] = s;
    crecv[slot] = r;
    crel[slot*3+0] = pos[s*3+0] - pos[r*3+0];
    crel[slot*3+1] = pos[s*3+1] - pos[r*3+1];
    crel[slot*3+2] = pos[s*3+2] - pos[r*3+2];
}

// ---------------------------------------------------------------------------
// MFMA stage: data' = act(W^T-frags MFMA data-frags + bias).  Data row-major
// [256][64] bf16 XOR-swizzled; each wave touches only its own 64 rows.
// ---------------------------------------------------------------------------
template<int KS, int WSTRIDE, bool BIAS, bool GELU>
__device__ __forceinline__ void mfma_stage(
    unsigned short* sData, const unsigned short* sW, const float* bias,
    int rbase, int lane)
{
    const int lm = lane & 15, lk = lane >> 4;
    bf16x8 Bf[4][KS];
#pragma unroll
    for (int nt = 0; nt < 4; ++nt)
#pragma unroll
        for (int ks = 0; ks < KS; ++ks) {
            int r = rbase + nt*16 + lm;
            int kb = ks*64 + lk*16;
            Bf[nt][ks] = *(const bf16x8*)((const char*)sData + r*128 + (kb ^ ((r&7)<<4)));
        }
#pragma unroll
    for (int mt = 0; mt < 4; ++mt) {
        bf16x8 Af[KS];
#pragma unroll
        for (int ks = 0; ks < KS; ++ks) {
            int r = mt*16 + lm;
            int kb = ks*64 + lk*16;
            int sw = ((r&7)<<4) & (WSTRIDE-1);
            Af[ks] = *(const bf16x8*)((const char*)sW + r*WSTRIDE + (kb ^ sw));
        }
        f32x4 b4 = {0,0,0,0};
        if (BIAS) b4 = *(const f32x4*)(bias + mt*16 + (lk<<2));
#pragma unroll
        for (int nt = 0; nt < 4; ++nt) {
            f32x4 acc = {0,0,0,0};
#pragma unroll
            for (int ks = 0; ks < KS; ++ks) acc = MFMA16(Af[ks], Bf[nt][ks], acc);
            bf16x4 pk;
#pragma unroll
            for (int r = 0; r < 4; ++r) {
                float v = acc[r] + b4[r];
                if (GELU) v = gelu_f(v);
                pk[r] = (short)f2bf(v);
            }
            int rr = rbase + nt*16 + lm;
            int cb = mt*32 + (lk<<3);
            *(bf16x4*)((char*)sData + rr*128 + (cb ^ ((rr&7)<<4))) = pk;
        }
    }
}

// ---------------------------------------------------------------------------
// Message passing: 256 items/block (item = slot*10+o, recv-sorted).  Phase 0
// computes monomial features -> bf16 LDS.  Three MFMA stages produce kc.
// Scatter: lane=channel, run-flush atomics per (recv,o).
// ---------------------------------------------------------------------------
__global__ __launch_bounds__(256) void k_msg(
    const float* __restrict__ hg, float* __restrict__ h1g,
    const int* __restrict__ csend, const int* __restrict__ crecv,
    const float* __restrict__ crel, const float* __restrict__ ori,
    const unsigned short* __restrict__ wW1T, const unsigned short* __restrict__ wW2T,
    const unsigned short* __restrict__ wCKT_l,
    const float* __restrict__ bb1, const float* __restrict__ bb2)
{
    __shared__ unsigned short sData[256*64];
    __shared__ unsigned short sW1[64*32];
    __shared__ unsigned short sW2[64*64];
    __shared__ unsigned short sCK[64*64];
    const int tid = threadIdx.x;
    const int lane = tid & 63, wv = tid >> 6;
    // stage weights (swizzled)
    for (int i = tid*16; i < 4096; i += 256*16) {
        int r = i >> 6, off = i & 63;
        *(f32x4*)((char*)sW1 + r*64 + (off ^ (((r&7)<<4) & 63))) = *(const f32x4*)((const char*)wW1T + i);
    }
    for (int i = tid*16; i < 8192; i += 256*16) {
        int r = i >> 7, off = i & 127;
        *(f32x4*)((char*)sW2 + r*128 + (off ^ ((r&7)<<4))) = *(const f32x4*)((const char*)wW2T + i);
    }
    for (int i = tid*16; i < 8192; i += 256*16) {
        int r = i >> 7, off = i & 127;
        *(f32x4*)((char*)sCK + r*128 + (off ^ ((r&7)<<4))) = *(const f32x4*)((const char*)wCKT_l + i);
    }
    // phase 0: per-item monomial features
    const int item = blockIdx.x * 256 + tid;
    const int slot = item / 10;
    const int oo = item - slot * 10;
    const int snd = csend[slot];
    const int rcv = crecv[slot];
    {
        float r0 = crel[slot*3+0], r1 = crel[slot*3+1], r2 = crel[slot*3+2];
        float o0 = ori[oo*3+0], o1 = ori[oo*3+1], o2 = ori[oo*3+2];
        float a = r0*o0 + r1*o1 + r2*o2;
        float p0 = fmaf(-a, o0, r0), p1 = fmaf(-a, o1, r1), p2 = fmaf(-a, o2, r2);
        float b = sqrtf(p0*p0 + p1*p1 + p2*p2);
        float a2 = a*a, b2 = b*b, ab = a*b;
        float m[14];
        m[0]=a; m[1]=b; m[2]=a2; m[3]=ab; m[4]=b2;
        m[5]=a2*a; m[6]=a2*b; m[7]=a*b2; m[8]=b2*b;
        m[9]=a2*a2; m[10]=a2*ab; m[11]=a2*b2; m[12]=ab*b2; m[13]=b2*b2;
        unsigned int pk[16];
#pragma unroll
        for (int j = 0; j < 7; ++j)
            pk[j] = (unsigned int)f2bf(m[2*j]) | ((unsigned int)f2bf(m[2*j+1]) << 16);
#pragma unroll
        for (int j = 7; j < 16; ++j) pk[j] = 0;
        int r = tid;
#pragma unroll
        for (int q = 0; q < 4; ++q) {
            int cb = q*16;
            *(f32x4*)((char*)sData + r*128 + (cb ^ ((r&7)<<4))) = ((const f32x4*)pk)[q];
        }
    }
    __syncthreads();
    const int rbase = wv * 64;
    mfma_stage<1, 64,  true,  true >(sData, sW1, bb1, rbase, lane);
    mfma_stage<2, 128, true,  true >(sData, sW2, bb2, rbase, lane);
    mfma_stage<2, 128, false, false>(sData, sCK, (const float*)0, rbase, lane);

    // scatter: run-flush per recv
    float a0=0,a1c=0,a2c=0,a3c=0,a4c=0,a5c=0,a6c=0,a7c=0,a8c=0,a9c=0;
    int cur = __builtin_amdgcn_readlane(rcv, 0);
#define FLUSH_RUN(R) { float* bp = h1g + (R)*640 + lane; \
    atomicAdd(bp+0,a0); atomicAdd(bp+64,a1c); atomicAdd(bp+128,a2c); atomicAdd(bp+192,a3c); \
    atomicAdd(bp+256,a4c); atomicAdd(bp+320,a5c); atomicAdd(bp+384,a6c); atomicAdd(bp+448,a7c); \
    atomicAdd(bp+512,a8c); atomicAdd(bp+576,a9c); \
    a0=a1c=a2c=a3c=a4c=a5c=a6c=a7c=a8c=a9c=0.0f; }
    for (int i = 0; i < 64; ++i) {
        int rc = __builtin_amdgcn_readlane(rcv, i);
        if (rc != cur) { FLUSH_RUN(cur); cur = rc; }
        int sn = __builtin_amdgcn_readlane(snd, i);
        int oi = __builtin_amdgcn_readlane(oo, i);
        int rr = rbase + i;
        unsigned short u = *(const unsigned short*)((const char*)sData + rr*128 + ((lane*2) ^ ((rr&7)<<4)));
        float kc = bf2f(u);
        float hv = hg[(sn*10 + oi)*64 + lane];
        float mv = kc * hv;
        if      (oi == 0) a0  += mv;
        else if (oi == 1) a1c += mv;
        else if (oi == 2) a2c += mv;
        else if (oi == 3) a3c += mv;
        else if (oi == 4) a4c += mv;
        else if (oi == 5) a5c += mv;
        else if (oi == 6) a6c += mv;
        else if (oi == 7) a7c += mv;
        else if (oi == 8) a8c += mv;
        else              a9c += mv;
    }
    FLUSH_RUN(cur);
#undef FLUSH_RUN
}

// ---------------------------------------------------------------------------
// Fused fiber conv + LayerNorm -> y bf16.  Wave per node, loops p; lane=c.
// ---------------------------------------------------------------------------
__global__ __launch_bounds__(256) void k_fln(
    const float* __restrict__ h1, const float* __restrict__ fkg,
    const float* __restrict__ cb, const float* __restrict__ ns,
    const float* __restrict__ nb, unsigned short* __restrict__ y)
{
    __shared__ float sFK[6400];
    const int tid = threadIdx.x;
    for (int i = tid; i < 6400; i += 256) sFK[i] = fkg[i];
    __syncthreads();
    const int lane = tid & 63, wv = tid >> 6;
    const int n = blockIdx.x * 4 + wv;
    float hr[10];
#pragma unroll
    for (int o = 0; o < O_; ++o) hr[o] = h1[n*640 + o*64 + lane];
    float cbv = cb[lane], nsv = ns[lane], nbv = nb[lane];
#pragma unroll
    for (int p = 0; p < O_; ++p) {
        float v = 0.0f;
#pragma unroll
        for (int o = 0; o < O_; ++o) v = fmaf(hr[o], sFK[(p*O_+o)*64 + lane], v);
        v = v * 0.1f + cbv;
        float s = v, q = v*v;
#pragma unroll
        for (int d = 1; d < 64; d <<= 1) { s += __shfl_xor(s, d); q += __shfl_xor(q, d); }
        float mu = s * (1.0f/64.0f);
        float var = q * (1.0f/64.0f) - mu*mu;
        float rs = rsqrtf(var + 1e-6f);
        float yv = (v - mu) * rs * nsv + nbv;
        y[(n*O_ + p)*64 + lane] = f2bf(yv);
    }
}

// ---------------------------------------------------------------------------
// MLP: 128 rows/block; y bf16 -> LDS; 4 hidden chunks of 64 (MFMA), gelu,
// second MFMA accumulates; + residual into h (fp32); readout MFMA -> racc.
// ---------------------------------------------------------------------------
__global__ __launch_bounds__(256) void k_mlp(
    const unsigned short* __restrict__ y, float* __restrict__ hg, float* __restrict__ racc,
    const unsigned short* __restrict__ wL1T_l, const float* __restrict__ l1b_l,
    const unsigned short* __restrict__ wL2T_l, const float* __restrict__ l2b_l,
    const unsigned short* __restrict__ wROT_l, const float* __restrict__ rob_l)
{
    __shared__ unsigned short sA[128*64];
    __shared__ unsigned short sMid[128*64];
    const int tid = threadIdx.x;
    const int lane = tid & 63, wv = tid >> 6;
    const int rb = blockIdx.x * 128;
    // stage y tile (clamped)
    for (int i = tid*16; i < 128*128; i += 256*16) {
        int r = i >> 7, off = i & 127;
        int grow = rb + r; if (grow >= NROW_) grow = NROW_ - 1;
        *(f32x4*)((char*)sA + r*128 + (off ^ ((r&7)<<4))) =
            *(const f32x4*)((const char*)y + (size_t)grow*128 + off);
    }
    __syncthreads();
    const int lm = lane & 15, lk = lane >> 4;
    // prehold y B-frags (wave's 32 rows)
    bf16x8 Yf[2][2];
#pragma unroll
    for (int nt = 0; nt < 2; ++nt)
#pragma unroll
        for (int ks = 0; ks < 2; ++ks) {
            int r = wv*32 + nt*16 + lm;
            int kb = ks*64 + lk*16;
            Yf[nt][ks] = *(const bf16x8*)((const char*)sA + r*128 + (kb ^ ((r&7)<<4)));
        }
    f32x4 acc2[4][2];
#pragma unroll
    for (int m = 0; m < 4; ++m)
#pragma unroll
        for (int n = 0; n < 2; ++n) acc2[m][n] = (f32x4){0,0,0,0};
#pragma unroll
    for (int jb = 0; jb < 4; ++jb) {
        // GEMM1: hidden chunk = gelu(W1^T y + b1)
#pragma unroll
        for (int mt = 0; mt < 4; ++mt) {
            bf16x8 A1[2];
#pragma unroll
            for (int ks = 0; ks < 2; ++ks)
                A1[ks] = *(const bf16x8*)(wL1T_l + ((jb*64 + mt*16 + lm)*64 + ks*32 + lk*8));
            f32x4 b4 = *(const f32x4*)(l1b_l + jb*64 + mt*16 + (lk<<2));
#pragma unroll
            for (int nt = 0; nt < 2; ++nt) {
                f32x4 acc = {0,0,0,0};
                acc = MFMA16(A1[0], Yf[nt][0], acc);
                acc = MFMA16(A1[1], Yf[nt][1], acc);
                bf16x4 pk;
#pragma unroll
                for (int r = 0; r < 4; ++r) pk[r] = (short)f2bf(gelu_f(acc[r] + b4[r]));
                int rr = wv*32 + nt*16 + lm;
                int cb = mt*32 + (lk<<3);
                *(bf16x4*)((char*)sMid + rr*128 + (cb ^ ((rr&7)<<4))) = pk;
            }
        }
        // GEMM2: accumulate W2^T(chunk) mid
        bf16x8 Mf[2][2];
#pragma unroll
        for (int nt = 0; nt < 2; ++nt)
#pragma unroll
            for (int ks = 0; ks < 2; ++ks) {
                int r = wv*32 + nt*16 + lm;
                int kb = ks*64 + lk*16;
                Mf[nt][ks] = *(const bf16x8*)((const char*)sMid + r*128 + (kb ^ ((r&7)<<4)));
            }
#pragma unroll
        for (int mt2 = 0; mt2 < 4; ++mt2) {
            bf16x8 A2[2];
#pragma unroll
            for (int ks = 0; ks < 2; ++ks)
                A2[ks] = *(const bf16x8*)(wL2T_l + ((mt2*16 + lm)*256 + jb*64 + ks*32 + lk*8));
#pragma unroll
            for (int nt = 0; nt < 2; ++nt) {
                acc2[mt2][nt] = MFMA16(A2[0], Mf[nt][0], acc2[mt2][nt]);
                acc2[mt2][nt] = MFMA16(A2[1], Mf[nt][1], acc2[mt2][nt]);
            }
        }
    }
    // epilogue: bias + residual into h, stash hn bf16 into sA
#pragma unroll
    for (int mt2 = 0; mt2 < 4; ++mt2) {
        f32x4 b2 = *(const f32x4*)(l2b_l + mt2*16 + (lk<<2));
#pragma unroll
        for (int nt = 0; nt < 2; ++nt) {
            int rloc = wv*32 + nt*16 + lm;
            int grow = rb + rloc;
            bool valid = grow < NROW_;
            int growc = valid ? grow : (NROW_ - 1);
            f32x4 hv = *(const f32x4*)(hg + (size_t)growc*64 + mt2*16 + (lk<<2));
            f32x4 hn;
            bf16x4 pk;
#pragma unroll
            for (int r = 0; r < 4; ++r) {
                hn[r] = hv[r] + acc2[mt2][nt][r] + b2[r];
                pk[r] = (short)f2bf(hn[r]);
            }
            if (valid) *(f32x4*)(hg + (size_t)grow*64 + mt2*16 + (lk<<2)) = hn;
            int cb = mt2*32 + (lk<<3);
            *(bf16x4*)((char*)sA + rloc*128 + (cb ^ ((rloc&7)<<4))) = pk;
        }
    }
    // readout: ro^T hn -> racc atomics
    bf16x8 Ro[2];
#pragma unroll
    for (int ks = 0; ks < 2; ++ks)
        Ro[ks] = *(const bf16x8*)(wROT_l + (lm*64 + ks*32 + lk*8));
    f32x4 rb4 = *(const f32x4*)(rob_l + (lk<<2));
#pragma unroll
    for (int nt = 0; nt < 2; ++nt) {
        int rloc = wv*32 + nt*16 + lm;
        bf16x8 Hf[2];
#pragma unroll
        for (int ks = 0; ks < 2; ++ks) {
            int kb = ks*64 + lk*16;
            Hf[ks] = *(const bf16x8*)((const char*)sA + rloc*128 + (kb ^ ((rloc&7)<<4)));
        }
        f32x4 r4 = {0,0,0,0};
        r4 = MFMA16(Ro[0], Hf[0], r4);
        r4 = MFMA16(Ro[1], Hf[1], r4);
        int grow = rb + rloc;
        if (grow < NROW_) {
            int n = grow / 10;
#pragma unroll
            for (int r = 0; r < 4; ++r)
                atomicAdd(&racc[n*16 + lk*4 + r], r4[r] + rb4[r]);
        }
    }
}

// ---------------------------------------------------------------------------
__global__ __launch_bounds__(256) void k_pool(
    const float* __restrict__ racc, const int* __restrict__ batch, float* __restrict__ out)
{
    int t = blockIdx.x * 256 + threadIdx.x;
    if (t >= N_ * 16) return;
    int n = t >> 4, j = t & 15;
    atomicAdd(&out[batch[n]*16 + j], racc[t] * (1.0f/20.0f));
}

// ---------------------------------------------------------------------------
extern "C" void kernel_launch(void* const* d_in, const int* in_sizes, int n_in,
                              void* d_out, int out_size, void* d_ws, size_t ws_size,
                              hipStream_t stream)
{
    const float* x    = (const float*)d_in[0];
    const float* pos  = (const float*)d_in[1];
    const float* bw1  = (const float*)d_in[2];
    const float* bb1  = (const float*)d_in[3];
    const float* bw2  = (const float*)d_in[4];
    const float* bb2  = (const float*)d_in[5];
    const float* fw1  = (const float*)d_in[6];
    const float* fb1  = (const float*)d_in[7];
    const float* fw2  = (const float*)d_in[8];
    const float* fb2  = (const float*)d_in[9];
    const float* embw = (const float*)d_in[10];
    const float* ckw  = (const float*)d_in[11];
    const float* cfw  = (const float*)d_in[12];
    const float* cb   = (const float*)d_in[13];
    const float* ns   = (const float*)d_in[14];
    const float* nbp  = (const float*)d_in[15];
    const float* l1w  = (const float*)d_in[16];
    const float* l1b  = (const float*)d_in[17];
    const float* l2w  = (const float*)d_in[18];
    const float* l2b  = (const float*)d_in[19];
    const float* row  = (const float*)d_in[20];
    const float* rob  = (const float*)d_in[21];
    const int*   ei   = (const int*)d_in[22];
    const int*   batch= (const int*)d_in[23];
    float* out = (float*)d_out;

    char* w = (char*)d_ws;
    size_t off = 0;
    auto alloc = [&](size_t bytes) -> char* {
        char* p = w + off; off += (bytes + 255) / 256 * 256; return p;
    };
    float* ori    = (float*)alloc(32 * 4);
    float* fkg    = (float*)alloc(2 * 6400 * 4);
    unsigned short* wW1T = (unsigned short*)alloc(64*32*2);
    unsigned short* wW2T = (unsigned short*)alloc(64*64*2);
    unsigned short* wCKT = (unsigned short*)alloc(2*64*64*2);
    unsigned short* wL1T = (unsigned short*)alloc(2*256*64*2);
    unsigned short* wL2T = (unsigned short*)alloc(2*64*256*2);
    unsigned short* wROT = (unsigned short*)alloc(2*16*64*2);
    float* h      = (float*)alloc((size_t)N_ * 640 * 4);
    float* h1     = (float*)alloc((size_t)N_ * 640 * 4);
    unsigned short* y = (unsigned short*)alloc((size_t)NROW_ * 64 * 2);
    float* racc   = (float*)alloc((size_t)N_ * 16 * 4);
    float* crel   = (float*)alloc((size_t)E_ * 3 * 4);
    int*   counts = (int*)alloc((N_ + 1) * 4);
    int*   offs   = (int*)alloc((N_ + 1) * 4);
    int*   cursor = (int*)alloc((N_ + 1) * 4);
    int*   csend  = (int*)alloc((size_t)E_ * 4);
    int*   crecv  = (int*)alloc((size_t)E_ * 4);

    hipMemsetAsync(out, 0, (size_t)out_size * 4, stream);
    hipMemsetAsync(racc, 0, (size_t)N_ * 16 * 4, stream);
    hipMemsetAsync(counts, 0, (N_ + 1) * 4, stream);

    k_small<<<1, 256, 0, stream>>>(bw1, fw1, fb1, fw2, fb2, cfw, bw2, ckw, l1w, l2w, row,
                                   ori, fkg, wW1T, wW2T, wCKT, wL1T, wL2T, wROT);
    k_embed<<<(N_ * 64 + 255) / 256, 256, 0, stream>>>(x, embw, h);
    k_hist<<<(E_ + 255) / 256, 256, 0, stream>>>(ei, counts);
    k_scan<<<1, 1024, 0, stream>>>(counts, offs, cursor);
    k_scatter<<<(E_ + 255) / 256, 256, 0, stream>>>(ei, pos, cursor, csend, crecv, crel);

    for (int l = 0; l < 2; ++l) {
        hipMemsetAsync(h1, 0, (size_t)N_ * 640 * 4, stream);
        k_msg<<<NITEM_ / 256, 256, 0, stream>>>(h, h1, csend, crecv, crel, ori,
                                                wW1T, wW2T, wCKT + l*4096,
                                                bb1, bb2);
        k_fln<<<N_ / 4, 256, 0, stream>>>(h1, fkg + l*6400, cb + l*64, ns + l*64, nbp + l*64, y);
        k_mlp<<<(NROW_ + 127) / 128, 256, 0, stream>>>(y, h, racc,
                                                       wL1T + l*16384, l1b + l*256,
                                                       wL2T + l*16384, l2b + l*64,
                                                       wROT + l*1024, rob + l*16);
    }
    k_pool<<<(N_ * 16 + 255) / 256, 256, 0, stream>>>(racc, batch, out);
}

// Round 4
// 736.060 us; speedup vs baseline: 13.4997x; 1.2240x over previous
//
#include <hip/hip_runtime.h>
#include <math.h>

#define N_   10000
#define E_   80000
#define O_   10
#define B_   16
#define OUT_ 16
#define NROW_ (N_*O_)    // 100000
#define NITEM_ (E_*O_)   // 800000

typedef __attribute__((ext_vector_type(8))) short bf16x8;
typedef __attribute__((ext_vector_type(4))) short bf16x4;
typedef __attribute__((ext_vector_type(4))) float f32x4;

#define MFMA16(a,b,c) __builtin_amdgcn_mfma_f32_16x16x32_bf16(a,b,c,0,0,0)

__device__ __forceinline__ float gelu_f(float x) {
    // x * (1 - 1/(exp(2*0.79788456*(x+0.044715x^3)) + 1))  == tanh-gelu
    float t = x * x;
    float u = fmaf(0.044715f, t, 1.0f);
    float e = __expf(1.5957691216057308f * x * u);
    float r = __fdividef(1.0f, e + 1.0f);
    return fmaf(-x, r, x);
}

__device__ __forceinline__ unsigned short f2bf(float f) {
    union { float f; unsigned int u; } v; v.f = f;
    unsigned int r = v.u + 0x7FFFu + ((v.u >> 16) & 1u);
    return (unsigned short)(r >> 16);
}
__device__ __forceinline__ float bf2f(unsigned short u) {
    union { unsigned int u; float f; } v; v.u = ((unsigned int)u) << 16;
    return v.f;
}

// ---------------------------------------------------------------------------
// Precompute (1 block): orientations, folded basis_w1, fiber MLP -> fk (fp32),
// and ALL bf16 transposed weight matrices for the MFMA kernels.
// ---------------------------------------------------------------------------
__global__ __launch_bounds__(256) void k_small(
    const float* __restrict__ bw1,
    const float* __restrict__ fw1, const float* __restrict__ fb1,
    const float* __restrict__ fw2, const float* __restrict__ fb2,
    const float* __restrict__ cfw,
    const float* __restrict__ bw2, const float* __restrict__ ckw,
    const float* __restrict__ l1w, const float* __restrict__ l2w,
    const float* __restrict__ row_w,
    float* __restrict__ orig, float* __restrict__ fkg,
    unsigned short* __restrict__ wW1T, unsigned short* __restrict__ wW2T,
    unsigned short* __restrict__ wCKT, unsigned short* __restrict__ wL1T,
    unsigned short* __restrict__ wL2T, unsigned short* __restrict__ wROT)
{
    __shared__ float sOri[32];
    __shared__ float sHid[6400];
    __shared__ float sFkb[6400];
    __shared__ float sW1f[14*64];
    int tid = threadIdx.x;
    if (tid < O_) {
        float i = (float)tid + 0.5f;
        float phi = acosf(1.0f - 2.0f * i / (float)O_);
        float theta = 3.14159265358979323846f * (1.0f + 2.2360679774997896964f) * i;
        float sp = sinf(phi);
        float v0 = cosf(theta) * sp, v1 = sinf(theta) * sp, v2 = cosf(phi);
        sOri[tid*3+0] = v0; sOri[tid*3+1] = v1; sOri[tid*3+2] = v2;
        orig[tid*3+0] = v0; orig[tid*3+1] = v1; orig[tid*3+2] = v2;
    }
    {
        const int map[30] = {0,1, 2,3,3,4, 5,6,6,7,6,7,7,8,
                             9,10,10,11,10,11,11,12, 10,11,11,12, 11,12,12,13};
        for (int idx = tid; idx < 14*64; idx += 256) {
            int mono = idx >> 6, c = idx & 63;
            float s = 0.0f;
            for (int p = 0; p < 30; ++p) if (map[p] == mono) s += bw1[p*64 + c];
            sW1f[idx] = s;
        }
    }
    __syncthreads();
    // bf16 transposed weights
    for (int idx = tid; idx < 64*32; idx += 256) {      // wW1T[c][p]
        int c = idx >> 5, p = idx & 31;
        wW1T[idx] = f2bf(p < 14 ? sW1f[p*64 + c] : 0.0f);
    }
    for (int idx = tid; idx < 64*64; idx += 256) {      // wW2T[bd][c] = bw2[c][bd]
        int bd = idx >> 6, c = idx & 63;
        wW2T[idx] = f2bf(bw2[c*64 + bd]);
    }
    for (int idx = tid; idx < 2*64*64; idx += 256) {    // wCKT[l][c'][bd] = ckw[l][bd][c']
        int l = idx >> 12, rem = idx & 4095;
        int cp = rem >> 6, bd = rem & 63;
        wCKT[idx] = f2bf(ckw[l*4096 + bd*64 + cp]);
    }
    for (int idx = tid; idx < 2*256*64; idx += 256) {   // wL1T[l][hid][c] = l1w[l][c][hid]
        int l = idx >> 14, rem = idx & 16383;
        int hid = rem >> 6, c = rem & 63;
        wL1T[idx] = f2bf(l1w[l*16384 + c*256 + hid]);
    }
    for (int idx = tid; idx < 2*64*256; idx += 256) {   // wL2T[l][c][hid] = l2w[l][hid][c]
        int l = idx >> 14, rem = idx & 16383;
        int c = rem >> 8, hid = rem & 255;
        wL2T[idx] = f2bf(l2w[l*16384 + hid*64 + c]);
    }
    for (int idx = tid; idx < 2*16*64; idx += 256) {    // wROT[l][j][c] = ro[l][c][j]
        int l = idx >> 10, rem = idx & 1023;
        int j = rem >> 6, c = rem & 63;
        wROT[idx] = f2bf(row_w[l*1024 + c*16 + j]);
    }
    // fiber basis MLP -> fkg (fp32)
    for (int it = tid; it < 6400; it += 256) {
        int pr = it >> 6, c = it & 63;
        int i = pr / O_, j = pr % O_;
        float a = sOri[i*3+0]*sOri[j*3+0] + sOri[i*3+1]*sOri[j*3+1] + sOri[i*3+2]*sOri[j*3+2];
        float f1 = a, f2 = a*a, f3 = f2*a, f4 = f3*a;
        float v = fb1[c];
        v = fmaf(f1, fw1[0*64+c], v);
        v = fmaf(f2, fw1[1*64+c], v);
        v = fmaf(f3, fw1[2*64+c], v);
        v = fmaf(f4, fw1[3*64+c], v);
        sHid[it] = gelu_f(v);
    }
    __syncthreads();
    for (int it = tid; it < 6400; it += 256) {
        int pr = it >> 6, c = it & 63;
        float v = fb2[c];
        for (int b = 0; b < 64; ++b) v = fmaf(sHid[pr*64+b], fw2[b*64+c], v);
        sFkb[it] = gelu_f(v);
    }
    __syncthreads();
    for (int l = 0; l < 2; ++l)
        for (int it = tid; it < 6400; it += 256) {
            int pr = it >> 6, c = it & 63;
            float v = 0.0f;
            for (int b = 0; b < 64; ++b) v = fmaf(sFkb[pr*64+b], cfw[l*4096 + b*64 + c], v);
            fkg[l*6400 + it] = v;
        }
}

// ---------------------------------------------------------------------------
__global__ __launch_bounds__(256) void k_embed(
    const float* __restrict__ x, const float* __restrict__ ew, float* __restrict__ hg)
{
    int t = blockIdx.x * 256 + threadIdx.x;
    if (t >= N_ * 64) return;
    int n = t >> 6, c = t & 63;
    float v = 0.0f;
#pragma unroll
    for (int k = 0; k < 16; ++k) v = fmaf(x[n*16+k], ew[k*64+c], v);
    int base = n * 640 + c;
#pragma unroll
    for (int o = 0; o < O_; ++o) hg[base + o*64] = v;
}

// ---------------------------------------------------------------------------
__global__ __launch_bounds__(256) void k_hist(const int* __restrict__ ei, int* __restrict__ counts)
{
    int e = blockIdx.x * 256 + threadIdx.x;
    if (e < E_) atomicAdd(&counts[ei[E_ + e]], 1);
}

__global__ __launch_bounds__(1024) void k_scan(
    const int* __restrict__ counts, int* __restrict__ offs, int* __restrict__ cursor)
{
    __shared__ int part[1024];
    int t = threadIdx.x;
    const int CH = 10;
    int base_i = t * CH;
    int s = 0;
#pragma unroll
    for (int i = 0; i < CH; ++i) { int idx = base_i + i; if (idx < N_) s += counts[idx]; }
    part[t] = s;
    __syncthreads();
    for (int off = 1; off < 1024; off <<= 1) {
        int v = (t >= off) ? part[t - off] : 0;
        __syncthreads();
        part[t] += v;
        __syncthreads();
    }
    int run = (t > 0) ? part[t - 1] : 0;
#pragma unroll
    for (int i = 0; i < CH; ++i) {
        int idx = base_i + i;
        if (idx < N_) { offs[idx] = run; cursor[idx] = run; run += counts[idx]; }
    }
    if (t == 1023) offs[N_] = run;
}

__global__ __launch_bounds__(256) void k_scatter(
    const int* __restrict__ ei, const float* __restrict__ pos,
    int* __restrict__ cursor, int* __restrict__ csend, int* __restrict__ crecv,
    float* __restrict__ crel)
{
    int e = blockIdx.x * 256 + threadIdx.x;
    if (e >= E_) return;
    int s = ei[e], r = ei[E_ + e];
    int slot = atomicAdd(&cursor[r], 1);
    csend[slot] = s;
    crecv[slot] = r;
    crel[slot*3+0] = pos[s*3+0] - pos[r*3+0];
    crel[slot*3+1] = pos[s*3+1] - pos[r*3+1];
    crel[slot*3+2] = pos[s*3+2] - pos[r*3+2];
}

// ---------------------------------------------------------------------------
// MFMA stage helper (unchanged structure)
// ---------------------------------------------------------------------------
template<int KS, int WSTRIDE, bool BIAS, bool GELU>
__device__ __forceinline__ void mfma_stage(
    unsigned short* sData, const unsigned short* sW, const float* bias,
    int rbase, int lane)
{
    const int lm = lane & 15, lk = lane >> 4;
    bf16x8 Bf[4][KS];
#pragma unroll
    for (int nt = 0; nt < 4; ++nt)
#pragma unroll
        for (int ks = 0; ks < KS; ++ks) {
            int r = rbase + nt*16 + lm;
            int kb = ks*64 + lk*16;
            Bf[nt][ks] = *(const bf16x8*)((const char*)sData + r*128 + (kb ^ ((r&7)<<4)));
        }
#pragma unroll
    for (int mt = 0; mt < 4; ++mt) {
        bf16x8 Af[KS];
#pragma unroll
        for (int ks = 0; ks < KS; ++ks) {
            int r = mt*16 + lm;
            int kb = ks*64 + lk*16;
            int sw = ((r&7)<<4) & (WSTRIDE-1);
            Af[ks] = *(const bf16x8*)((const char*)sW + r*WSTRIDE + (kb ^ sw));
        }
        f32x4 b4 = {0,0,0,0};
        if (BIAS) b4 = *(const f32x4*)(bias + mt*16 + (lk<<2));
#pragma unroll
        for (int nt = 0; nt < 4; ++nt) {
            f32x4 acc = {0,0,0,0};
#pragma unroll
            for (int ks = 0; ks < KS; ++ks) acc = MFMA16(Af[ks], Bf[nt][ks], acc);
            bf16x4 pk;
#pragma unroll
            for (int r = 0; r < 4; ++r) {
                float v = acc[r] + b4[r];
                if (GELU) v = gelu_f(v);
                pk[r] = (short)f2bf(v);
            }
            int rr = rbase + nt*16 + lm;
            int cb = mt*32 + (lk<<3);
            *(bf16x4*)((char*)sData + rr*128 + (cb ^ ((rr&7)<<4))) = pk;
        }
    }
}

// ---------------------------------------------------------------------------
// Message passing: 256 items/block.  MFMA basis pipeline -> kc; scatter tail
// with ballot run-mask + 16-deep prefetch + SALU o-cycling.
// ---------------------------------------------------------------------------
__global__ __launch_bounds__(256) void k_msg(
    const float* __restrict__ hg, float* __restrict__ h1g,
    const int* __restrict__ csend, const int* __restrict__ crecv,
    const float* __restrict__ crel, const float* __restrict__ ori,
    const unsigned short* __restrict__ wW1T, const unsigned short* __restrict__ wW2T,
    const unsigned short* __restrict__ wCKT_l,
    const float* __restrict__ bb1, const float* __restrict__ bb2)
{
    __shared__ unsigned short sData[256*64];
    __shared__ unsigned short sW1[64*32];
    __shared__ unsigned short sW2[64*64];
    __shared__ unsigned short sCK[64*64];
    const int tid = threadIdx.x;
    const int lane = tid & 63, wv = tid >> 6;
    // stage weights (swizzled)
    for (int i = tid*16; i < 4096; i += 256*16) {
        int r = i >> 6, off = i & 63;
        *(f32x4*)((char*)sW1 + r*64 + (off ^ (((r&7)<<4) & 63))) = *(const f32x4*)((const char*)wW1T + i);
    }
    for (int i = tid*16; i < 8192; i += 256*16) {
        int r = i >> 7, off = i & 127;
        *(f32x4*)((char*)sW2 + r*128 + (off ^ ((r&7)<<4))) = *(const f32x4*)((const char*)wW2T + i);
    }
    for (int i = tid*16; i < 8192; i += 256*16) {
        int r = i >> 7, off = i & 127;
        *(f32x4*)((char*)sCK + r*128 + (off ^ ((r&7)<<4))) = *(const f32x4*)((const char*)wCKT_l + i);
    }
    // phase 0: per-item monomial features
    const int item = blockIdx.x * 256 + tid;
    const int slot = item / 10;
    const int oo = item - slot * 10;
    const int snd = csend[slot];
    const int rcv = crecv[slot];
    {
        float r0 = crel[slot*3+0], r1 = crel[slot*3+1], r2 = crel[slot*3+2];
        float o0 = ori[oo*3+0], o1 = ori[oo*3+1], o2 = ori[oo*3+2];
        float a = r0*o0 + r1*o1 + r2*o2;
        float p0 = fmaf(-a, o0, r0), p1 = fmaf(-a, o1, r1), p2 = fmaf(-a, o2, r2);
        float b = sqrtf(p0*p0 + p1*p1 + p2*p2);
        float a2 = a*a, b2 = b*b, ab = a*b;
        float m[14];
        m[0]=a; m[1]=b; m[2]=a2; m[3]=ab; m[4]=b2;
        m[5]=a2*a; m[6]=a2*b; m[7]=a*b2; m[8]=b2*b;
        m[9]=a2*a2; m[10]=a2*ab; m[11]=a2*b2; m[12]=ab*b2; m[13]=b2*b2;
        unsigned int pk[16];
#pragma unroll
        for (int j = 0; j < 7; ++j)
            pk[j] = (unsigned int)f2bf(m[2*j]) | ((unsigned int)f2bf(m[2*j+1]) << 16);
#pragma unroll
        for (int j = 7; j < 16; ++j) pk[j] = 0;
        int r = tid;
#pragma unroll
        for (int q = 0; q < 4; ++q) {
            int cb = q*16;
            *(f32x4*)((char*)sData + r*128 + (cb ^ ((r&7)<<4))) = ((const f32x4*)pk)[q];
        }
    }
    __syncthreads();
    const int rbase = wv * 64;
    mfma_stage<1, 64,  true,  true >(sData, sW1, bb1, rbase, lane);
    mfma_stage<2, 128, true,  true >(sData, sW2, bb2, rbase, lane);
    mfma_stage<2, 128, false, false>(sData, sCK, (const float*)0, rbase, lane);

    // ---- scatter tail: prefetched, SALU-driven run handling ----
    const int myaddr = (snd * 10 + oo) * 64;           // per-lane gather base
    int prevr = __shfl_up(rcv, 1);
    unsigned long long bmask = __ballot(lane > 0 && rcv != prevr);
    const float* hb = hg + lane;
    float a0=0,a1c=0,a2c=0,a3c=0,a4c=0,a5c=0,a6c=0,a7c=0,a8c=0,a9c=0;
    int cur = __builtin_amdgcn_readfirstlane(rcv);
    int soi = (blockIdx.x * 256 + rbase) % 10;         // scalar o index, cycles
#define FLUSH_RUN(R) { float* bp = h1g + (R)*640 + lane; \
    atomicAdd(bp+0,a0); atomicAdd(bp+64,a1c); atomicAdd(bp+128,a2c); atomicAdd(bp+192,a3c); \
    atomicAdd(bp+256,a4c); atomicAdd(bp+320,a5c); atomicAdd(bp+384,a6c); atomicAdd(bp+448,a7c); \
    atomicAdd(bp+512,a8c); atomicAdd(bp+576,a9c); \
    a0=a1c=a2c=a3c=a4c=a5c=a6c=a7c=a8c=a9c=0.0f; }
#pragma unroll
    for (int ch = 0; ch < 4; ++ch) {
        float hv[16], kcv[16];
#pragma unroll
        for (int j = 0; j < 16; ++j) {
            const int i = ch*16 + j;
            hv[j] = hb[__builtin_amdgcn_readlane(myaddr, i)];
            const int rr = rbase + i;
            kcv[j] = bf2f(*(const unsigned short*)((const char*)sData + rr*128 + ((lane*2) ^ ((rr&7)<<4))));
        }
#pragma unroll
        for (int j = 0; j < 16; ++j) {
            const int i = ch*16 + j;
            if (bmask & (1ull << i)) { FLUSH_RUN(cur); cur = __builtin_amdgcn_readlane(rcv, i); }
            float mv = kcv[j] * hv[j];
            if      (soi == 0) a0  += mv;
            else if (soi == 1) a1c += mv;
            else if (soi == 2) a2c += mv;
            else if (soi == 3) a3c += mv;
            else if (soi == 4) a4c += mv;
            else if (soi == 5) a5c += mv;
            else if (soi == 6) a6c += mv;
            else if (soi == 7) a7c += mv;
            else if (soi == 8) a8c += mv;
            else               a9c += mv;
            soi = (soi == 9) ? 0 : soi + 1;
        }
    }
    FLUSH_RUN(cur);
#undef FLUSH_RUN
}

// ---------------------------------------------------------------------------
// Fused fiber conv + LayerNorm -> y bf16.  Grid-strided; wave per node.
// ---------------------------------------------------------------------------
__global__ __launch_bounds__(256) void k_fln(
    const float* __restrict__ h1, const float* __restrict__ fkg,
    const float* __restrict__ cb, const float* __restrict__ ns,
    const float* __restrict__ nb, unsigned short* __restrict__ y)
{
    __shared__ float sFK[6400];
    const int tid = threadIdx.x;
    for (int i = tid; i < 6400; i += 256) sFK[i] = fkg[i];
    __syncthreads();
    const int lane = tid & 63, wv = tid >> 6;
    float cbv = cb[lane], nsv = ns[lane], nbv = nb[lane];
    for (int g4 = blockIdx.x; g4 < N_/4; g4 += gridDim.x) {
        const int n = g4 * 4 + wv;
        float hr[10];
#pragma unroll
        for (int o = 0; o < O_; ++o) hr[o] = h1[n*640 + o*64 + lane];
#pragma unroll
        for (int p = 0; p < O_; ++p) {
            float v = 0.0f;
#pragma unroll
            for (int o = 0; o < O_; ++o) v = fmaf(hr[o], sFK[(p*O_+o)*64 + lane], v);
            v = v * 0.1f + cbv;
            float s = v, q = v*v;
#pragma unroll
            for (int d = 1; d < 64; d <<= 1) { s += __shfl_xor(s, d); q += __shfl_xor(q, d); }
            float mu = s * (1.0f/64.0f);
            float var = q * (1.0f/64.0f) - mu*mu;
            float rs = rsqrtf(var + 1e-6f);
            float yv = (v - mu) * rs * nsv + nbv;
            y[(n*O_ + p)*64 + lane] = f2bf(yv);
        }
    }
}

// ---------------------------------------------------------------------------
// MLP: 128 rows/block; single 16KB LDS buffer (y tile -> per-wave mid scratch
// -> hn stash; all wave-private after the one sync).
// ---------------------------------------------------------------------------
__global__ __launch_bounds__(256, 4) void k_mlp(
    const unsigned short* __restrict__ y, float* __restrict__ hg, float* __restrict__ racc,
    const unsigned short* __restrict__ wL1T_l, const float* __restrict__ l1b_l,
    const unsigned short* __restrict__ wL2T_l, const float* __restrict__ l2b_l,
    const unsigned short* __restrict__ wROT_l, const float* __restrict__ rob_l)
{
    __shared__ unsigned short sA[128*64];
    const int tid = threadIdx.x;
    const int lane = tid & 63, wv = tid >> 6;
    const int rb = blockIdx.x * 128;
    // stage y tile (clamped)
    for (int i = tid*16; i < 128*128; i += 256*16) {
        int r = i >> 7, off = i & 127;
        int grow = rb + r; if (grow >= NROW_) grow = NROW_ - 1;
        *(f32x4*)((char*)sA + r*128 + (off ^ ((r&7)<<4))) =
            *(const f32x4*)((const char*)y + (size_t)grow*128 + off);
    }
    __syncthreads();
    const int lm = lane & 15, lk = lane >> 4;
    // prehold y B-frags (wave's 32 rows) -- after this, sA rows wv*32.. are scratch
    bf16x8 Yf[2][2];
#pragma unroll
    for (int nt = 0; nt < 2; ++nt)
#pragma unroll
        for (int ks = 0; ks < 2; ++ks) {
            int r = wv*32 + nt*16 + lm;
            int kb = ks*64 + lk*16;
            Yf[nt][ks] = *(const bf16x8*)((const char*)sA + r*128 + (kb ^ ((r&7)<<4)));
        }
    f32x4 acc2[4][2];
#pragma unroll
    for (int m = 0; m < 4; ++m)
#pragma unroll
        for (int n = 0; n < 2; ++n) acc2[m][n] = (f32x4){0,0,0,0};
#pragma unroll
    for (int jb = 0; jb < 4; ++jb) {
        // GEMM1: hidden chunk = gelu(W1^T y + b1) -> wave-private mid scratch
#pragma unroll
        for (int mt = 0; mt < 4; ++mt) {
            bf16x8 A1[2];
#pragma unroll
            for (int ks = 0; ks < 2; ++ks)
                A1[ks] = *(const bf16x8*)(wL1T_l + ((jb*64 + mt*16 + lm)*64 + ks*32 + lk*8));
            f32x4 b4 = *(const f32x4*)(l1b_l + jb*64 + mt*16 + (lk<<2));
#pragma unroll
            for (int nt = 0; nt < 2; ++nt) {
                f32x4 acc = {0,0,0,0};
                acc = MFMA16(A1[0], Yf[nt][0], acc);
                acc = MFMA16(A1[1], Yf[nt][1], acc);
                bf16x4 pk;
#pragma unroll
                for (int r = 0; r < 4; ++r) pk[r] = (short)f2bf(gelu_f(acc[r] + b4[r]));
                int rr = wv*32 + nt*16 + lm;
                int cb = mt*32 + (lk<<3);
                *(bf16x4*)((char*)sA + rr*128 + (cb ^ ((rr&7)<<4))) = pk;
            }
        }
        // GEMM2: accumulate W2^T(chunk) mid
        bf16x8 Mf[2][2];
#pragma unroll
        for (int nt = 0; nt < 2; ++nt)
#pragma unroll
            for (int ks = 0; ks < 2; ++ks) {
                int r = wv*32 + nt*16 + lm;
                int kb = ks*64 + lk*16;
                Mf[nt][ks] = *(const bf16x8*)((const char*)sA + r*128 + (kb ^ ((r&7)<<4)));
            }
#pragma unroll
        for (int mt2 = 0; mt2 < 4; ++mt2) {
            bf16x8 A2[2];
#pragma unroll
            for (int ks = 0; ks < 2; ++ks)
                A2[ks] = *(const bf16x8*)(wL2T_l + ((mt2*16 + lm)*256 + jb*64 + ks*32 + lk*8));
#pragma unroll
            for (int nt = 0; nt < 2; ++nt) {
                acc2[mt2][nt] = MFMA16(A2[0], Mf[nt][0], acc2[mt2][nt]);
                acc2[mt2][nt] = MFMA16(A2[1], Mf[nt][1], acc2[mt2][nt]);
            }
        }
    }
    // epilogue: bias + residual into h, stash hn bf16 into sA
#pragma unroll
    for (int mt2 = 0; mt2 < 4; ++mt2) {
        f32x4 b2 = *(const f32x4*)(l2b_l + mt2*16 + (lk<<2));
#pragma unroll
        for (int nt = 0; nt < 2; ++nt) {
            int rloc = wv*32 + nt*16 + lm;
            int grow = rb + rloc;
            bool valid = grow < NROW_;
            int growc = valid ? grow : (NROW_ - 1);
            f32x4 hv = *(const f32x4*)(hg + (size_t)growc*64 + mt2*16 + (lk<<2));
            f32x4 hn;
            bf16x4 pk;
#pragma unroll
            for (int r = 0; r < 4; ++r) {
                hn[r] = hv[r] + acc2[mt2][nt][r] + b2[r];
                pk[r] = (short)f2bf(hn[r]);
            }
            if (valid) *(f32x4*)(hg + (size_t)grow*64 + mt2*16 + (lk<<2)) = hn;
            int cb = mt2*32 + (lk<<3);
            *(bf16x4*)((char*)sA + rloc*128 + (cb ^ ((rloc&7)<<4))) = pk;
        }
    }
    // readout: ro^T hn -> racc atomics
    bf16x8 Ro[2];
#pragma unroll
    for (int ks = 0; ks < 2; ++ks)
        Ro[ks] = *(const bf16x8*)(wROT_l + (lm*64 + ks*32 + lk*8));
    f32x4 rb4 = *(const f32x4*)(rob_l + (lk<<2));
#pragma unroll
    for (int nt = 0; nt < 2; ++nt) {
        int rloc = wv*32 + nt*16 + lm;
        bf16x8 Hf[2];
#pragma unroll
        for (int ks = 0; ks < 2; ++ks) {
            int kb = ks*64 + lk*16;
            Hf[ks] = *(const bf16x8*)((const char*)sA + rloc*128 + (kb ^ ((rloc&7)<<4)));
        }
        f32x4 r4 = {0,0,0,0};
        r4 = MFMA16(Ro[0], Hf[0], r4);
        r4 = MFMA16(Ro[1], Hf[1], r4);
        int grow = rb + rloc;
        if (grow < NROW_) {
            int n = grow / 10;
#pragma unroll
            for (int r = 0; r < 4; ++r)
                atomicAdd(&racc[n*16 + lk*4 + r], r4[r] + rb4[r]);
        }
    }
}

// ---------------------------------------------------------------------------
__global__ __launch_bounds__(256) void k_pool(
    const float* __restrict__ racc, const int* __restrict__ batch, float* __restrict__ out)
{
    int t = blockIdx.x * 256 + threadIdx.x;
    if (t >= N_ * 16) return;
    int n = t >> 4, j = t & 15;
    atomicAdd(&out[batch[n]*16 + j], racc[t] * (1.0f/20.0f));
}

// ---------------------------------------------------------------------------
extern "C" void kernel_launch(void* const* d_in, const int* in_sizes, int n_in,
                              void* d_out, int out_size, void* d_ws, size_t ws_size,
                              hipStream_t stream)
{
    const float* x    = (const float*)d_in[0];
    const float* pos  = (const float*)d_in[1];
    const float* bw1  = (const float*)d_in[2];
    const float* bb1  = (const float*)d_in[3];
    const float* bw2  = (const float*)d_in[4];
    const float* bb2  = (const float*)d_in[5];
    const float* fw1  = (const float*)d_in[6];
    const float* fb1  = (const float*)d_in[7];
    const float* fw2  = (const float*)d_in[8];
    const float* fb2  = (const float*)d_in[9];
    const float* embw = (const float*)d_in[10];
    const float* ckw  = (const float*)d_in[11];
    const float* cfw  = (const float*)d_in[12];
    const float* cb   = (const float*)d_in[13];
    const float* ns   = (const float*)d_in[14];
    const float* nbp  = (const float*)d_in[15];
    const float* l1w  = (const float*)d_in[16];
    const float* l1b  = (const float*)d_in[17];
    const float* l2w  = (const float*)d_in[18];
    const float* l2b  = (const float*)d_in[19];
    const float* row  = (const float*)d_in[20];
    const float* rob  = (const float*)d_in[21];
    const int*   ei   = (const int*)d_in[22];
    const int*   batch= (const int*)d_in[23];
    float* out = (float*)d_out;

    char* w = (char*)d_ws;
    size_t off = 0;
    auto alloc = [&](size_t bytes) -> char* {
        char* p = w + off; off += (bytes + 255) / 256 * 256; return p;
    };
    float* ori    = (float*)alloc(32 * 4);
    float* fkg    = (float*)alloc(2 * 6400 * 4);
    unsigned short* wW1T = (unsigned short*)alloc(64*32*2);
    unsigned short* wW2T = (unsigned short*)alloc(64*64*2);
    unsigned short* wCKT = (unsigned short*)alloc(2*64*64*2);
    unsigned short* wL1T = (unsigned short*)alloc(2*256*64*2);
    unsigned short* wL2T = (unsigned short*)alloc(2*64*256*2);
    unsigned short* wROT = (unsigned short*)alloc(2*16*64*2);
    float* h      = (float*)alloc((size_t)N_ * 640 * 4);
    float* h1     = (float*)alloc((size_t)N_ * 640 * 4);
    unsigned short* y = (unsigned short*)alloc((size_t)NROW_ * 64 * 2);
    float* racc   = (float*)alloc((size_t)N_ * 16 * 4);
    float* crel   = (float*)alloc((size_t)E_ * 3 * 4);
    int*   counts = (int*)alloc((N_ + 1) * 4);
    int*   offs   = (int*)alloc((N_ + 1) * 4);
    int*   cursor = (int*)alloc((N_ + 1) * 4);
    int*   csend  = (int*)alloc((size_t)E_ * 4);
    int*   crecv  = (int*)alloc((size_t)E_ * 4);

    hipMemsetAsync(out, 0, (size_t)out_size * 4, stream);
    hipMemsetAsync(racc, 0, (size_t)N_ * 16 * 4, stream);
    hipMemsetAsync(counts, 0, (N_ + 1) * 4, stream);

    k_small<<<1, 256, 0, stream>>>(bw1, fw1, fb1, fw2, fb2, cfw, bw2, ckw, l1w, l2w, row,
                                   ori, fkg, wW1T, wW2T, wCKT, wL1T, wL2T, wROT);
    k_embed<<<(N_ * 64 + 255) / 256, 256, 0, stream>>>(x, embw, h);
    k_hist<<<(E_ + 255) / 256, 256, 0, stream>>>(ei, counts);
    k_scan<<<1, 1024, 0, stream>>>(counts, offs, cursor);
    k_scatter<<<(E_ + 255) / 256, 256, 0, stream>>>(ei, pos, cursor, csend, crecv, crel);

    for (int l = 0; l < 2; ++l) {
        hipMemsetAsync(h1, 0, (size_t)N_ * 640 * 4, stream);
        k_msg<<<NITEM_ / 256, 256, 0, stream>>>(h, h1, csend, crecv, crel, ori,
                                                wW1T, wW2T, wCKT + l*4096,
                                                bb1, bb2);
        k_fln<<<625, 256, 0, stream>>>(h1, fkg + l*6400, cb + l*64, ns + l*64, nbp + l*64, y);
        k_mlp<<<(NROW_ + 127) / 128, 256, 0, stream>>>(y, h, racc,
                                                       wL1T + l*16384, l1b + l*256,
                                                       wL2T + l*16384, l2b + l*64,
                                                       wROT + l*1024, rob + l*16);
    }
    k_pool<<<(N_ * 16 + 255) / 256, 256, 0, stream>>>(racc, batch, out);
}

// Round 5
// 536.455 us; speedup vs baseline: 18.5228x; 1.3721x over previous
//
#include <hip/hip_runtime.h>
#include <math.h>

#define N_   10000
#define E_   80000
#define O_   10
#define B_   16
#define OUT_ 16
#define NROW_ (N_*O_)    // 100000
#define NITEM_ (E_*O_)   // 800000

typedef __attribute__((ext_vector_type(8))) short bf16x8;
typedef __attribute__((ext_vector_type(4))) short bf16x4;
typedef __attribute__((ext_vector_type(4))) float f32x4;

#define MFMA16(a,b,c) __builtin_amdgcn_mfma_f32_16x16x32_bf16(a,b,c,0,0,0)

__device__ __forceinline__ float gelu_f(float x) {
    float t = x * x;
    float u = fmaf(0.044715f, t, 1.0f);
    float e = __expf(1.5957691216057308f * x * u);
    float r = __fdividef(1.0f, e + 1.0f);
    return fmaf(-x, r, x);
}

__device__ __forceinline__ unsigned short f2bf(float f) {
    union { float f; unsigned int u; } v; v.f = f;
    unsigned int r = v.u + 0x7FFFu + ((v.u >> 16) & 1u);
    return (unsigned short)(r >> 16);
}
__device__ __forceinline__ float bf2f(unsigned short u) {
    union { unsigned int u; float f; } v; v.u = ((unsigned int)u) << 16;
    return v.f;
}

// ---------------------------------------------------------------------------
// Precompute (1 block): orientations, folded basis_w1, fiber MLP -> fk (fp32),
// and ALL weights pre-packed in MFMA A-fragment order:
//   P[((mt*KS+ks)*64 + lane)*8 + j] = WT[mt*16 + (lane&15)][ks*32 + (lane>>4)*8 + j]
// so every A-frag load in the hot kernels is one coalesced 16 B/lane load.
// ---------------------------------------------------------------------------
__global__ __launch_bounds__(256) void k_small(
    const float* __restrict__ bw1,
    const float* __restrict__ fw1, const float* __restrict__ fb1,
    const float* __restrict__ fw2, const float* __restrict__ fb2,
    const float* __restrict__ cfw,
    const float* __restrict__ bw2, const float* __restrict__ ckw,
    const float* __restrict__ l1w, const float* __restrict__ l2w,
    const float* __restrict__ row_w,
    float* __restrict__ orig, float* __restrict__ fkg,
    unsigned short* __restrict__ wW1P, unsigned short* __restrict__ wW2P,
    unsigned short* __restrict__ wCKP, unsigned short* __restrict__ wL1P,
    unsigned short* __restrict__ wL2P, unsigned short* __restrict__ wROP)
{
    __shared__ float sOri[32];
    __shared__ float sHid[6400];
    __shared__ float sFkb[6400];
    __shared__ float sW1f[14*64];
    int tid = threadIdx.x;
    if (tid < O_) {
        float i = (float)tid + 0.5f;
        float phi = acosf(1.0f - 2.0f * i / (float)O_);
        float theta = 3.14159265358979323846f * (1.0f + 2.2360679774997896964f) * i;
        float sp = sinf(phi);
        float v0 = cosf(theta) * sp, v1 = sinf(theta) * sp, v2 = cosf(phi);
        sOri[tid*3+0] = v0; sOri[tid*3+1] = v1; sOri[tid*3+2] = v2;
        orig[tid*3+0] = v0; orig[tid*3+1] = v1; orig[tid*3+2] = v2;
    }
    {
        const int map[30] = {0,1, 2,3,3,4, 5,6,6,7,6,7,7,8,
                             9,10,10,11,10,11,11,12, 10,11,11,12, 11,12,12,13};
        for (int idx = tid; idx < 14*64; idx += 256) {
            int mono = idx >> 6, c = idx & 63;
            float s = 0.0f;
            for (int p = 0; p < 30; ++p) if (map[p] == mono) s += bw1[p*64 + c];
            sW1f[idx] = s;
        }
    }
    __syncthreads();
    // ---- frag-packed weights ----
    // W1: M=64,K=32 (pad>=14 with 0); WT[c][p] = sW1f[p*64+c]
    for (int idx = tid; idx < 4*512; idx += 256) {
        int t = idx >> 9, rem = idx & 511;
        int ln = rem >> 3, j = rem & 7;
        int row = t*16 + (ln & 15);
        int k = (ln >> 4)*8 + j;
        wW1P[idx] = f2bf(k < 14 ? sW1f[k*64 + row] : 0.0f);
    }
    // W2: M=64,K=64; WT[bd][c] = bw2[c*64+bd]
    for (int idx = tid; idx < 8*512; idx += 256) {
        int t = idx >> 9, rem = idx & 511;
        int mt = t >> 1, ks = t & 1;
        int ln = rem >> 3, j = rem & 7;
        int row = mt*16 + (ln & 15);
        int k = ks*32 + (ln >> 4)*8 + j;
        wW2P[idx] = f2bf(bw2[k*64 + row]);
    }
    // CK[l]: M=64,K=64; WT[c'][bd] = ckw[l][bd][c']
    for (int idx = tid; idx < 2*8*512; idx += 256) {
        int l = idx >> 12, r2 = idx & 4095;
        int t = r2 >> 9, rem = r2 & 511;
        int mt = t >> 1, ks = t & 1;
        int ln = rem >> 3, j = rem & 7;
        int row = mt*16 + (ln & 15);
        int k = ks*32 + (ln >> 4)*8 + j;
        wCKP[idx] = f2bf(ckw[l*4096 + k*64 + row]);
    }
    // L1[l]: M=256,K=64; WT[hid][c] = l1w[l][c][hid]
    for (int idx = tid; idx < 2*32*512; idx += 256) {
        int l = idx >> 14, r2 = idx & 16383;
        int t = r2 >> 9, rem = r2 & 511;
        int mt = t >> 1, ks = t & 1;          // mt 0..15
        int ln = rem >> 3, j = rem & 7;
        int row = mt*16 + (ln & 15);
        int k = ks*32 + (ln >> 4)*8 + j;
        wL1P[idx] = f2bf(l1w[l*16384 + k*256 + row]);
    }
    // L2[l]: M=64,K=256; WT[c][hid] = l2w[l][hid][c]
    for (int idx = tid; idx < 2*32*512; idx += 256) {
        int l = idx >> 14, r2 = idx & 16383;
        int t = r2 >> 9, rem = r2 & 511;
        int mt2 = t >> 3, ksg = t & 7;        // mt2 0..3, ksg 0..7
        int ln = rem >> 3, j = rem & 7;
        int row = mt2*16 + (ln & 15);
        int k = ksg*32 + (ln >> 4)*8 + j;
        wL2P[idx] = f2bf(l2w[l*16384 + k*64 + row]);
    }
    // RO[l]: M=16,K=64; WT[j'][c] = row_w[l][c][j']
    for (int idx = tid; idx < 2*2*512; idx += 256) {
        int l = idx >> 10, r2 = idx & 1023;
        int ks = r2 >> 9, rem = r2 & 511;
        int ln = rem >> 3, j = rem & 7;
        int row = ln & 15;
        int k = ks*32 + (ln >> 4)*8 + j;
        wROP[idx] = f2bf(row_w[l*1024 + k*16 + row]);
    }
    // ---- fiber basis MLP -> fkg (fp32) ----
    for (int it = tid; it < 6400; it += 256) {
        int pr = it >> 6, c = it & 63;
        int i = pr / O_, j = pr % O_;
        float a = sOri[i*3+0]*sOri[j*3+0] + sOri[i*3+1]*sOri[j*3+1] + sOri[i*3+2]*sOri[j*3+2];
        float f1 = a, f2 = a*a, f3 = f2*a, f4 = f3*a;
        float v = fb1[c];
        v = fmaf(f1, fw1[0*64+c], v);
        v = fmaf(f2, fw1[1*64+c], v);
        v = fmaf(f3, fw1[2*64+c], v);
        v = fmaf(f4, fw1[3*64+c], v);
        sHid[it] = gelu_f(v);
    }
    __syncthreads();
    for (int it = tid; it < 6400; it += 256) {
        int pr = it >> 6, c = it & 63;
        float v = fb2[c];
        for (int b = 0; b < 64; ++b) v = fmaf(sHid[pr*64+b], fw2[b*64+c], v);
        sFkb[it] = gelu_f(v);
    }
    __syncthreads();
    for (int l = 0; l < 2; ++l)
        for (int it = tid; it < 6400; it += 256) {
            int pr = it >> 6, c = it & 63;
            float v = 0.0f;
            for (int b = 0; b < 64; ++b) v = fmaf(sFkb[pr*64+b], cfw[l*4096 + b*64 + c], v);
            fkg[l*6400 + it] = v;
        }
}

// ---------------------------------------------------------------------------
__global__ __launch_bounds__(256) void k_embed(
    const float* __restrict__ x, const float* __restrict__ ew, float* __restrict__ hg)
{
    int t = blockIdx.x * 256 + threadIdx.x;
    if (t >= N_ * 64) return;
    int n = t >> 6, c = t & 63;
    float v = 0.0f;
#pragma unroll
    for (int k = 0; k < 16; ++k) v = fmaf(x[n*16+k], ew[k*64+c], v);
    int base = n * 640 + c;
#pragma unroll
    for (int o = 0; o < O_; ++o) hg[base + o*64] = v;
}

// ---------------------------------------------------------------------------
__global__ __launch_bounds__(256) void k_hist(const int* __restrict__ ei, int* __restrict__ counts)
{
    int e = blockIdx.x * 256 + threadIdx.x;
    if (e < E_) atomicAdd(&counts[ei[E_ + e]], 1);
}

__global__ __launch_bounds__(1024) void k_scan(
    const int* __restrict__ counts, int* __restrict__ offs, int* __restrict__ cursor)
{
    __shared__ int part[1024];
    int t = threadIdx.x;
    const int CH = 10;
    int base_i = t * CH;
    int s = 0;
#pragma unroll
    for (int i = 0; i < CH; ++i) { int idx = base_i + i; if (idx < N_) s += counts[idx]; }
    part[t] = s;
    __syncthreads();
    for (int off = 1; off < 1024; off <<= 1) {
        int v = (t >= off) ? part[t - off] : 0;
        __syncthreads();
        part[t] += v;
        __syncthreads();
    }
    int run = (t > 0) ? part[t - 1] : 0;
#pragma unroll
    for (int i = 0; i < CH; ++i) {
        int idx = base_i + i;
        if (idx < N_) { offs[idx] = run; cursor[idx] = run; run += counts[idx]; }
    }
    if (t == 1023) offs[N_] = run;
}

__global__ __launch_bounds__(256) void k_scatter(
    const int* __restrict__ ei, const float* __restrict__ pos,
    int* __restrict__ cursor, int* __restrict__ csend, int* __restrict__ crecv,
    float* __restrict__ crel)
{
    int e = blockIdx.x * 256 + threadIdx.x;
    if (e >= E_) return;
    int s = ei[e], r = ei[E_ + e];
    int slot = atomicAdd(&cursor[r], 1);
    csend[slot] = s;
    crecv[slot] = r;
    crel[slot*3+0] = pos[s*3+0] - pos[r*3+0];
    crel[slot*3+1] = pos[s*3+1] - pos[r*3+1];
    crel[slot*3+2] = pos[s*3+2] - pos[r*3+2];
}

// ---------------------------------------------------------------------------
// MFMA stage with frag-packed global weights (coalesced 16 B/lane loads).
// ---------------------------------------------------------------------------
template<int KS, bool BIAS, bool GELU>
__device__ __forceinline__ void mfma_stageP(
    unsigned short* sData, const unsigned short* __restrict__ Wp,
    const float* __restrict__ bias, int rbase, int lane)
{
    const int lm = lane & 15, lk = lane >> 4;
    bf16x8 Bf[4][KS];
#pragma unroll
    for (int nt = 0; nt < 4; ++nt)
#pragma unroll
        for (int ks = 0; ks < KS; ++ks) {
            int r = rbase + nt*16 + lm;
            int kb = ks*64 + lk*16;
            Bf[nt][ks] = *(const bf16x8*)((const char*)sData + r*128 + (kb ^ ((r&7)<<4)));
        }
#pragma unroll
    for (int mt = 0; mt < 4; ++mt) {
        bf16x8 Af[KS];
#pragma unroll
        for (int ks = 0; ks < KS; ++ks)
            Af[ks] = *(const bf16x8*)(Wp + ((mt*KS + ks)*64 + lane)*8);
        f32x4 b4 = {0,0,0,0};
        if (BIAS) b4 = *(const f32x4*)(bias + mt*16 + (lk<<2));
#pragma unroll
        for (int nt = 0; nt < 4; ++nt) {
            f32x4 acc = {0,0,0,0};
#pragma unroll
            for (int ks = 0; ks < KS; ++ks) acc = MFMA16(Af[ks], Bf[nt][ks], acc);
            bf16x4 pk;
#pragma unroll
            for (int r = 0; r < 4; ++r) {
                float v = acc[r] + b4[r];
                if (GELU) v = gelu_f(v);
                pk[r] = (short)f2bf(v);
            }
            int rr = rbase + nt*16 + lm;
            int cb = mt*32 + (lk<<3);
            *(bf16x4*)((char*)sData + rr*128 + (cb ^ ((rr&7)<<4))) = pk;
        }
    }
}

// ---------------------------------------------------------------------------
// Message passing: 256 items/block, barrier-free (all LDS use is wave-private;
// DS ops are in-order within a wave).  32 KB LDS -> 5 blocks/CU.
// ---------------------------------------------------------------------------
__global__ __launch_bounds__(256) void k_msg(
    const float* __restrict__ hg, float* __restrict__ h1g,
    const int* __restrict__ csend, const int* __restrict__ crecv,
    const float* __restrict__ crel, const float* __restrict__ ori,
    const unsigned short* __restrict__ wW1P, const unsigned short* __restrict__ wW2P,
    const unsigned short* __restrict__ wCKP_l,
    const float* __restrict__ bb1, const float* __restrict__ bb2)
{
    __shared__ unsigned short sData[256*64];
    const int tid = threadIdx.x;
    const int lane = tid & 63, wv = tid >> 6;
    const int item = blockIdx.x * 256 + tid;
    const int slot = item / 10;
    const int oo = item - slot * 10;
    const int snd = csend[slot];
    const int rcv = crecv[slot];
    {
        float r0 = crel[slot*3+0], r1 = crel[slot*3+1], r2 = crel[slot*3+2];
        float o0 = ori[oo*3+0], o1 = ori[oo*3+1], o2 = ori[oo*3+2];
        float a = r0*o0 + r1*o1 + r2*o2;
        float p0 = fmaf(-a, o0, r0), p1 = fmaf(-a, o1, r1), p2 = fmaf(-a, o2, r2);
        float b = sqrtf(p0*p0 + p1*p1 + p2*p2);
        float a2 = a*a, b2 = b*b, ab = a*b;
        float m[14];
        m[0]=a; m[1]=b; m[2]=a2; m[3]=ab; m[4]=b2;
        m[5]=a2*a; m[6]=a2*b; m[7]=a*b2; m[8]=b2*b;
        m[9]=a2*a2; m[10]=a2*ab; m[11]=a2*b2; m[12]=ab*b2; m[13]=b2*b2;
        unsigned int pk[16];
#pragma unroll
        for (int j = 0; j < 7; ++j)
            pk[j] = (unsigned int)f2bf(m[2*j]) | ((unsigned int)f2bf(m[2*j+1]) << 16);
#pragma unroll
        for (int j = 7; j < 16; ++j) pk[j] = 0;
        int r = tid;
#pragma unroll
        for (int q = 0; q < 4; ++q) {
            int cb = q*16;
            *(f32x4*)((char*)sData + r*128 + (cb ^ ((r&7)<<4))) = ((const f32x4*)pk)[q];
        }
    }
    const int rbase = wv * 64;
    mfma_stageP<1, true,  true >(sData, wW1P,   bb1, rbase, lane);
    mfma_stageP<2, true,  true >(sData, wW2P,   bb2, rbase, lane);
    mfma_stageP<2, false, false>(sData, wCKP_l, (const float*)0, rbase, lane);

    // ---- scatter tail: prefetched, SALU-driven run handling ----
    const int myaddr = (snd * 10 + oo) * 64;
    int prevr = __shfl_up(rcv, 1);
    unsigned long long bmask = __ballot(lane > 0 && rcv != prevr);
    const float* hb = hg + lane;
    float a0=0,a1c=0,a2c=0,a3c=0,a4c=0,a5c=0,a6c=0,a7c=0,a8c=0,a9c=0;
    int cur = __builtin_amdgcn_readfirstlane(rcv);
    int soi = (blockIdx.x * 256 + rbase) % 10;
#define FLUSH_RUN(R) { float* bp = h1g + (R)*640 + lane; \
    atomicAdd(bp+0,a0); atomicAdd(bp+64,a1c); atomicAdd(bp+128,a2c); atomicAdd(bp+192,a3c); \
    atomicAdd(bp+256,a4c); atomicAdd(bp+320,a5c); atomicAdd(bp+384,a6c); atomicAdd(bp+448,a7c); \
    atomicAdd(bp+512,a8c); atomicAdd(bp+576,a9c); \
    a0=a1c=a2c=a3c=a4c=a5c=a6c=a7c=a8c=a9c=0.0f; }
#pragma unroll
    for (int ch = 0; ch < 4; ++ch) {
        float hv[16], kcv[16];
#pragma unroll
        for (int j = 0; j < 16; ++j) {
            const int i = ch*16 + j;
            hv[j] = hb[__builtin_amdgcn_readlane(myaddr, i)];
            const int rr = rbase + i;
            kcv[j] = bf2f(*(const unsigned short*)((const char*)sData + rr*128 + ((lane*2) ^ ((rr&7)<<4))));
        }
#pragma unroll
        for (int j = 0; j < 16; ++j) {
            const int i = ch*16 + j;
            if (bmask & (1ull << i)) { FLUSH_RUN(cur); cur = __builtin_amdgcn_readlane(rcv, i); }
            float mv = kcv[j] * hv[j];
            if      (soi == 0) a0  += mv;
            else if (soi == 1) a1c += mv;
            else if (soi == 2) a2c += mv;
            else if (soi == 3) a3c += mv;
            else if (soi == 4) a4c += mv;
            else if (soi == 5) a5c += mv;
            else if (soi == 6) a6c += mv;
            else if (soi == 7) a7c += mv;
            else if (soi == 8) a8c += mv;
            else               a9c += mv;
            soi = (soi == 9) ? 0 : soi + 1;
        }
    }
    FLUSH_RUN(cur);
#undef FLUSH_RUN
}

// ---------------------------------------------------------------------------
// Fused fiber conv + LayerNorm -> y bf16.  Grid-strided; wave per node.
// ---------------------------------------------------------------------------
__global__ __launch_bounds__(256) void k_fln(
    const float* __restrict__ h1, const float* __restrict__ fkg,
    const float* __restrict__ cb, const float* __restrict__ ns,
    const float* __restrict__ nb, unsigned short* __restrict__ y)
{
    __shared__ float sFK[6400];
    const int tid = threadIdx.x;
    for (int i = tid; i < 6400; i += 256) sFK[i] = fkg[i];
    __syncthreads();
    const int lane = tid & 63, wv = tid >> 6;
    float cbv = cb[lane], nsv = ns[lane], nbv = nb[lane];
    for (int g4 = blockIdx.x; g4 < N_/4; g4 += gridDim.x) {
        const int n = g4 * 4 + wv;
        float hr[10];
#pragma unroll
        for (int o = 0; o < O_; ++o) hr[o] = h1[n*640 + o*64 + lane];
#pragma unroll
        for (int p = 0; p < O_; ++p) {
            float v = 0.0f;
#pragma unroll
            for (int o = 0; o < O_; ++o) v = fmaf(hr[o], sFK[(p*O_+o)*64 + lane], v);
            v = v * 0.1f + cbv;
            float s = v, q = v*v;
#pragma unroll
            for (int d = 1; d < 64; d <<= 1) { s += __shfl_xor(s, d); q += __shfl_xor(q, d); }
            float mu = s * (1.0f/64.0f);
            float var = q * (1.0f/64.0f) - mu*mu;
            float rs = rsqrtf(var + 1e-6f);
            float yv = (v - mu) * rs * nsv + nbv;
            y[(n*O_ + p)*64 + lane] = f2bf(yv);
        }
    }
}

// ---------------------------------------------------------------------------
// MLP: 64 rows/block (grid 1563), frag-packed weights, readout stored (no
// atomics).  8 KB LDS; wave owns 16 rows.
// ---------------------------------------------------------------------------
__global__ __launch_bounds__(256, 4) void k_mlp(
    const unsigned short* __restrict__ y, float* __restrict__ hg, float* __restrict__ rout,
    const unsigned short* __restrict__ wL1P_l, const float* __restrict__ l1b_l,
    const unsigned short* __restrict__ wL2P_l, const float* __restrict__ l2b_l,
    const unsigned short* __restrict__ wROP_l, const float* __restrict__ rob_l)
{
    __shared__ unsigned short sA[64*64];
    const int tid = threadIdx.x;
    const int lane = tid & 63, wv = tid >> 6;
    const int rb = blockIdx.x * 64;
    // stage y tile (clamped): 64 rows x 128 B
#pragma unroll
    for (int i = tid*16; i < 64*128; i += 256*16) {
        int r = i >> 7, off = i & 127;
        int grow = rb + r; if (grow >= NROW_) grow = NROW_ - 1;
        *(f32x4*)((char*)sA + r*128 + (off ^ ((r&7)<<4))) =
            *(const f32x4*)((const char*)y + (size_t)grow*128 + off);
    }
    __syncthreads();
    const int lm = lane & 15, lk = lane >> 4;
    const int r0 = wv*16 + lm;              // wave-private row
    // prehold y B-frags; after this, sA rows wv*16.. are wave scratch
    bf16x8 Yf[2];
#pragma unroll
    for (int ks = 0; ks < 2; ++ks) {
        int kb = ks*64 + lk*16;
        Yf[ks] = *(const bf16x8*)((const char*)sA + r0*128 + (kb ^ ((r0&7)<<4)));
    }
    f32x4 acc2[4];
#pragma unroll
    for (int m = 0; m < 4; ++m) acc2[m] = (f32x4){0,0,0,0};
#pragma unroll
    for (int jb = 0; jb < 4; ++jb) {
        // GEMM1: hidden chunk = gelu(W1^T y + b1) -> wave scratch
#pragma unroll
        for (int mt = 0; mt < 4; ++mt) {
            bf16x8 A1[2];
#pragma unroll
            for (int ks = 0; ks < 2; ++ks)
                A1[ks] = *(const bf16x8*)(wL1P_l + (((jb*4 + mt)*2 + ks)*64 + lane)*8);
            f32x4 b4 = *(const f32x4*)(l1b_l + jb*64 + mt*16 + (lk<<2));
            f32x4 acc = {0,0,0,0};
            acc = MFMA16(A1[0], Yf[0], acc);
            acc = MFMA16(A1[1], Yf[1], acc);
            bf16x4 pk;
#pragma unroll
            for (int r = 0; r < 4; ++r) pk[r] = (short)f2bf(gelu_f(acc[r] + b4[r]));
            int cb = mt*32 + (lk<<3);
            *(bf16x4*)((char*)sA + r0*128 + (cb ^ ((r0&7)<<4))) = pk;
        }
        // GEMM2: accumulate W2^T(chunk)
        bf16x8 Mf[2];
#pragma unroll
        for (int ks = 0; ks < 2; ++ks) {
            int kb = ks*64 + lk*16;
            Mf[ks] = *(const bf16x8*)((const char*)sA + r0*128 + (kb ^ ((r0&7)<<4)));
        }
#pragma unroll
        for (int mt2 = 0; mt2 < 4; ++mt2) {
            bf16x8 A2[2];
#pragma unroll
            for (int ks = 0; ks < 2; ++ks)
                A2[ks] = *(const bf16x8*)(wL2P_l + ((mt2*8 + jb*2 + ks)*64 + lane)*8);
            acc2[mt2] = MFMA16(A2[0], Mf[0], acc2[mt2]);
            acc2[mt2] = MFMA16(A2[1], Mf[1], acc2[mt2]);
        }
    }
    // epilogue: bias + residual into h, stash hn bf16 into sA
    const int grow = rb + r0;
    const bool valid = grow < NROW_;
    const int growc = valid ? grow : (NROW_ - 1);
#pragma unroll
    for (int mt2 = 0; mt2 < 4; ++mt2) {
        f32x4 b2 = *(const f32x4*)(l2b_l + mt2*16 + (lk<<2));
        f32x4 hv = *(const f32x4*)(hg + (size_t)growc*64 + mt2*16 + (lk<<2));
        f32x4 hn;
        bf16x4 pk;
#pragma unroll
        for (int r = 0; r < 4; ++r) {
            hn[r] = hv[r] + acc2[mt2][r] + b2[r];
            pk[r] = (short)f2bf(hn[r]);
        }
        if (valid) *(f32x4*)(hg + (size_t)grow*64 + mt2*16 + (lk<<2)) = hn;
        int cb = mt2*32 + (lk<<3);
        *(bf16x4*)((char*)sA + r0*128 + (cb ^ ((r0&7)<<4))) = pk;
    }
    // readout: ro^T hn -> store (no atomics)
    bf16x8 Ro[2];
#pragma unroll
    for (int ks = 0; ks < 2; ++ks)
        Ro[ks] = *(const bf16x8*)(wROP_l + (ks*64 + lane)*8);
    f32x4 rb4 = *(const f32x4*)(rob_l + (lk<<2));
    bf16x8 Hf[2];
#pragma unroll
    for (int ks = 0; ks < 2; ++ks) {
        int kb = ks*64 + lk*16;
        Hf[ks] = *(const bf16x8*)((const char*)sA + r0*128 + (kb ^ ((r0&7)<<4)));
    }
    f32x4 r4 = {0,0,0,0};
    r4 = MFMA16(Ro[0], Hf[0], r4);
    r4 = MFMA16(Ro[1], Hf[1], r4);
#pragma unroll
    for (int r = 0; r < 4; ++r) r4[r] += rb4[r];
    if (valid) *(f32x4*)(rout + (size_t)grow*16 + (lk<<2)) = r4;
}

// ---------------------------------------------------------------------------
// Pool: out[batch[n]][j] += (sum_p rout0+rout1) / 20
// ---------------------------------------------------------------------------
__global__ __launch_bounds__(256) void k_pool(
    const float* __restrict__ r0, const float* __restrict__ r1,
    const int* __restrict__ batch, float* __restrict__ out)
{
    int t = blockIdx.x * 256 + threadIdx.x;
    if (t >= N_ * 16) return;
    int n = t >> 4, j = t & 15;
    float s = 0.0f;
#pragma unroll
    for (int p = 0; p < O_; ++p)
        s += r0[(n*O_ + p)*16 + j] + r1[(n*O_ + p)*16 + j];
    atomicAdd(&out[batch[n]*16 + j], s * (1.0f/20.0f));
}

// ---------------------------------------------------------------------------
extern "C" void kernel_launch(void* const* d_in, const int* in_sizes, int n_in,
                              void* d_out, int out_size, void* d_ws, size_t ws_size,
                              hipStream_t stream)
{
    const float* x    = (const float*)d_in[0];
    const float* pos  = (const float*)d_in[1];
    const float* bw1  = (const float*)d_in[2];
    const float* bb1  = (const float*)d_in[3];
    const float* bw2  = (const float*)d_in[4];
    const float* bb2  = (const float*)d_in[5];
    const float* fw1  = (const float*)d_in[6];
    const float* fb1  = (const float*)d_in[7];
    const float* fw2  = (const float*)d_in[8];
    const float* fb2  = (const float*)d_in[9];
    const float* embw = (const float*)d_in[10];
    const float* ckw  = (const float*)d_in[11];
    const float* cfw  = (const float*)d_in[12];
    const float* cb   = (const float*)d_in[13];
    const float* ns   = (const float*)d_in[14];
    const float* nbp  = (const float*)d_in[15];
    const float* l1w  = (const float*)d_in[16];
    const float* l1b  = (const float*)d_in[17];
    const float* l2w  = (const float*)d_in[18];
    const float* l2b  = (const float*)d_in[19];
    const float* row  = (const float*)d_in[20];
    const float* rob  = (const float*)d_in[21];
    const int*   ei   = (const int*)d_in[22];
    const int*   batch= (const int*)d_in[23];
    float* out = (float*)d_out;

    char* w = (char*)d_ws;
    size_t off = 0;
    auto alloc = [&](size_t bytes) -> char* {
        char* p = w + off; off += (bytes + 255) / 256 * 256; return p;
    };
    float* ori    = (float*)alloc(32 * 4);
    float* fkg    = (float*)alloc(2 * 6400 * 4);
    unsigned short* wW1P = (unsigned short*)alloc(4*512*2);
    unsigned short* wW2P = (unsigned short*)alloc(8*512*2);
    unsigned short* wCKP = (unsigned short*)alloc(2*8*512*2);
    unsigned short* wL1P = (unsigned short*)alloc(2*32*512*2);
    unsigned short* wL2P = (unsigned short*)alloc(2*32*512*2);
    unsigned short* wROP = (unsigned short*)alloc(2*2*512*2);
    float* h      = (float*)alloc((size_t)N_ * 640 * 4);
    float* h1     = (float*)alloc((size_t)N_ * 640 * 4);
    unsigned short* y = (unsigned short*)alloc((size_t)NROW_ * 64 * 2);
    float* rout0  = (float*)alloc((size_t)NROW_ * 16 * 4);
    float* rout1  = (float*)alloc((size_t)NROW_ * 16 * 4);
    float* crel   = (float*)alloc((size_t)E_ * 3 * 4);
    int*   counts = (int*)alloc((N_ + 1) * 4);
    int*   offs   = (int*)alloc((N_ + 1) * 4);
    int*   cursor = (int*)alloc((N_ + 1) * 4);
    int*   csend  = (int*)alloc((size_t)E_ * 4);
    int*   crecv  = (int*)alloc((size_t)E_ * 4);

    hipMemsetAsync(out, 0, (size_t)out_size * 4, stream);
    hipMemsetAsync(counts, 0, (N_ + 1) * 4, stream);

    k_small<<<1, 256, 0, stream>>>(bw1, fw1, fb1, fw2, fb2, cfw, bw2, ckw, l1w, l2w, row,
                                   ori, fkg, wW1P, wW2P, wCKP, wL1P, wL2P, wROP);
    k_embed<<<(N_ * 64 + 255) / 256, 256, 0, stream>>>(x, embw, h);
    k_hist<<<(E_ + 255) / 256, 256, 0, stream>>>(ei, counts);
    k_scan<<<1, 1024, 0, stream>>>(counts, offs, cursor);
    k_scatter<<<(E_ + 255) / 256, 256, 0, stream>>>(ei, pos, cursor, csend, crecv, crel);

    for (int l = 0; l < 2; ++l) {
        hipMemsetAsync(h1, 0, (size_t)N_ * 640 * 4, stream);
        k_msg<<<NITEM_ / 256, 256, 0, stream>>>(h, h1, csend, crecv, crel, ori,
                                                wW1P, wW2P, wCKP + l*4096,
                                                bb1, bb2);
        k_fln<<<625, 256, 0, stream>>>(h1, fkg + l*6400, cb + l*64, ns + l*64, nbp + l*64, y);
        k_mlp<<<(NROW_ + 63) / 64, 256, 0, stream>>>(y, h, (l == 0 ? rout0 : rout1),
                                                     wL1P + l*16384, l1b + l*256,
                                                     wL2P + l*16384, l2b + l*64,
                                                     wROP + l*1024, rob + l*16);
    }
    k_pool<<<(N_ * 16 + 255) / 256, 256, 0, stream>>>(rout0, rout1, batch, out);
}

// Round 6
// 478.640 us; speedup vs baseline: 20.7602x; 1.1208x over previous
//
#include <hip/hip_runtime.h>
#include <math.h>

#define N_   10000
#define E_   80000
#define O_   10
#define B_   16
#define OUT_ 16
#define NROW_ (N_*O_)    // 100000
#define NITEM_ (E_*O_)   // 800000

typedef __attribute__((ext_vector_type(8))) short bf16x8;
typedef __attribute__((ext_vector_type(4))) short bf16x4;
typedef __attribute__((ext_vector_type(4))) float f32x4;

#define MFMA16(a,b,c) __builtin_amdgcn_mfma_f32_16x16x32_bf16(a,b,c,0,0,0)

__device__ __forceinline__ float gelu_f(float x) {
    // tanh-gelu via exp2 + rcp (quarter-rate trans x2, 5 VALU)
    float u = fmaf(0.044715f, x * x, 1.0f);
    float e = __builtin_amdgcn_exp2f(2.3022083f * x * u);
    float r = __builtin_amdgcn_rcpf(e + 1.0f);
    return fmaf(-x, r, x);
}

__device__ __forceinline__ unsigned short f2bf(float f) {
    union { float f; unsigned int u; } v; v.f = f;
    unsigned int r = v.u + 0x7FFFu + ((v.u >> 16) & 1u);
    return (unsigned short)(r >> 16);
}
__device__ __forceinline__ float bf2f(unsigned short u) {
    union { unsigned int u; float f; } v; v.u = ((unsigned int)u) << 16;
    return v.f;
}
__device__ __forceinline__ unsigned int cvtpk(float lo, float hi) {
    unsigned int r;
    asm("v_cvt_pk_bf16_f32 %0, %1, %2" : "=v"(r) : "v"(lo), "v"(hi));
    return r;
}
__device__ __forceinline__ bf16x4 pack4(float a, float b, float c, float d) {
    union { unsigned int u[2]; bf16x4 v; } z;
    z.u[0] = cvtpk(a, b);
    z.u[1] = cvtpk(c, d);
    return z.v;
}

// ---------------------------------------------------------------------------
// Precompute (1 block): orientations, folded basis_w1, fiber MLP -> fk (fp32),
// all weights frag-packed in MFMA A-fragment order (coalesced 16 B/lane loads).
// ---------------------------------------------------------------------------
__global__ __launch_bounds__(256) void k_small(
    const float* __restrict__ bw1,
    const float* __restrict__ fw1, const float* __restrict__ fb1,
    const float* __restrict__ fw2, const float* __restrict__ fb2,
    const float* __restrict__ cfw,
    const float* __restrict__ bw2, const float* __restrict__ ckw,
    const float* __restrict__ l1w, const float* __restrict__ l2w,
    const float* __restrict__ row_w,
    float* __restrict__ orig, float* __restrict__ fkg,
    unsigned short* __restrict__ wW1P, unsigned short* __restrict__ wW2P,
    unsigned short* __restrict__ wCKP, unsigned short* __restrict__ wL1P,
    unsigned short* __restrict__ wL2P, unsigned short* __restrict__ wROP)
{
    __shared__ float sOri[32];
    __shared__ float sHid[6400];
    __shared__ float sFkb[6400];
    __shared__ float sW1f[14*64];
    int tid = threadIdx.x;
    if (tid < O_) {
        float i = (float)tid + 0.5f;
        float phi = acosf(1.0f - 2.0f * i / (float)O_);
        float theta = 3.14159265358979323846f * (1.0f + 2.2360679774997896964f) * i;
        float sp = sinf(phi);
        float v0 = cosf(theta) * sp, v1 = sinf(theta) * sp, v2 = cosf(phi);
        sOri[tid*3+0] = v0; sOri[tid*3+1] = v1; sOri[tid*3+2] = v2;
        orig[tid*3+0] = v0; orig[tid*3+1] = v1; orig[tid*3+2] = v2;
    }
    {
        const int map[30] = {0,1, 2,3,3,4, 5,6,6,7,6,7,7,8,
                             9,10,10,11,10,11,11,12, 10,11,11,12, 11,12,12,13};
        for (int idx = tid; idx < 14*64; idx += 256) {
            int mono = idx >> 6, c = idx & 63;
            float s = 0.0f;
            for (int p = 0; p < 30; ++p) if (map[p] == mono) s += bw1[p*64 + c];
            sW1f[idx] = s;
        }
    }
    __syncthreads();
    // ---- frag-packed weights ----
    for (int idx = tid; idx < 4*512; idx += 256) {
        int t = idx >> 9, rem = idx & 511;
        int ln = rem >> 3, j = rem & 7;
        int row = t*16 + (ln & 15);
        int k = (ln >> 4)*8 + j;
        wW1P[idx] = f2bf(k < 14 ? sW1f[k*64 + row] : 0.0f);
    }
    for (int idx = tid; idx < 8*512; idx += 256) {
        int t = idx >> 9, rem = idx & 511;
        int mt = t >> 1, ks = t & 1;
        int ln = rem >> 3, j = rem & 7;
        int row = mt*16 + (ln & 15);
        int k = ks*32 + (ln >> 4)*8 + j;
        wW2P[idx] = f2bf(bw2[k*64 + row]);
    }
    for (int idx = tid; idx < 2*8*512; idx += 256) {
        int l = idx >> 12, r2 = idx & 4095;
        int t = r2 >> 9, rem = r2 & 511;
        int mt = t >> 1, ks = t & 1;
        int ln = rem >> 3, j = rem & 7;
        int row = mt*16 + (ln & 15);
        int k = ks*32 + (ln >> 4)*8 + j;
        wCKP[idx] = f2bf(ckw[l*4096 + k*64 + row]);
    }
    for (int idx = tid; idx < 2*32*512; idx += 256) {
        int l = idx >> 14, r2 = idx & 16383;
        int t = r2 >> 9, rem = r2 & 511;
        int mt = t >> 1, ks = t & 1;
        int ln = rem >> 3, j = rem & 7;
        int row = mt*16 + (ln & 15);
        int k = ks*32 + (ln >> 4)*8 + j;
        wL1P[idx] = f2bf(l1w[l*16384 + k*256 + row]);
    }
    for (int idx = tid; idx < 2*32*512; idx += 256) {
        int l = idx >> 14, r2 = idx & 16383;
        int t = r2 >> 9, rem = r2 & 511;
        int mt2 = t >> 3, ksg = t & 7;
        int ln = rem >> 3, j = rem & 7;
        int row = mt2*16 + (ln & 15);
        int k = ksg*32 + (ln >> 4)*8 + j;
        wL2P[idx] = f2bf(l2w[l*16384 + k*64 + row]);
    }
    for (int idx = tid; idx < 2*2*512; idx += 256) {
        int l = idx >> 10, r2 = idx & 1023;
        int ks = r2 >> 9, rem = r2 & 511;
        int ln = rem >> 3, j = rem & 7;
        int row = ln & 15;
        int k = ks*32 + (ln >> 4)*8 + j;
        wROP[idx] = f2bf(row_w[l*1024 + k*16 + row]);
    }
    // ---- fiber basis MLP -> fkg (fp32) ----
    for (int it = tid; it < 6400; it += 256) {
        int pr = it >> 6, c = it & 63;
        int i = pr / O_, j = pr % O_;
        float a = sOri[i*3+0]*sOri[j*3+0] + sOri[i*3+1]*sOri[j*3+1] + sOri[i*3+2]*sOri[j*3+2];
        float f1 = a, f2 = a*a, f3 = f2*a, f4 = f3*a;
        float v = fb1[c];
        v = fmaf(f1, fw1[0*64+c], v);
        v = fmaf(f2, fw1[1*64+c], v);
        v = fmaf(f3, fw1[2*64+c], v);
        v = fmaf(f4, fw1[3*64+c], v);
        sHid[it] = gelu_f(v);
    }
    __syncthreads();
    for (int it = tid; it < 6400; it += 256) {
        int pr = it >> 6, c = it & 63;
        float v = fb2[c];
        for (int b = 0; b < 64; ++b) v = fmaf(sHid[pr*64+b], fw2[b*64+c], v);
        sFkb[it] = gelu_f(v);
    }
    __syncthreads();
    for (int l = 0; l < 2; ++l)
        for (int it = tid; it < 6400; it += 256) {
            int pr = it >> 6, c = it & 63;
            float v = 0.0f;
            for (int b = 0; b < 64; ++b) v = fmaf(sFkb[pr*64+b], cfw[l*4096 + b*64 + c], v);
            fkg[l*6400 + it] = v;
        }
}

// ---------------------------------------------------------------------------
// Embed: h[n][o][c] fp32 broadcast + bf16 gather table hbf0[n][c]
// ---------------------------------------------------------------------------
__global__ __launch_bounds__(256) void k_embed(
    const float* __restrict__ x, const float* __restrict__ ew,
    float* __restrict__ hg, unsigned short* __restrict__ hbf0)
{
    int t = blockIdx.x * 256 + threadIdx.x;
    if (t >= N_ * 64) return;
    int n = t >> 6, c = t & 63;
    float v = 0.0f;
#pragma unroll
    for (int k = 0; k < 16; ++k) v = fmaf(x[n*16+k], ew[k*64+c], v);
    int base = n * 640 + c;
#pragma unroll
    for (int o = 0; o < O_; ++o) hg[base + o*64] = v;
    hbf0[t] = f2bf(v);
}

// ---------------------------------------------------------------------------
__global__ __launch_bounds__(256) void k_hist(const int* __restrict__ ei, int* __restrict__ counts)
{
    int e = blockIdx.x * 256 + threadIdx.x;
    if (e < E_) atomicAdd(&counts[ei[E_ + e]], 1);
}

__global__ __launch_bounds__(1024) void k_scan(
    const int* __restrict__ counts, int* __restrict__ offs, int* __restrict__ cursor)
{
    __shared__ int part[1024];
    int t = threadIdx.x;
    const int CH = 10;
    int base_i = t * CH;
    int s = 0;
#pragma unroll
    for (int i = 0; i < CH; ++i) { int idx = base_i + i; if (idx < N_) s += counts[idx]; }
    part[t] = s;
    __syncthreads();
    for (int off = 1; off < 1024; off <<= 1) {
        int v = (t >= off) ? part[t - off] : 0;
        __syncthreads();
        part[t] += v;
        __syncthreads();
    }
    int run = (t > 0) ? part[t - 1] : 0;
#pragma unroll
    for (int i = 0; i < CH; ++i) {
        int idx = base_i + i;
        if (idx < N_) { offs[idx] = run; cursor[idx] = run; run += counts[idx]; }
    }
    if (t == 1023) offs[N_] = run;
}

__global__ __launch_bounds__(256) void k_scatter(
    const int* __restrict__ ei, const float* __restrict__ pos,
    int* __restrict__ cursor, int* __restrict__ csend, int* __restrict__ crecv,
    float* __restrict__ crel)
{
    int e = blockIdx.x * 256 + threadIdx.x;
    if (e >= E_) return;
    int s = ei[e], r = ei[E_ + e];
    int slot = atomicAdd(&cursor[r], 1);
    csend[slot] = s;
    crecv[slot] = r;
    crel[slot*3+0] = pos[s*3+0] - pos[r*3+0];
    crel[slot*3+1] = pos[s*3+1] - pos[r*3+1];
    crel[slot*3+2] = pos[s*3+2] - pos[r*3+2];
}

// ---------------------------------------------------------------------------
// MFMA stage: bias via C-init, gelu + cvt_pk epilogue.
// ---------------------------------------------------------------------------
template<int KS, bool BIAS, bool GELU>
__device__ __forceinline__ void mfma_stageP(
    unsigned short* sData, const unsigned short* __restrict__ Wp,
    const float* __restrict__ bias, int rbase, int lane)
{
    const int lm = lane & 15, lk = lane >> 4;
    bf16x8 Bf[4][KS];
#pragma unroll
    for (int nt = 0; nt < 4; ++nt)
#pragma unroll
        for (int ks = 0; ks < KS; ++ks) {
            int r = rbase + nt*16 + lm;
            int kb = ks*64 + lk*16;
            Bf[nt][ks] = *(const bf16x8*)((const char*)sData + r*128 + (kb ^ ((r&7)<<4)));
        }
#pragma unroll
    for (int mt = 0; mt < 4; ++mt) {
        bf16x8 Af[KS];
#pragma unroll
        for (int ks = 0; ks < KS; ++ks)
            Af[ks] = *(const bf16x8*)(Wp + ((mt*KS + ks)*64 + lane)*8);
        f32x4 b4 = {0,0,0,0};
        if (BIAS) b4 = *(const f32x4*)(bias + mt*16 + (lk<<2));
#pragma unroll
        for (int nt = 0; nt < 4; ++nt) {
            f32x4 acc = b4;
#pragma unroll
            for (int ks = 0; ks < KS; ++ks) acc = MFMA16(Af[ks], Bf[nt][ks], acc);
            float v0 = acc[0], v1 = acc[1], v2 = acc[2], v3 = acc[3];
            if (GELU) { v0 = gelu_f(v0); v1 = gelu_f(v1); v2 = gelu_f(v2); v3 = gelu_f(v3); }
            bf16x4 pk = pack4(v0, v1, v2, v3);
            int rr = rbase + nt*16 + lm;
            int cb = mt*32 + (lk<<3);
            *(bf16x4*)((char*)sData + rr*128 + (cb ^ ((rr&7)<<4))) = pk;
        }
    }
}

// ---------------------------------------------------------------------------
// Message passing: 128 items/block (2 waves, 16 KB LDS -> 10 blocks/CU),
// barrier-free.  L0: gather from hbf0[n][c] (1.28 MB, L2-hot, o-independent);
// L1: gather from hbf[n*10+o][c] (bf16).
// ---------------------------------------------------------------------------
template<bool L0>
__global__ __launch_bounds__(128) void k_msg(
    const unsigned short* __restrict__ hbf, float* __restrict__ h1g,
    const int* __restrict__ csend, const int* __restrict__ crecv,
    const float* __restrict__ crel, const float* __restrict__ ori,
    const unsigned short* __restrict__ wW1P, const unsigned short* __restrict__ wW2P,
    const unsigned short* __restrict__ wCKP_l,
    const float* __restrict__ bb1, const float* __restrict__ bb2)
{
    __shared__ unsigned short sData[128*64];
    const int tid = threadIdx.x;
    const int lane = tid & 63, wv = tid >> 6;
    const int item = blockIdx.x * 128 + tid;
    const int slot = item / 10;
    const int oo = item - slot * 10;
    const int snd = csend[slot];
    const int rcv = crecv[slot];
    {
        float r0 = crel[slot*3+0], r1 = crel[slot*3+1], r2 = crel[slot*3+2];
        float o0 = ori[oo*3+0], o1 = ori[oo*3+1], o2 = ori[oo*3+2];
        float a = r0*o0 + r1*o1 + r2*o2;
        float p0 = fmaf(-a, o0, r0), p1 = fmaf(-a, o1, r1), p2 = fmaf(-a, o2, r2);
        float b = sqrtf(p0*p0 + p1*p1 + p2*p2);
        float a2 = a*a, b2 = b*b, ab = a*b;
        float m[14];
        m[0]=a; m[1]=b; m[2]=a2; m[3]=ab; m[4]=b2;
        m[5]=a2*a; m[6]=a2*b; m[7]=a*b2; m[8]=b2*b;
        m[9]=a2*a2; m[10]=a2*ab; m[11]=a2*b2; m[12]=ab*b2; m[13]=b2*b2;
        unsigned int pk[16];
#pragma unroll
        for (int j = 0; j < 7; ++j) pk[j] = cvtpk(m[2*j], m[2*j+1]);
#pragma unroll
        for (int j = 7; j < 16; ++j) pk[j] = 0;
        int r = tid;
#pragma unroll
        for (int q = 0; q < 4; ++q) {
            int cb = q*16;
            *(f32x4*)((char*)sData + r*128 + (cb ^ ((r&7)<<4))) = ((const f32x4*)pk)[q];
        }
    }
    const int rbase = wv * 64;
    mfma_stageP<1, true,  true >(sData, wW1P,   bb1, rbase, lane);
    mfma_stageP<2, true,  true >(sData, wW2P,   bb2, rbase, lane);
    mfma_stageP<2, false, false>(sData, wCKP_l, (const float*)0, rbase, lane);

    // ---- scatter tail ----
    const int myaddr = L0 ? (snd * 64) : ((snd * 10 + oo) * 64);
    int prevr = __shfl_up(rcv, 1);
    unsigned long long bmask = __ballot(lane > 0 && rcv != prevr);
    const unsigned short* hb = hbf + lane;
    float a0=0,a1c=0,a2c=0,a3c=0,a4c=0,a5c=0,a6c=0,a7c=0,a8c=0,a9c=0;
    int cur = __builtin_amdgcn_readfirstlane(rcv);
    int soi = (blockIdx.x * 128 + rbase) % 10;
#define FLUSH_RUN(R) { float* bp = h1g + (R)*640 + lane; \
    atomicAdd(bp+0,a0); atomicAdd(bp+64,a1c); atomicAdd(bp+128,a2c); atomicAdd(bp+192,a3c); \
    atomicAdd(bp+256,a4c); atomicAdd(bp+320,a5c); atomicAdd(bp+384,a6c); atomicAdd(bp+448,a7c); \
    atomicAdd(bp+512,a8c); atomicAdd(bp+576,a9c); \
    a0=a1c=a2c=a3c=a4c=a5c=a6c=a7c=a8c=a9c=0.0f; }
#pragma unroll
    for (int ch = 0; ch < 4; ++ch) {
        unsigned short hvu[16];
        float kcv[16];
#pragma unroll
        for (int j = 0; j < 16; ++j) {
            const int i = ch*16 + j;
            hvu[j] = hb[__builtin_amdgcn_readlane(myaddr, i)];
            const int rr = rbase + i;
            kcv[j] = bf2f(*(const unsigned short*)((const char*)sData + rr*128 + ((lane*2) ^ ((rr&7)<<4))));
        }
#pragma unroll
        for (int j = 0; j < 16; ++j) {
            const int i = ch*16 + j;
            if (bmask & (1ull << i)) { FLUSH_RUN(cur); cur = __builtin_amdgcn_readlane(rcv, i); }
            float mv = kcv[j] * bf2f(hvu[j]);
            if      (soi == 0) a0  += mv;
            else if (soi == 1) a1c += mv;
            else if (soi == 2) a2c += mv;
            else if (soi == 3) a3c += mv;
            else if (soi == 4) a4c += mv;
            else if (soi == 5) a5c += mv;
            else if (soi == 6) a6c += mv;
            else if (soi == 7) a7c += mv;
            else if (soi == 8) a8c += mv;
            else               a9c += mv;
            soi = (soi == 9) ? 0 : soi + 1;
        }
    }
    FLUSH_RUN(cur);
#undef FLUSH_RUN
}

// ---------------------------------------------------------------------------
// Fused fiber conv + LayerNorm -> y bf16.  Grid-strided; wave per node.
// ---------------------------------------------------------------------------
__global__ __launch_bounds__(256) void k_fln(
    const float* __restrict__ h1, const float* __restrict__ fkg,
    const float* __restrict__ cb, const float* __restrict__ ns,
    const float* __restrict__ nb, unsigned short* __restrict__ y)
{
    __shared__ float sFK[6400];
    const int tid = threadIdx.x;
    for (int i = tid; i < 6400; i += 256) sFK[i] = fkg[i];
    __syncthreads();
    const int lane = tid & 63, wv = tid >> 6;
    float cbv = cb[lane], nsv = ns[lane], nbv = nb[lane];
    for (int g4 = blockIdx.x; g4 < N_/4; g4 += gridDim.x) {
        const int n = g4 * 4 + wv;
        float hr[10];
#pragma unroll
        for (int o = 0; o < O_; ++o) hr[o] = h1[n*640 + o*64 + lane];
#pragma unroll
        for (int p = 0; p < O_; ++p) {
            float v = 0.0f;
#pragma unroll
            for (int o = 0; o < O_; ++o) v = fmaf(hr[o], sFK[(p*O_+o)*64 + lane], v);
            v = v * 0.1f + cbv;
            float s = v, q = v*v;
#pragma unroll
            for (int d = 1; d < 64; d <<= 1) { s += __shfl_xor(s, d); q += __shfl_xor(q, d); }
            float mu = s * (1.0f/64.0f);
            float var = q * (1.0f/64.0f) - mu*mu;
            float rs = rsqrtf(var + 1e-6f);
            float yv = (v - mu) * rs * nsv + nbv;
            y[(n*O_ + p)*64 + lane] = f2bf(yv);
        }
    }
}

// ---------------------------------------------------------------------------
// MLP: 64 rows/block, frag-packed weights, readout stored.  Writes hn back
// into ybuf (bf16) in-place (block-private rows) -> next layer's gather table.
// ---------------------------------------------------------------------------
__global__ __launch_bounds__(256, 4) void k_mlp(
    unsigned short* ybuf, float* __restrict__ hg, float* __restrict__ rout,
    const unsigned short* __restrict__ wL1P_l, const float* __restrict__ l1b_l,
    const unsigned short* __restrict__ wL2P_l, const float* __restrict__ l2b_l,
    const unsigned short* __restrict__ wROP_l, const float* __restrict__ rob_l)
{
    __shared__ unsigned short sA[64*64];
    const int tid = threadIdx.x;
    const int lane = tid & 63, wv = tid >> 6;
    const int rb = blockIdx.x * 64;
#pragma unroll
    for (int i = tid*16; i < 64*128; i += 256*16) {
        int r = i >> 7, off = i & 127;
        int grow = rb + r; if (grow >= NROW_) grow = NROW_ - 1;
        *(f32x4*)((char*)sA + r*128 + (off ^ ((r&7)<<4))) =
            *(const f32x4*)((const char*)ybuf + (size_t)grow*128 + off);
    }
    __syncthreads();
    const int lm = lane & 15, lk = lane >> 4;
    const int r0 = wv*16 + lm;
    bf16x8 Yf[2];
#pragma unroll
    for (int ks = 0; ks < 2; ++ks) {
        int kb = ks*64 + lk*16;
        Yf[ks] = *(const bf16x8*)((const char*)sA + r0*128 + (kb ^ ((r0&7)<<4)));
    }
    f32x4 acc2[4];
#pragma unroll
    for (int m = 0; m < 4; ++m) acc2[m] = *(const f32x4*)(l2b_l + m*16 + (lk<<2));
#pragma unroll
    for (int jb = 0; jb < 4; ++jb) {
#pragma unroll
        for (int mt = 0; mt < 4; ++mt) {
            bf16x8 A1[2];
#pragma unroll
            for (int ks = 0; ks < 2; ++ks)
                A1[ks] = *(const bf16x8*)(wL1P_l + (((jb*4 + mt)*2 + ks)*64 + lane)*8);
            f32x4 acc = *(const f32x4*)(l1b_l + jb*64 + mt*16 + (lk<<2));
            acc = MFMA16(A1[0], Yf[0], acc);
            acc = MFMA16(A1[1], Yf[1], acc);
            bf16x4 pk = pack4(gelu_f(acc[0]), gelu_f(acc[1]), gelu_f(acc[2]), gelu_f(acc[3]));
            int cb = mt*32 + (lk<<3);
            *(bf16x4*)((char*)sA + r0*128 + (cb ^ ((r0&7)<<4))) = pk;
        }
        bf16x8 Mf[2];
#pragma unroll
        for (int ks = 0; ks < 2; ++ks) {
            int kb = ks*64 + lk*16;
            Mf[ks] = *(const bf16x8*)((const char*)sA + r0*128 + (kb ^ ((r0&7)<<4)));
        }
#pragma unroll
        for (int mt2 = 0; mt2 < 4; ++mt2) {
            bf16x8 A2[2];
#pragma unroll
            for (int ks = 0; ks < 2; ++ks)
                A2[ks] = *(const bf16x8*)(wL2P_l + ((mt2*8 + jb*2 + ks)*64 + lane)*8);
            acc2[mt2] = MFMA16(A2[0], Mf[0], acc2[mt2]);
            acc2[mt2] = MFMA16(A2[1], Mf[1], acc2[mt2]);
        }
    }
    // epilogue: residual into h (fp32) + hn bf16 to LDS and to ybuf (next-layer gather)
    const int grow = rb + r0;
    const bool valid = grow < NROW_;
    const int growc = valid ? grow : (NROW_ - 1);
#pragma unroll
    for (int mt2 = 0; mt2 < 4; ++mt2) {
        f32x4 hv = *(const f32x4*)(hg + (size_t)growc*64 + mt2*16 + (lk<<2));
        f32x4 hn;
#pragma unroll
        for (int r = 0; r < 4; ++r) hn[r] = hv[r] + acc2[mt2][r];
        bf16x4 pk = pack4(hn[0], hn[1], hn[2], hn[3]);
        if (valid) {
            *(f32x4*)(hg + (size_t)grow*64 + mt2*16 + (lk<<2)) = hn;
            *(bf16x4*)((char*)ybuf + (size_t)grow*128 + (mt2*16 + (lk<<2))*2) = pk;
        }
        int cb = mt2*32 + (lk<<3);
        *(bf16x4*)((char*)sA + r0*128 + (cb ^ ((r0&7)<<4))) = pk;
    }
    // readout: ro^T hn -> store
    bf16x8 Ro[2];
#pragma unroll
    for (int ks = 0; ks < 2; ++ks)
        Ro[ks] = *(const bf16x8*)(wROP_l + (ks*64 + lane)*8);
    f32x4 r4 = *(const f32x4*)(rob_l + (lk<<2));
    bf16x8 Hf[2];
#pragma unroll
    for (int ks = 0; ks < 2; ++ks) {
        int kb = ks*64 + lk*16;
        Hf[ks] = *(const bf16x8*)((const char*)sA + r0*128 + (kb ^ ((r0&7)<<4)));
    }
    r4 = MFMA16(Ro[0], Hf[0], r4);
    r4 = MFMA16(Ro[1], Hf[1], r4);
    if (valid) *(f32x4*)(rout + (size_t)grow*16 + (lk<<2)) = r4;
}

// ---------------------------------------------------------------------------
__global__ __launch_bounds__(256) void k_pool(
    const float* __restrict__ r0, const float* __restrict__ r1,
    const int* __restrict__ batch, float* __restrict__ out)
{
    int t = blockIdx.x * 256 + threadIdx.x;
    if (t >= N_ * 16) return;
    int n = t >> 4, j = t & 15;
    float s = 0.0f;
#pragma unroll
    for (int p = 0; p < O_; ++p)
        s += r0[(n*O_ + p)*16 + j] + r1[(n*O_ + p)*16 + j];
    atomicAdd(&out[batch[n]*16 + j], s * (1.0f/20.0f));
}

// ---------------------------------------------------------------------------
extern "C" void kernel_launch(void* const* d_in, const int* in_sizes, int n_in,
                              void* d_out, int out_size, void* d_ws, size_t ws_size,
                              hipStream_t stream)
{
    const float* x    = (const float*)d_in[0];
    const float* pos  = (const float*)d_in[1];
    const float* bw1  = (const float*)d_in[2];
    const float* bb1  = (const float*)d_in[3];
    const float* bw2  = (const float*)d_in[4];
    const float* bb2  = (const float*)d_in[5];
    const float* fw1  = (const float*)d_in[6];
    const float* fb1  = (const float*)d_in[7];
    const float* fw2  = (const float*)d_in[8];
    const float* fb2  = (const float*)d_in[9];
    const float* embw = (const float*)d_in[10];
    const float* ckw  = (const float*)d_in[11];
    const float* cfw  = (const float*)d_in[12];
    const float* cb   = (const float*)d_in[13];
    const float* ns   = (const float*)d_in[14];
    const float* nbp  = (const float*)d_in[15];
    const float* l1w  = (const float*)d_in[16];
    const float* l1b  = (const float*)d_in[17];
    const float* l2w  = (const float*)d_in[18];
    const float* l2b  = (const float*)d_in[19];
    const float* row  = (const float*)d_in[20];
    const float* rob  = (const float*)d_in[21];
    const int*   ei   = (const int*)d_in[22];
    const int*   batch= (const int*)d_in[23];
    float* out = (float*)d_out;

    char* w = (char*)d_ws;
    size_t off = 0;
    auto alloc = [&](size_t bytes) -> char* {
        char* p = w + off; off += (bytes + 255) / 256 * 256; return p;
    };
    float* ori    = (float*)alloc(32 * 4);
    float* fkg    = (float*)alloc(2 * 6400 * 4);
    unsigned short* wW1P = (unsigned short*)alloc(4*512*2);
    unsigned short* wW2P = (unsigned short*)alloc(8*512*2);
    unsigned short* wCKP = (unsigned short*)alloc(2*8*512*2);
    unsigned short* wL1P = (unsigned short*)alloc(2*32*512*2);
    unsigned short* wL2P = (unsigned short*)alloc(2*32*512*2);
    unsigned short* wROP = (unsigned short*)alloc(2*2*512*2);
    float* h      = (float*)alloc((size_t)N_ * 640 * 4);
    float* h1     = (float*)alloc((size_t)N_ * 640 * 4);
    unsigned short* y = (unsigned short*)alloc((size_t)NROW_ * 64 * 2);  // y / hbf alias
    unsigned short* hbf0 = (unsigned short*)alloc((size_t)N_ * 64 * 2);
    float* rout0  = (float*)alloc((size_t)NROW_ * 16 * 4);
    float* rout1  = (float*)alloc((size_t)NROW_ * 16 * 4);
    float* crel   = (float*)alloc((size_t)E_ * 3 * 4);
    int*   counts = (int*)alloc((N_ + 1) * 4);
    int*   offs   = (int*)alloc((N_ + 1) * 4);
    int*   cursor = (int*)alloc((N_ + 1) * 4);
    int*   csend  = (int*)alloc((size_t)E_ * 4);
    int*   crecv  = (int*)alloc((size_t)E_ * 4);

    hipMemsetAsync(out, 0, (size_t)out_size * 4, stream);
    hipMemsetAsync(counts, 0, (N_ + 1) * 4, stream);

    k_small<<<1, 256, 0, stream>>>(bw1, fw1, fb1, fw2, fb2, cfw, bw2, ckw, l1w, l2w, row,
                                   ori, fkg, wW1P, wW2P, wCKP, wL1P, wL2P, wROP);
    k_embed<<<(N_ * 64 + 255) / 256, 256, 0, stream>>>(x, embw, h, hbf0);
    k_hist<<<(E_ + 255) / 256, 256, 0, stream>>>(ei, counts);
    k_scan<<<1, 1024, 0, stream>>>(counts, offs, cursor);
    k_scatter<<<(E_ + 255) / 256, 256, 0, stream>>>(ei, pos, cursor, csend, crecv, crel);

    for (int l = 0; l < 2; ++l) {
        hipMemsetAsync(h1, 0, (size_t)N_ * 640 * 4, stream);
        if (l == 0)
            k_msg<true><<<NITEM_ / 128, 128, 0, stream>>>(hbf0, h1, csend, crecv, crel, ori,
                                                          wW1P, wW2P, wCKP + l*4096, bb1, bb2);
        else
            k_msg<false><<<NITEM_ / 128, 128, 0, stream>>>(y, h1, csend, crecv, crel, ori,
                                                           wW1P, wW2P, wCKP + l*4096, bb1, bb2);
        k_fln<<<625, 256, 0, stream>>>(h1, fkg + l*6400, cb + l*64, ns + l*64, nbp + l*64, y);
        k_mlp<<<(NROW_ + 63) / 64, 256, 0, stream>>>(y, h, (l == 0 ? rout0 : rout1),
                                                     wL1P + l*16384, l1b + l*256,
                                                     wL2P + l*16384, l2b + l*64,
                                                     wROP + l*1024, rob + l*16);
    }
    k_pool<<<(N_ * 16 + 255) / 256, 256, 0, stream>>>(rout0, rout1, batch, out);
}

// Round 7
// 432.737 us; speedup vs baseline: 22.9623x; 1.1061x over previous
//
#include <hip/hip_runtime.h>
#include <math.h>

#define N_   10000
#define E_   80000
#define O_   10
#define B_   16
#define OUT_ 16
#define NROW_ (N_*O_)    // 100000
#define NITEM_ (E_*O_)   // 800000

typedef __attribute__((ext_vector_type(8))) short bf16x8;
typedef __attribute__((ext_vector_type(4))) short bf16x4;
typedef __attribute__((ext_vector_type(4))) float f32x4;

#define MFMA16(a,b,c) __builtin_amdgcn_mfma_f32_16x16x32_bf16(a,b,c,0,0,0)

__device__ __forceinline__ float gelu_f(float x) {
    float u = fmaf(0.044715f, x * x, 1.0f);
    float e = __builtin_amdgcn_exp2f(2.3022083f * x * u);
    float r = __builtin_amdgcn_rcpf(e + 1.0f);
    return fmaf(-x, r, x);
}

__device__ __forceinline__ unsigned short f2bf(float f) {
    union { float f; unsigned int u; } v; v.f = f;
    unsigned int r = v.u + 0x7FFFu + ((v.u >> 16) & 1u);
    return (unsigned short)(r >> 16);
}
__device__ __forceinline__ float bf2f(unsigned short u) {
    union { unsigned int u; float f; } v; v.u = ((unsigned int)u) << 16;
    return v.f;
}
__device__ __forceinline__ unsigned int cvtpk(float lo, float hi) {
    unsigned int r;
    asm("v_cvt_pk_bf16_f32 %0, %1, %2" : "=v"(r) : "v"(lo), "v"(hi));
    return r;
}
__device__ __forceinline__ bf16x4 pack4(float a, float b, float c, float d) {
    union { unsigned int u[2]; bf16x4 v; } z;
    z.u[0] = cvtpk(a, b);
    z.u[1] = cvtpk(c, d);
    return z.v;
}

__device__ __forceinline__ void fib_vec(int idx, float& vx, float& vy, float& vz) {
    float i = (float)idx + 0.5f;
    float phi = acosf(1.0f - 2.0f * i / (float)O_);
    float theta = 3.14159265358979323846f * (1.0f + 2.2360679774997896964f) * i;
    float sp = sinf(phi);
    vx = cosf(theta) * sp; vy = sinf(theta) * sp; vz = cosf(phi);
}

// ---------------------------------------------------------------------------
// Parallel weight frag-pack: one thread per output element.
//   P[((mt*KS+ks)*64 + lane)*8 + j] = WT[mt*16 + (lane&15)][ks*32 + (lane>>4)*8 + j]
// Ranges: [0,2048) W1 | [2048,6144) W2 | [6144,14336) CK | [14336,47104) L1 |
//         [47104,79872) L2 | [79872,81920) RO | [81920,81930) orientations.
// ---------------------------------------------------------------------------
__global__ __launch_bounds__(256) void k_pack(
    const float* __restrict__ bw1, const float* __restrict__ bw2,
    const float* __restrict__ ckw, const float* __restrict__ l1w,
    const float* __restrict__ l2w, const float* __restrict__ row_w,
    float* __restrict__ orig,
    unsigned short* __restrict__ wW1P, unsigned short* __restrict__ wW2P,
    unsigned short* __restrict__ wCKP, unsigned short* __restrict__ wL1P,
    unsigned short* __restrict__ wL2P, unsigned short* __restrict__ wROP)
{
    const int g = blockIdx.x * 256 + threadIdx.x;
    if (g < 2048) {                                   // W1 (folded): M=64,K=32
        int idx = g;
        int t = idx >> 9, rem = idx & 511;
        int ln = rem >> 3, j = rem & 7;
        int row = t*16 + (ln & 15);
        int k = (ln >> 4)*8 + j;
        float s = 0.0f;
        if (k < 14) {
            const int moff[14] = {0,1,2,3,5,6,7,10,13,14,15,19,25,29};
            const int mcnt[14] = {1,1,1,2,1,1,3,3,1,1,4,6,4,1};
            const int mlist[30] = {0,1,2,3,4,5,6,7,8,10,9,11,12,13,14,
                                   15,16,18,22,17,19,20,23,24,26,21,25,27,28,29};
            for (int q = 0; q < mcnt[k]; ++q) s += bw1[mlist[moff[k]+q]*64 + row];
        }
        wW1P[idx] = f2bf(s);
    } else if (g < 6144) {                            // W2: M=64,K=64
        int idx = g - 2048;
        int t = idx >> 9, rem = idx & 511;
        int mt = t >> 1, ks = t & 1;
        int ln = rem >> 3, j = rem & 7;
        int row = mt*16 + (ln & 15);
        int k = ks*32 + (ln >> 4)*8 + j;
        wW2P[idx] = f2bf(bw2[k*64 + row]);
    } else if (g < 14336) {                           // CK[l]: M=64,K=64
        int idx = g - 6144;
        int l = idx >> 12, r2 = idx & 4095;
        int t = r2 >> 9, rem = r2 & 511;
        int mt = t >> 1, ks = t & 1;
        int ln = rem >> 3, j = rem & 7;
        int row = mt*16 + (ln & 15);
        int k = ks*32 + (ln >> 4)*8 + j;
        wCKP[idx] = f2bf(ckw[l*4096 + k*64 + row]);
    } else if (g < 47104) {                           // L1[l]: M=256,K=64
        int idx = g - 14336;
        int l = idx >> 14, r2 = idx & 16383;
        int t = r2 >> 9, rem = r2 & 511;
        int mt = t >> 1, ks = t & 1;
        int ln = rem >> 3, j = rem & 7;
        int row = mt*16 + (ln & 15);
        int k = ks*32 + (ln >> 4)*8 + j;
        wL1P[idx] = f2bf(l1w[l*16384 + k*256 + row]);
    } else if (g < 79872) {                           // L2[l]: M=64,K=256
        int idx = g - 47104;
        int l = idx >> 14, r2 = idx & 16383;
        int t = r2 >> 9, rem = r2 & 511;
        int mt2 = t >> 3, ksg = t & 7;
        int ln = rem >> 3, j = rem & 7;
        int row = mt2*16 + (ln & 15);
        int k = ksg*32 + (ln >> 4)*8 + j;
        wL2P[idx] = f2bf(l2w[l*16384 + k*64 + row]);
    } else if (g < 81920) {                           // RO[l]: M=16,K=64
        int idx = g - 79872;
        int l = idx >> 10, r2 = idx & 1023;
        int ks = r2 >> 9, rem = r2 & 511;
        int ln = rem >> 3, j = rem & 7;
        int row = ln & 15;
        int k = ks*32 + (ln >> 4)*8 + j;
        wROP[idx] = f2bf(row_w[l*1024 + k*16 + row]);
    } else if (g < 81920 + O_) {                      // orientations
        int o = g - 81920;
        float vx, vy, vz;
        fib_vec(o, vx, vy, vz);
        orig[o*3+0] = vx; orig[o*3+1] = vy; orig[o*3+2] = vz;
    }
}

// ---------------------------------------------------------------------------
// Fiber-basis precompute: one wave per orientation pair (100 waves).
// hid/fkb rows bounce through wave-private LDS (lockstep-safe).
// ---------------------------------------------------------------------------
__global__ __launch_bounds__(256) void k_fibpre(
    const float* __restrict__ fw1, const float* __restrict__ fb1,
    const float* __restrict__ fw2, const float* __restrict__ fb2,
    const float* __restrict__ cfw, float* __restrict__ fkg)
{
    __shared__ float sRow[4][64];
    const int wv = threadIdx.x >> 6, lane = threadIdx.x & 63;
    const int pr = blockIdx.x * 4 + wv;
    if (pr >= 100) return;
    const int i = pr / O_, j = pr % O_;
    float ix, iy, iz, jx, jy, jz;
    fib_vec(i, ix, iy, iz);
    fib_vec(j, jx, jy, jz);
    float a = ix*jx + iy*jy + iz*jz;
    float a2 = a*a, a3 = a2*a, a4 = a3*a;
    float v = fb1[lane];
    v = fmaf(a,  fw1[0*64+lane], v);
    v = fmaf(a2, fw1[1*64+lane], v);
    v = fmaf(a3, fw1[2*64+lane], v);
    v = fmaf(a4, fw1[3*64+lane], v);
    sRow[wv][lane] = gelu_f(v);
    float acc = fb2[lane];
    for (int b = 0; b < 64; ++b) acc = fmaf(sRow[wv][b], fw2[b*64+lane], acc);
    sRow[wv][lane] = gelu_f(acc);          // lockstep within wave: safe overwrite
    for (int l = 0; l < 2; ++l) {
        float s = 0.0f;
        for (int b = 0; b < 64; ++b) s = fmaf(sRow[wv][b], cfw[l*4096 + b*64 + lane], s);
        fkg[l*6400 + pr*64 + lane] = s;
    }
}

// ---------------------------------------------------------------------------
// Embed: h[n][o][c] fp32 broadcast + bf16 gather table hbf0[n][c]
// ---------------------------------------------------------------------------
__global__ __launch_bounds__(256) void k_embed(
    const float* __restrict__ x, const float* __restrict__ ew,
    float* __restrict__ hg, unsigned short* __restrict__ hbf0)
{
    int t = blockIdx.x * 256 + threadIdx.x;
    if (t >= N_ * 64) return;
    int n = t >> 6, c = t & 63;
    float v = 0.0f;
#pragma unroll
    for (int k = 0; k < 16; ++k) v = fmaf(x[n*16+k], ew[k*64+c], v);
    int base = n * 640 + c;
#pragma unroll
    for (int o = 0; o < O_; ++o) hg[base + o*64] = v;
    hbf0[t] = f2bf(v);
}

// ---------------------------------------------------------------------------
__global__ __launch_bounds__(256) void k_hist(const int* __restrict__ ei, int* __restrict__ counts)
{
    int e = blockIdx.x * 256 + threadIdx.x;
    if (e < E_) atomicAdd(&counts[ei[E_ + e]], 1);
}

__global__ __launch_bounds__(1024) void k_scan(
    const int* __restrict__ counts, int* __restrict__ offs, int* __restrict__ cursor)
{
    __shared__ int part[1024];
    int t = threadIdx.x;
    const int CH = 10;
    int base_i = t * CH;
    int s = 0;
#pragma unroll
    for (int i = 0; i < CH; ++i) { int idx = base_i + i; if (idx < N_) s += counts[idx]; }
    part[t] = s;
    __syncthreads();
    for (int off = 1; off < 1024; off <<= 1) {
        int v = (t >= off) ? part[t - off] : 0;
        __syncthreads();
        part[t] += v;
        __syncthreads();
    }
    int run = (t > 0) ? part[t - 1] : 0;
#pragma unroll
    for (int i = 0; i < CH; ++i) {
        int idx = base_i + i;
        if (idx < N_) { offs[idx] = run; cursor[idx] = run; run += counts[idx]; }
    }
    if (t == 1023) offs[N_] = run;
}

__global__ __launch_bounds__(256) void k_scatter(
    const int* __restrict__ ei, const float* __restrict__ pos,
    int* __restrict__ cursor, int* __restrict__ csend, int* __restrict__ crecv,
    float* __restrict__ crel)
{
    int e = blockIdx.x * 256 + threadIdx.x;
    if (e >= E_) return;
    int s = ei[e], r = ei[E_ + e];
    int slot = atomicAdd(&cursor[r], 1);
    csend[slot] = s;
    crecv[slot] = r;
    crel[slot*3+0] = pos[s*3+0] - pos[r*3+0];
    crel[slot*3+1] = pos[s*3+1] - pos[r*3+1];
    crel[slot*3+2] = pos[s*3+2] - pos[r*3+2];
}

// ---------------------------------------------------------------------------
// MFMA stage: bias via C-init, gelu + cvt_pk epilogue.
// ---------------------------------------------------------------------------
template<int KS, bool BIAS, bool GELU>
__device__ __forceinline__ void mfma_stageP(
    unsigned short* sData, const unsigned short* __restrict__ Wp,
    const float* __restrict__ bias, int rbase, int lane)
{
    const int lm = lane & 15, lk = lane >> 4;
    bf16x8 Bf[4][KS];
#pragma unroll
    for (int nt = 0; nt < 4; ++nt)
#pragma unroll
        for (int ks = 0; ks < KS; ++ks) {
            int r = rbase + nt*16 + lm;
            int kb = ks*64 + lk*16;
            Bf[nt][ks] = *(const bf16x8*)((const char*)sData + r*128 + (kb ^ ((r&7)<<4)));
        }
#pragma unroll
    for (int mt = 0; mt < 4; ++mt) {
        bf16x8 Af[KS];
#pragma unroll
        for (int ks = 0; ks < KS; ++ks)
            Af[ks] = *(const bf16x8*)(Wp + ((mt*KS + ks)*64 + lane)*8);
        f32x4 b4 = {0,0,0,0};
        if (BIAS) b4 = *(const f32x4*)(bias + mt*16 + (lk<<2));
#pragma unroll
        for (int nt = 0; nt < 4; ++nt) {
            f32x4 acc = b4;
#pragma unroll
            for (int ks = 0; ks < KS; ++ks) acc = MFMA16(Af[ks], Bf[nt][ks], acc);
            float v0 = acc[0], v1 = acc[1], v2 = acc[2], v3 = acc[3];
            if (GELU) { v0 = gelu_f(v0); v1 = gelu_f(v1); v2 = gelu_f(v2); v3 = gelu_f(v3); }
            bf16x4 pk = pack4(v0, v1, v2, v3);
            int rr = rbase + nt*16 + lm;
            int cb = mt*32 + (lk<<3);
            *(bf16x4*)((char*)sData + rr*128 + (cb ^ ((rr&7)<<4))) = pk;
        }
    }
}

// ---------------------------------------------------------------------------
// Message passing: 128 items/block (2 waves, 16 KB LDS), barrier-free.
// L0: gather from hbf0[n][c] (1.28 MB, L2-hot); L1: gather from y[n*10+o][c].
// ---------------------------------------------------------------------------
template<bool L0>
__global__ __launch_bounds__(128) void k_msg(
    const unsigned short* __restrict__ hbf, float* __restrict__ h1g,
    const int* __restrict__ csend, const int* __restrict__ crecv,
    const float* __restrict__ crel, const float* __restrict__ ori,
    const unsigned short* __restrict__ wW1P, const unsigned short* __restrict__ wW2P,
    const unsigned short* __restrict__ wCKP_l,
    const float* __restrict__ bb1, const float* __restrict__ bb2)
{
    __shared__ unsigned short sData[128*64];
    const int tid = threadIdx.x;
    const int lane = tid & 63, wv = tid >> 6;
    const int item = blockIdx.x * 128 + tid;
    const int slot = item / 10;
    const int oo = item - slot * 10;
    const int snd = csend[slot];
    const int rcv = crecv[slot];
    {
        float r0 = crel[slot*3+0], r1 = crel[slot*3+1], r2 = crel[slot*3+2];
        float o0 = ori[oo*3+0], o1 = ori[oo*3+1], o2 = ori[oo*3+2];
        float a = r0*o0 + r1*o1 + r2*o2;
        float p0 = fmaf(-a, o0, r0), p1 = fmaf(-a, o1, r1), p2 = fmaf(-a, o2, r2);
        float b = sqrtf(p0*p0 + p1*p1 + p2*p2);
        float a2 = a*a, b2 = b*b, ab = a*b;
        float m[14];
        m[0]=a; m[1]=b; m[2]=a2; m[3]=ab; m[4]=b2;
        m[5]=a2*a; m[6]=a2*b; m[7]=a*b2; m[8]=b2*b;
        m[9]=a2*a2; m[10]=a2*ab; m[11]=a2*b2; m[12]=ab*b2; m[13]=b2*b2;
        unsigned int pk[16];
#pragma unroll
        for (int j = 0; j < 7; ++j) pk[j] = cvtpk(m[2*j], m[2*j+1]);
#pragma unroll
        for (int j = 7; j < 16; ++j) pk[j] = 0;
        int r = tid;
#pragma unroll
        for (int q = 0; q < 4; ++q) {
            int cb = q*16;
            *(f32x4*)((char*)sData + r*128 + (cb ^ ((r&7)<<4))) = ((const f32x4*)pk)[q];
        }
    }
    const int rbase = wv * 64;
    mfma_stageP<1, true,  true >(sData, wW1P,   bb1, rbase, lane);
    mfma_stageP<2, true,  true >(sData, wW2P,   bb2, rbase, lane);
    mfma_stageP<2, false, false>(sData, wCKP_l, (const float*)0, rbase, lane);

    // ---- scatter tail ----
    const int myaddr = L0 ? (snd * 64) : ((snd * 10 + oo) * 64);
    int prevr = __shfl_up(rcv, 1);
    unsigned long long bmask = __ballot(lane > 0 && rcv != prevr);
    const unsigned short* hb = hbf + lane;
    float a0=0,a1c=0,a2c=0,a3c=0,a4c=0,a5c=0,a6c=0,a7c=0,a8c=0,a9c=0;
    int cur = __builtin_amdgcn_readfirstlane(rcv);
    int soi = (blockIdx.x * 128 + rbase) % 10;
#define FLUSH_RUN(R) { float* bp = h1g + (R)*640 + lane; \
    atomicAdd(bp+0,a0); atomicAdd(bp+64,a1c); atomicAdd(bp+128,a2c); atomicAdd(bp+192,a3c); \
    atomicAdd(bp+256,a4c); atomicAdd(bp+320,a5c); atomicAdd(bp+384,a6c); atomicAdd(bp+448,a7c); \
    atomicAdd(bp+512,a8c); atomicAdd(bp+576,a9c); \
    a0=a1c=a2c=a3c=a4c=a5c=a6c=a7c=a8c=a9c=0.0f; }
#pragma unroll
    for (int ch = 0; ch < 4; ++ch) {
        unsigned short hvu[16];
        float kcv[16];
#pragma unroll
        for (int j = 0; j < 16; ++j) {
            const int i = ch*16 + j;
            hvu[j] = hb[__builtin_amdgcn_readlane(myaddr, i)];
            const int rr = rbase + i;
            kcv[j] = bf2f(*(const unsigned short*)((const char*)sData + rr*128 + ((lane*2) ^ ((rr&7)<<4))));
        }
#pragma unroll
        for (int j = 0; j < 16; ++j) {
            const int i = ch*16 + j;
            if (bmask & (1ull << i)) { FLUSH_RUN(cur); cur = __builtin_amdgcn_readlane(rcv, i); }
            float mv = kcv[j] * bf2f(hvu[j]);
            if      (soi == 0) a0  += mv;
            else if (soi == 1) a1c += mv;
            else if (soi == 2) a2c += mv;
            else if (soi == 3) a3c += mv;
            else if (soi == 4) a4c += mv;
            else if (soi == 5) a5c += mv;
            else if (soi == 6) a6c += mv;
            else if (soi == 7) a7c += mv;
            else if (soi == 8) a8c += mv;
            else               a9c += mv;
            soi = (soi == 9) ? 0 : soi + 1;
        }
    }
    FLUSH_RUN(cur);
#undef FLUSH_RUN
}

// ---------------------------------------------------------------------------
// Fused fiber conv + LayerNorm -> y bf16.  Grid-strided; wave per node.
// ---------------------------------------------------------------------------
__global__ __launch_bounds__(256) void k_fln(
    const float* __restrict__ h1, const float* __restrict__ fkg,
    const float* __restrict__ cb, const float* __restrict__ ns,
    const float* __restrict__ nb, unsigned short* __restrict__ y)
{
    __shared__ float sFK[6400];
    const int tid = threadIdx.x;
    for (int i = tid; i < 6400; i += 256) sFK[i] = fkg[i];
    __syncthreads();
    const int lane = tid & 63, wv = tid >> 6;
    float cbv = cb[lane], nsv = ns[lane], nbv = nb[lane];
    for (int g4 = blockIdx.x; g4 < N_/4; g4 += gridDim.x) {
        const int n = g4 * 4 + wv;
        float hr[10];
#pragma unroll
        for (int o = 0; o < O_; ++o) hr[o] = h1[n*640 + o*64 + lane];
#pragma unroll
        for (int p = 0; p < O_; ++p) {
            float v = 0.0f;
#pragma unroll
            for (int o = 0; o < O_; ++o) v = fmaf(hr[o], sFK[(p*O_+o)*64 + lane], v);
            v = v * 0.1f + cbv;
            float s = v, q = v*v;
#pragma unroll
            for (int d = 1; d < 64; d <<= 1) { s += __shfl_xor(s, d); q += __shfl_xor(q, d); }
            float mu = s * (1.0f/64.0f);
            float var = q * (1.0f/64.0f) - mu*mu;
            float rs = rsqrtf(var + 1e-6f);
            float yv = (v - mu) * rs * nsv + nbv;
            y[(n*O_ + p)*64 + lane] = f2bf(yv);
        }
    }
}

// ---------------------------------------------------------------------------
// MLP: 64 rows/block, frag-packed weights, readout stored.  Writes hn back
// into ybuf (bf16) in-place -> next layer's gather table.
// ---------------------------------------------------------------------------
__global__ __launch_bounds__(256, 4) void k_mlp(
    unsigned short* ybuf, float* __restrict__ hg, float* __restrict__ rout,
    const unsigned short* __restrict__ wL1P_l, const float* __restrict__ l1b_l,
    const unsigned short* __restrict__ wL2P_l, const float* __restrict__ l2b_l,
    const unsigned short* __restrict__ wROP_l, const float* __restrict__ rob_l)
{
    __shared__ unsigned short sA[64*64];
    const int tid = threadIdx.x;
    const int lane = tid & 63, wv = tid >> 6;
    const int rb = blockIdx.x * 64;
#pragma unroll
    for (int i = tid*16; i < 64*128; i += 256*16) {
        int r = i >> 7, off = i & 127;
        int grow = rb + r; if (grow >= NROW_) grow = NROW_ - 1;
        *(f32x4*)((char*)sA + r*128 + (off ^ ((r&7)<<4))) =
            *(const f32x4*)((const char*)ybuf + (size_t)grow*128 + off);
    }
    __syncthreads();
    const int lm = lane & 15, lk = lane >> 4;
    const int r0 = wv*16 + lm;
    bf16x8 Yf[2];
#pragma unroll
    for (int ks = 0; ks < 2; ++ks) {
        int kb = ks*64 + lk*16;
        Yf[ks] = *(const bf16x8*)((const char*)sA + r0*128 + (kb ^ ((r0&7)<<4)));
    }
    f32x4 acc2[4];
#pragma unroll
    for (int m = 0; m < 4; ++m) acc2[m] = *(const f32x4*)(l2b_l + m*16 + (lk<<2));
#pragma unroll
    for (int jb = 0; jb < 4; ++jb) {
#pragma unroll
        for (int mt = 0; mt < 4; ++mt) {
            bf16x8 A1[2];
#pragma unroll
            for (int ks = 0; ks < 2; ++ks)
                A1[ks] = *(const bf16x8*)(wL1P_l + (((jb*4 + mt)*2 + ks)*64 + lane)*8);
            f32x4 acc = *(const f32x4*)(l1b_l + jb*64 + mt*16 + (lk<<2));
            acc = MFMA16(A1[0], Yf[0], acc);
            acc = MFMA16(A1[1], Yf[1], acc);
            bf16x4 pk = pack4(gelu_f(acc[0]), gelu_f(acc[1]), gelu_f(acc[2]), gelu_f(acc[3]));
            int cb = mt*32 + (lk<<3);
            *(bf16x4*)((char*)sA + r0*128 + (cb ^ ((r0&7)<<4))) = pk;
        }
        bf16x8 Mf[2];
#pragma unroll
        for (int ks = 0; ks < 2; ++ks) {
            int kb = ks*64 + lk*16;
            Mf[ks] = *(const bf16x8*)((const char*)sA + r0*128 + (kb ^ ((r0&7)<<4)));
        }
#pragma unroll
        for (int mt2 = 0; mt2 < 4; ++mt2) {
            bf16x8 A2[2];
#pragma unroll
            for (int ks = 0; ks < 2; ++ks)
                A2[ks] = *(const bf16x8*)(wL2P_l + ((mt2*8 + jb*2 + ks)*64 + lane)*8);
            acc2[mt2] = MFMA16(A2[0], Mf[0], acc2[mt2]);
            acc2[mt2] = MFMA16(A2[1], Mf[1], acc2[mt2]);
        }
    }
    const int grow = rb + r0;
    const bool valid = grow < NROW_;
    const int growc = valid ? grow : (NROW_ - 1);
#pragma unroll
    for (int mt2 = 0; mt2 < 4; ++mt2) {
        f32x4 hv = *(const f32x4*)(hg + (size_t)growc*64 + mt2*16 + (lk<<2));
        f32x4 hn;
#pragma unroll
        for (int r = 0; r < 4; ++r) hn[r] = hv[r] + acc2[mt2][r];
        bf16x4 pk = pack4(hn[0], hn[1], hn[2], hn[3]);
        if (valid) {
            *(f32x4*)(hg + (size_t)grow*64 + mt2*16 + (lk<<2)) = hn;
            *(bf16x4*)((char*)ybuf + (size_t)grow*128 + (mt2*16 + (lk<<2))*2) = pk;
        }
        int cb = mt2*32 + (lk<<3);
        *(bf16x4*)((char*)sA + r0*128 + (cb ^ ((r0&7)<<4))) = pk;
    }
    bf16x8 Ro[2];
#pragma unroll
    for (int ks = 0; ks < 2; ++ks)
        Ro[ks] = *(const bf16x8*)(wROP_l + (ks*64 + lane)*8);
    f32x4 r4 = *(const f32x4*)(rob_l + (lk<<2));
    bf16x8 Hf[2];
#pragma unroll
    for (int ks = 0; ks < 2; ++ks) {
        int kb = ks*64 + lk*16;
        Hf[ks] = *(const bf16x8*)((const char*)sA + r0*128 + (kb ^ ((r0&7)<<4)));
    }
    r4 = MFMA16(Ro[0], Hf[0], r4);
    r4 = MFMA16(Ro[1], Hf[1], r4);
    if (valid) *(f32x4*)(rout + (size_t)grow*16 + (lk<<2)) = r4;
}

// ---------------------------------------------------------------------------
__global__ __launch_bounds__(256) void k_pool(
    const float* __restrict__ r0, const float* __restrict__ r1,
    const int* __restrict__ batch, float* __restrict__ out)
{
    int t = blockIdx.x * 256 + threadIdx.x;
    if (t >= N_ * 16) return;
    int n = t >> 4, j = t & 15;
    float s = 0.0f;
#pragma unroll
    for (int p = 0; p < O_; ++p)
        s += r0[(n*O_ + p)*16 + j] + r1[(n*O_ + p)*16 + j];
    atomicAdd(&out[batch[n]*16 + j], s * (1.0f/20.0f));
}

// ---------------------------------------------------------------------------
extern "C" void kernel_launch(void* const* d_in, const int* in_sizes, int n_in,
                              void* d_out, int out_size, void* d_ws, size_t ws_size,
                              hipStream_t stream)
{
    const float* x    = (const float*)d_in[0];
    const float* pos  = (const float*)d_in[1];
    const float* bw1  = (const float*)d_in[2];
    const float* bb1  = (const float*)d_in[3];
    const float* bw2  = (const float*)d_in[4];
    const float* bb2  = (const float*)d_in[5];
    const float* fw1  = (const float*)d_in[6];
    const float* fb1  = (const float*)d_in[7];
    const float* fw2  = (const float*)d_in[8];
    const float* fb2  = (const float*)d_in[9];
    const float* embw = (const float*)d_in[10];
    const float* ckw  = (const float*)d_in[11];
    const float* cfw  = (const float*)d_in[12];
    const float* cb   = (const float*)d_in[13];
    const float* ns   = (const float*)d_in[14];
    const float* nbp  = (const float*)d_in[15];
    const float* l1w  = (const float*)d_in[16];
    const float* l1b  = (const float*)d_in[17];
    const float* l2w  = (const float*)d_in[18];
    const float* l2b  = (const float*)d_in[19];
    const float* row  = (const float*)d_in[20];
    const float* rob  = (const float*)d_in[21];
    const int*   ei   = (const int*)d_in[22];
    const int*   batch= (const int*)d_in[23];
    float* out = (float*)d_out;

    char* w = (char*)d_ws;
    size_t off = 0;
    auto alloc = [&](size_t bytes) -> char* {
        char* p = w + off; off += (bytes + 255) / 256 * 256; return p;
    };
    float* ori    = (float*)alloc(32 * 4);
    float* fkg    = (float*)alloc(2 * 6400 * 4);
    unsigned short* wW1P = (unsigned short*)alloc(4*512*2);
    unsigned short* wW2P = (unsigned short*)alloc(8*512*2);
    unsigned short* wCKP = (unsigned short*)alloc(2*8*512*2);
    unsigned short* wL1P = (unsigned short*)alloc(2*32*512*2);
    unsigned short* wL2P = (unsigned short*)alloc(2*32*512*2);
    unsigned short* wROP = (unsigned short*)alloc(2*2*512*2);
    float* h      = (float*)alloc((size_t)N_ * 640 * 4);
    float* h1     = (float*)alloc((size_t)N_ * 640 * 4);
    unsigned short* y = (unsigned short*)alloc((size_t)NROW_ * 64 * 2);
    unsigned short* hbf0 = (unsigned short*)alloc((size_t)N_ * 64 * 2);
    float* rout0  = (float*)alloc((size_t)NROW_ * 16 * 4);
    float* rout1  = (float*)alloc((size_t)NROW_ * 16 * 4);
    float* crel   = (float*)alloc((size_t)E_ * 3 * 4);
    int*   counts = (int*)alloc((N_ + 1) * 4);
    int*   offs   = (int*)alloc((N_ + 1) * 4);
    int*   cursor = (int*)alloc((N_ + 1) * 4);
    int*   csend  = (int*)alloc((size_t)E_ * 4);
    int*   crecv  = (int*)alloc((size_t)E_ * 4);

    hipMemsetAsync(out, 0, (size_t)out_size * 4, stream);
    hipMemsetAsync(counts, 0, (N_ + 1) * 4, stream);

    k_pack<<<321, 256, 0, stream>>>(bw1, bw2, ckw, l1w, l2w, row, ori,
                                    wW1P, wW2P, wCKP, wL1P, wL2P, wROP);
    k_fibpre<<<25, 256, 0, stream>>>(fw1, fb1, fw2, fb2, cfw, fkg);
    k_embed<<<(N_ * 64 + 255) / 256, 256, 0, stream>>>(x, embw, h, hbf0);
    k_hist<<<(E_ + 255) / 256, 256, 0, stream>>>(ei, counts);
    k_scan<<<1, 1024, 0, stream>>>(counts, offs, cursor);
    k_scatter<<<(E_ + 255) / 256, 256, 0, stream>>>(ei, pos, cursor, csend, crecv, crel);

    for (int l = 0; l < 2; ++l) {
        hipMemsetAsync(h1, 0, (size_t)N_ * 640 * 4, stream);
        if (l == 0)
            k_msg<true><<<NITEM_ / 128, 128, 0, stream>>>(hbf0, h1, csend, crecv, crel, ori,
                                                          wW1P, wW2P, wCKP + l*4096, bb1, bb2);
        else
            k_msg<false><<<NITEM_ / 128, 128, 0, stream>>>(y, h1, csend, crecv, crel, ori,
                                                           wW1P, wW2P, wCKP + l*4096, bb1, bb2);
        k_fln<<<625, 256, 0, stream>>>(h1, fkg + l*6400, cb + l*64, ns + l*64, nbp + l*64, y);
        k_mlp<<<(NROW_ + 63) / 64, 256, 0, stream>>>(y, h, (l == 0 ? rout0 : rout1),
                                                     wL1P + l*16384, l1b + l*256,
                                                     wL2P + l*16384, l2b + l*64,
                                                     wROP + l*1024, rob + l*16);
    }
    k_pool<<<(N_ * 16 + 255) / 256, 256, 0, stream>>>(rout0, rout1, batch, out);
}

// Round 9
// 414.857 us; speedup vs baseline: 23.9519x; 1.0431x over previous
//
#include <hip/hip_runtime.h>
#include <math.h>

#define N_   10000
#define E_   80000
#define O_   10
#define B_   16
#define OUT_ 16
#define NROW_ (N_*O_)    // 100000
#define NITEM_ (E_*O_)   // 800000

typedef __attribute__((ext_vector_type(8))) short bf16x8;
typedef __attribute__((ext_vector_type(4))) short bf16x4;
typedef __attribute__((ext_vector_type(4))) float f32x4;

#define MFMA16(a,b,c) __builtin_amdgcn_mfma_f32_16x16x32_bf16(a,b,c,0,0,0)

__device__ __forceinline__ float gelu_f(float x) {
    float u = fmaf(0.044715f, x * x, 1.0f);
    float e = __builtin_amdgcn_exp2f(2.3022083f * x * u);
    float r = __builtin_amdgcn_rcpf(e + 1.0f);
    return fmaf(-x, r, x);
}

__device__ __forceinline__ unsigned short f2bf(float f) {
    union { float f; unsigned int u; } v; v.f = f;
    unsigned int r = v.u + 0x7FFFu + ((v.u >> 16) & 1u);
    return (unsigned short)(r >> 16);
}
__device__ __forceinline__ float bf2f(unsigned short u) {
    union { unsigned int u; float f; } v; v.u = ((unsigned int)u) << 16;
    return v.f;
}
__device__ __forceinline__ unsigned int cvtpk(float lo, float hi) {
    unsigned int r;
    asm("v_cvt_pk_bf16_f32 %0, %1, %2" : "=v"(r) : "v"(lo), "v"(hi));
    return r;
}
__device__ __forceinline__ bf16x4 pack4(float a, float b, float c, float d) {
    union { unsigned int u[2]; bf16x4 v; } z;
    z.u[0] = cvtpk(a, b);
    z.u[1] = cvtpk(c, d);
    return z.v;
}

__device__ __forceinline__ void fib_vec(int idx, float& vx, float& vy, float& vz) {
    float i = (float)idx + 0.5f;
    float phi = acosf(1.0f - 2.0f * i / (float)O_);
    float theta = 3.14159265358979323846f * (1.0f + 2.2360679774997896964f) * i;
    float sp = sinf(phi);
    vx = cosf(theta) * sp; vy = sinf(theta) * sp; vz = cosf(phi);
}

// ---------------------------------------------------------------------------
// Parallel weight frag-pack (one thread per element) + orientations.
// ---------------------------------------------------------------------------
__global__ __launch_bounds__(256) void k_pack(
    const float* __restrict__ bw1, const float* __restrict__ bw2,
    const float* __restrict__ ckw, const float* __restrict__ l1w,
    const float* __restrict__ l2w, const float* __restrict__ row_w,
    float* __restrict__ orig,
    unsigned short* __restrict__ wW1P, unsigned short* __restrict__ wW2P,
    unsigned short* __restrict__ wCKP, unsigned short* __restrict__ wL1P,
    unsigned short* __restrict__ wL2P, unsigned short* __restrict__ wROP)
{
    const int g = blockIdx.x * 256 + threadIdx.x;
    if (g < 2048) {                                   // W1 (folded): M=64,K=32
        int idx = g;
        int t = idx >> 9, rem = idx & 511;
        int ln = rem >> 3, j = rem & 7;
        int row = t*16 + (ln & 15);
        int k = (ln >> 4)*8 + j;
        float s = 0.0f;
        if (k < 14) {
            const int moff[14] = {0,1,2,3,5,6,7,10,13,14,15,19,25,29};
            const int mcnt[14] = {1,1,1,2,1,1,3,3,1,1,4,6,4,1};
            const int mlist[30] = {0,1,2,3,4,5,6,7,8,10,9,11,12,13,14,
                                   15,16,18,22,17,19,20,23,24,26,21,25,27,28,29};
            for (int q = 0; q < mcnt[k]; ++q) s += bw1[mlist[moff[k]+q]*64 + row];
        }
        wW1P[idx] = f2bf(s);
    } else if (g < 6144) {                            // W2: M=64,K=64
        int idx = g - 2048;
        int t = idx >> 9, rem = idx & 511;
        int mt = t >> 1, ks = t & 1;
        int ln = rem >> 3, j = rem & 7;
        int row = mt*16 + (ln & 15);
        int k = ks*32 + (ln >> 4)*8 + j;
        wW2P[idx] = f2bf(bw2[k*64 + row]);
    } else if (g < 14336) {                           // CK[l]: M=64,K=64
        int idx = g - 6144;
        int l = idx >> 12, r2 = idx & 4095;
        int t = r2 >> 9, rem = r2 & 511;
        int mt = t >> 1, ks = t & 1;
        int ln = rem >> 3, j = rem & 7;
        int row = mt*16 + (ln & 15);
        int k = ks*32 + (ln >> 4)*8 + j;
        wCKP[idx] = f2bf(ckw[l*4096 + k*64 + row]);
    } else if (g < 47104) {                           // L1[l]: M=256,K=64
        int idx = g - 14336;
        int l = idx >> 14, r2 = idx & 16383;
        int t = r2 >> 9, rem = r2 & 511;
        int mt = t >> 1, ks = t & 1;
        int ln = rem >> 3, j = rem & 7;
        int row = mt*16 + (ln & 15);
        int k = ks*32 + (ln >> 4)*8 + j;
        wL1P[idx] = f2bf(l1w[l*16384 + k*256 + row]);
    } else if (g < 79872) {                           // L2[l]: M=64,K=256
        int idx = g - 47104;
        int l = idx >> 14, r2 = idx & 16383;
        int t = r2 >> 9, rem = r2 & 511;
        int mt2 = t >> 3, ksg = t & 7;
        int ln = rem >> 3, j = rem & 7;
        int row = mt2*16 + (ln & 15);
        int k = ksg*32 + (ln >> 4)*8 + j;
        wL2P[idx] = f2bf(l2w[l*16384 + k*64 + row]);
    } else if (g < 81920) {                           // RO[l]: M=16,K=64
        int idx = g - 79872;
        int l = idx >> 10, r2 = idx & 1023;
        int ks = r2 >> 9, rem = r2 & 511;
        int ln = rem >> 3, j = rem & 7;
        int row = ln & 15;
        int k = ks*32 + (ln >> 4)*8 + j;
        wROP[idx] = f2bf(row_w[l*1024 + k*16 + row]);
    } else if (g < 81920 + O_) {                      // orientations
        int o = g - 81920;
        float vx, vy, vz;
        fib_vec(o, vx, vy, vz);
        orig[o*3+0] = vx; orig[o*3+1] = vy; orig[o*3+2] = vz;
    }
}

// ---------------------------------------------------------------------------
// Fiber-basis precompute: one wave per orientation pair.
// ---------------------------------------------------------------------------
__global__ __launch_bounds__(256) void k_fibpre(
    const float* __restrict__ fw1, const float* __restrict__ fb1,
    const float* __restrict__ fw2, const float* __restrict__ fb2,
    const float* __restrict__ cfw, float* __restrict__ fkg)
{
    __shared__ float sRow[4][64];
    const int wv = threadIdx.x >> 6, lane = threadIdx.x & 63;
    const int pr = blockIdx.x * 4 + wv;
    if (pr >= 100) return;
    const int i = pr / O_, j = pr % O_;
    float ix, iy, iz, jx, jy, jz;
    fib_vec(i, ix, iy, iz);
    fib_vec(j, jx, jy, jz);
    float a = ix*jx + iy*jy + iz*jz;
    float a2 = a*a, a3 = a2*a, a4 = a3*a;
    float v = fb1[lane];
    v = fmaf(a,  fw1[0*64+lane], v);
    v = fmaf(a2, fw1[1*64+lane], v);
    v = fmaf(a3, fw1[2*64+lane], v);
    v = fmaf(a4, fw1[3*64+lane], v);
    sRow[wv][lane] = gelu_f(v);
    float acc = fb2[lane];
    for (int b = 0; b < 64; ++b) acc = fmaf(sRow[wv][b], fw2[b*64+lane], acc);
    sRow[wv][lane] = gelu_f(acc);
    for (int l = 0; l < 2; ++l) {
        float s = 0.0f;
        for (int b = 0; b < 64; ++b) s = fmaf(sRow[wv][b], cfw[l*4096 + b*64 + lane], s);
        fkg[l*6400 + pr*64 + lane] = s;
    }
}

// ---------------------------------------------------------------------------
__global__ __launch_bounds__(256) void k_embed(
    const float* __restrict__ x, const float* __restrict__ ew,
    float* __restrict__ hg, unsigned short* __restrict__ hbf0)
{
    int t = blockIdx.x * 256 + threadIdx.x;
    if (t >= N_ * 64) return;
    int n = t >> 6, c = t & 63;
    float v = 0.0f;
#pragma unroll
    for (int k = 0; k < 16; ++k) v = fmaf(x[n*16+k], ew[k*64+c], v);
    int base = n * 640 + c;
#pragma unroll
    for (int o = 0; o < O_; ++o) hg[base + o*64] = v;
    hbf0[t] = f2bf(v);
}

// ---------------------------------------------------------------------------
__global__ __launch_bounds__(256) void k_hist(const int* __restrict__ ei, int* __restrict__ counts)
{
    int e = blockIdx.x * 256 + threadIdx.x;
    if (e < E_) atomicAdd(&counts[ei[E_ + e]], 1);
}

__global__ __launch_bounds__(1024) void k_scan(
    const int* __restrict__ counts, int* __restrict__ offs, int* __restrict__ cursor)
{
    __shared__ int part[1024];
    int t = threadIdx.x;
    const int CH = 10;
    int base_i = t * CH;
    int s = 0;
#pragma unroll
    for (int i = 0; i < CH; ++i) { int idx = base_i + i; if (idx < N_) s += counts[idx]; }
    part[t] = s;
    __syncthreads();
    for (int off = 1; off < 1024; off <<= 1) {
        int v = (t >= off) ? part[t - off] : 0;
        __syncthreads();
        part[t] += v;
        __syncthreads();
    }
    int run = (t > 0) ? part[t - 1] : 0;
#pragma unroll
    for (int i = 0; i < CH; ++i) {
        int idx = base_i + i;
        if (idx < N_) { offs[idx] = run; cursor[idx] = run; run += counts[idx]; }
    }
    if (t == 1023) offs[N_] = run;
}

__global__ __launch_bounds__(256) void k_scatter(
    const int* __restrict__ ei, const float* __restrict__ pos,
    int* __restrict__ cursor, int* __restrict__ csend, int* __restrict__ crecv,
    float* __restrict__ crel)
{
    int e = blockIdx.x * 256 + threadIdx.x;
    if (e >= E_) return;
    int s = ei[e], r = ei[E_ + e];
    int slot = atomicAdd(&cursor[r], 1);
    csend[slot] = s;
    crecv[slot] = r;
    crel[slot*3+0] = pos[s*3+0] - pos[r*3+0];
    crel[slot*3+1] = pos[s*3+1] - pos[r*3+1];
    crel[slot*3+2] = pos[s*3+2] - pos[r*3+2];
}

// ---------------------------------------------------------------------------
// MFMA stage helpers (single-wave block: rows 0..63 of sData).
// ---------------------------------------------------------------------------
template<int KS>
__device__ __forceinline__ void loadB(
    const unsigned short* sData, int lane, bf16x8 Bf[4][KS])
{
    const int lm = lane & 15, lk = lane >> 4;
#pragma unroll
    for (int nt = 0; nt < 4; ++nt)
#pragma unroll
        for (int ks = 0; ks < KS; ++ks) {
            int r = nt*16 + lm;
            int kb = ks*64 + lk*16;
            Bf[nt][ks] = *(const bf16x8*)((const char*)sData + r*128 + (kb ^ ((r&7)<<4)));
        }
}

template<int KS, bool BIAS, bool GELU>
__device__ __forceinline__ void stageC(
    unsigned short* sData, const bf16x8 Bf[4][KS],
    const unsigned short* __restrict__ Wp, const float* __restrict__ bias, int lane)
{
    const int lm = lane & 15, lk = lane >> 4;
#pragma unroll
    for (int mt = 0; mt < 4; ++mt) {
        bf16x8 Af[KS];
#pragma unroll
        for (int ks = 0; ks < KS; ++ks)
            Af[ks] = *(const bf16x8*)(Wp + ((mt*KS + ks)*64 + lane)*8);
        f32x4 b4 = {0,0,0,0};
        if (BIAS) b4 = *(const f32x4*)(bias + mt*16 + (lk<<2));
#pragma unroll
        for (int nt = 0; nt < 4; ++nt) {
            f32x4 acc = b4;
#pragma unroll
            for (int ks = 0; ks < KS; ++ks) acc = MFMA16(Af[ks], Bf[nt][ks], acc);
            float v0 = acc[0], v1 = acc[1], v2 = acc[2], v3 = acc[3];
            if (GELU) { v0 = gelu_f(v0); v1 = gelu_f(v1); v2 = gelu_f(v2); v3 = gelu_f(v3); }
            bf16x4 pk = pack4(v0, v1, v2, v3);
            int rr = nt*16 + lm;
            int cb = mt*32 + (lk<<3);
            *(bf16x4*)((char*)sData + rr*128 + (cb ^ ((rr&7)<<4))) = pk;
        }
    }
}

// phase 0: per-item monomial features -> sData row tid
__device__ __forceinline__ void phase0(
    unsigned short* sData, int slot, int oo, const float* __restrict__ crel,
    const float* __restrict__ ori, int tid)
{
    float r0 = crel[slot*3+0], r1 = crel[slot*3+1], r2 = crel[slot*3+2];
    float o0 = ori[oo*3+0], o1 = ori[oo*3+1], o2 = ori[oo*3+2];
    float a = r0*o0 + r1*o1 + r2*o2;
    float p0 = fmaf(-a, o0, r0), p1 = fmaf(-a, o1, r1), p2 = fmaf(-a, o2, r2);
    float b = sqrtf(p0*p0 + p1*p1 + p2*p2);
    float a2 = a*a, b2 = b*b, ab = a*b;
    float m[14];
    m[0]=a; m[1]=b; m[2]=a2; m[3]=ab; m[4]=b2;
    m[5]=a2*a; m[6]=a2*b; m[7]=a*b2; m[8]=b2*b;
    m[9]=a2*a2; m[10]=a2*ab; m[11]=a2*b2; m[12]=ab*b2; m[13]=b2*b2;
    unsigned int pk[16];
#pragma unroll
    for (int j = 0; j < 7; ++j) pk[j] = cvtpk(m[2*j], m[2*j+1]);
#pragma unroll
    for (int j = 7; j < 16; ++j) pk[j] = 0;
#pragma unroll
    for (int q = 0; q < 4; ++q) {
        int cb = q*16;
        *(f32x4*)((char*)sData + tid*128 + (cb ^ ((tid&7)<<4))) = ((const f32x4*)pk)[q];
    }
}

// scatter tail: lane=channel; kc from LDS (or global for lite kernel)
#define SCATTER_BODY(KC_EXPR)                                                        \
    int prevr = __shfl_up(rcv, 1);                                                   \
    unsigned long long bmask = __ballot(lane > 0 && rcv != prevr);                   \
    float a0=0,a1c=0,a2c=0,a3c=0,a4c=0,a5c=0,a6c=0,a7c=0,a8c=0,a9c=0;                \
    int cur = __builtin_amdgcn_readfirstlane(rcv);                                   \
    int soi = item0 % 10;                                                            \
    _Pragma("unroll")                                                                \
    for (int ch = 0; ch < 4; ++ch) {                                                 \
        unsigned short hvu[16]; float kcv[16];                                       \
        _Pragma("unroll")                                                            \
        for (int j = 0; j < 16; ++j) {                                               \
            const int i = ch*16 + j;                                                 \
            hvu[j] = hb[__builtin_amdgcn_readlane(myaddr, i)];                       \
            kcv[j] = (KC_EXPR);                                                      \
        }                                                                            \
        _Pragma("unroll")                                                            \
        for (int j = 0; j < 16; ++j) {                                               \
            const int i = ch*16 + j;                                                 \
            if (bmask & (1ull << i)) { FLUSH_RUN(cur); cur = __builtin_amdgcn_readlane(rcv, i); } \
            float mv = kcv[j] * bf2f(hvu[j]);                                        \
            if      (soi == 0) a0  += mv;                                            \
            else if (soi == 1) a1c += mv;                                            \
            else if (soi == 2) a2c += mv;                                            \
            else if (soi == 3) a3c += mv;                                            \
            else if (soi == 4) a4c += mv;                                            \
            else if (soi == 5) a5c += mv;                                            \
            else if (soi == 6) a6c += mv;                                            \
            else if (soi == 7) a7c += mv;                                            \
            else if (soi == 8) a8c += mv;                                            \
            else               a9c += mv;                                            \
            soi = (soi == 9) ? 0 : soi + 1;                                          \
        }                                                                            \
    }                                                                                \
    FLUSH_RUN(cur);

#define FLUSH_RUN(R) { float* bp = h1g + (R)*640 + lane; \
    atomicAdd(bp+0,a0); atomicAdd(bp+64,a1c); atomicAdd(bp+128,a2c); atomicAdd(bp+192,a3c); \
    atomicAdd(bp+256,a4c); atomicAdd(bp+320,a5c); atomicAdd(bp+384,a6c); atomicAdd(bp+448,a7c); \
    atomicAdd(bp+512,a8c); atomicAdd(bp+576,a9c); \
    a0=a1c=a2c=a3c=a4c=a5c=a6c=a7c=a8c=a9c=0.0f; }

// ---------------------------------------------------------------------------
// Fallback full k_msg (1 wave/block, 8 KB LDS).  L0: gather hbf0[n][c].
// ---------------------------------------------------------------------------
template<bool L0>
__global__ __launch_bounds__(64) void k_msg(
    const unsigned short* __restrict__ hbf, float* __restrict__ h1g,
    const int* __restrict__ csend, const int* __restrict__ crecv,
    const float* __restrict__ crel, const float* __restrict__ ori,
    const unsigned short* __restrict__ wW1P, const unsigned short* __restrict__ wW2P,
    const unsigned short* __restrict__ wCKP_l,
    const float* __restrict__ bb1, const float* __restrict__ bb2)
{
    __shared__ unsigned short sData[64*64];
    const int lane = threadIdx.x;
    const int item0 = blockIdx.x * 64;
    const int item = item0 + lane;
    const int slot = item / 10;
    const int oo = item - slot * 10;
    const int snd = csend[slot];
    const int rcv = crecv[slot];
    phase0(sData, slot, oo, crel, ori, lane);
    {
        bf16x8 Bf1[4][1]; loadB<1>(sData, lane, Bf1);
        stageC<1, true, true>(sData, Bf1, wW1P, bb1, lane);
    }
    {
        bf16x8 Bf2[4][2]; loadB<2>(sData, lane, Bf2);
        stageC<2, true, true>(sData, Bf2, wW2P, bb2, lane);
    }
    {
        bf16x8 Bf3[4][2]; loadB<2>(sData, lane, Bf3);
        stageC<2, false, false>(sData, Bf3, wCKP_l, (const float*)0, lane);
    }
    const int myaddr = L0 ? (snd * 64) : ((snd * 10 + oo) * 64);
    const unsigned short* hb = hbf + lane;
    SCATTER_BODY(bf2f(*(const unsigned short*)((const char*)sData + i*128 + ((lane*2) ^ ((i&7)<<4)))))
}

// ---------------------------------------------------------------------------
// Layer-0 dual k_msg: shared stages 1-2, stage3 for BOTH layers; kc1 -> global,
// kc0 -> scatter with hbf0.
// ---------------------------------------------------------------------------
__global__ __launch_bounds__(64) void k_msg0dual(
    const unsigned short* __restrict__ hbf, float* __restrict__ h1g,
    unsigned short* __restrict__ kc1g,
    const int* __restrict__ csend, const int* __restrict__ crecv,
    const float* __restrict__ crel, const float* __restrict__ ori,
    const unsigned short* __restrict__ wW1P, const unsigned short* __restrict__ wW2P,
    const unsigned short* __restrict__ wCK0, const unsigned short* __restrict__ wCK1,
    const float* __restrict__ bb1, const float* __restrict__ bb2)
{
    __shared__ unsigned short sData[64*64];
    const int lane = threadIdx.x;
    const int item0 = blockIdx.x * 64;
    const int item = item0 + lane;
    const int slot = item / 10;
    const int oo = item - slot * 10;
    const int snd = csend[slot];
    const int rcv = crecv[slot];
    phase0(sData, slot, oo, crel, ori, lane);
    {
        bf16x8 Bf1[4][1]; loadB<1>(sData, lane, Bf1);
        stageC<1, true, true>(sData, Bf1, wW1P, bb1, lane);
    }
    {
        bf16x8 Bf2[4][2]; loadB<2>(sData, lane, Bf2);
        stageC<2, true, true>(sData, Bf2, wW2P, bb2, lane);
    }
    bf16x8 Bf3[4][2]; loadB<2>(sData, lane, Bf3);
    // stage3 layer 1 -> kc1g (each lane copies its FULL 128-byte row)
    stageC<2, false, false>(sData, Bf3, wCK1, (const float*)0, lane);
#pragma unroll
    for (int q = 0; q < 8; ++q) {
        f32x4 v = *(const f32x4*)((const char*)sData + lane*128 + ((q*16) ^ ((lane&7)<<4)));
        *(f32x4*)((char*)kc1g + (size_t)item*128 + ((q*16) ^ ((lane&7)<<4))) = v;
    }
    // stage3 layer 0 -> scatter
    stageC<2, false, false>(sData, Bf3, wCK0, (const float*)0, lane);
    const int myaddr = snd * 64;
    const unsigned short* hb = hbf + lane;
    SCATTER_BODY(bf2f(*(const unsigned short*)((const char*)sData + i*128 + ((lane*2) ^ ((i&7)<<4)))))
}

// ---------------------------------------------------------------------------
// Layer-1 lite k_msg: precomputed kc1 (row-stored, same swizzle as LDS rows)
// + gather + scatter.  No MFMA, no LDS.
// ---------------------------------------------------------------------------
__global__ __launch_bounds__(64) void k_msg1lite(
    const unsigned short* __restrict__ kc1g, const unsigned short* __restrict__ hbf,
    float* __restrict__ h1g,
    const int* __restrict__ csend, const int* __restrict__ crecv)
{
    const int lane = threadIdx.x;
    const int item0 = blockIdx.x * 64;
    const int item = item0 + lane;
    const int slot = item / 10;
    const int oo = item - slot * 10;
    const int snd = csend[slot];
    const int rcv = crecv[slot];
    const int myaddr = (snd * 10 + oo) * 64;
    const unsigned short* hb = hbf + lane;
    const char* kb = (const char*)kc1g + (size_t)item0 * 128;
    SCATTER_BODY(bf2f(*(const unsigned short*)(kb + (size_t)i*128 + ((lane*2) ^ ((i&7)<<4)))))
}
#undef FLUSH_RUN
#undef SCATTER_BODY

// ---------------------------------------------------------------------------
// Fused fiber conv + LayerNorm -> y bf16; optionally zero h1 after read.
// ---------------------------------------------------------------------------
__global__ __launch_bounds__(256) void k_fln(
    float* __restrict__ h1, const float* __restrict__ fkg,
    const float* __restrict__ cb, const float* __restrict__ ns,
    const float* __restrict__ nb, unsigned short* __restrict__ y, int zero_h1)
{
    __shared__ float sFK[6400];
    const int tid = threadIdx.x;
    for (int i = tid; i < 6400; i += 256) sFK[i] = fkg[i];
    __syncthreads();
    const int lane = tid & 63, wv = tid >> 6;
    float cbv = cb[lane], nsv = ns[lane], nbv = nb[lane];
    for (int g4 = blockIdx.x; g4 < N_/4; g4 += gridDim.x) {
        const int n = g4 * 4 + wv;
        float hr[10];
#pragma unroll
        for (int o = 0; o < O_; ++o) hr[o] = h1[n*640 + o*64 + lane];
        if (zero_h1) {
#pragma unroll
            for (int o = 0; o < O_; ++o) h1[n*640 + o*64 + lane] = 0.0f;
        }
#pragma unroll
        for (int p = 0; p < O_; ++p) {
            float v = 0.0f;
#pragma unroll
            for (int o = 0; o < O_; ++o) v = fmaf(hr[o], sFK[(p*O_+o)*64 + lane], v);
            v = v * 0.1f + cbv;
            float s = v, q = v*v;
#pragma unroll
            for (int d = 1; d < 64; d <<= 1) { s += __shfl_xor(s, d); q += __shfl_xor(q, d); }
            float mu = s * (1.0f/64.0f);
            float var = q * (1.0f/64.0f) - mu*mu;
            float rs = rsqrtf(var + 1e-6f);
            float yv = (v - mu) * rs * nsv + nbv;
            y[(n*O_ + p)*64 + lane] = f2bf(yv);
        }
    }
}

// ---------------------------------------------------------------------------
// MLP: 64 rows/block, frag-packed weights, readout stored.  Writes hn back
// into ybuf (bf16) in-place -> next layer's gather table.
// ---------------------------------------------------------------------------
__global__ __launch_bounds__(256, 4) void k_mlp(
    unsigned short* ybuf, float* __restrict__ hg, float* __restrict__ rout,
    const unsigned short* __restrict__ wL1P_l, const float* __restrict__ l1b_l,
    const unsigned short* __restrict__ wL2P_l, const float* __restrict__ l2b_l,
    const unsigned short* __restrict__ wROP_l, const float* __restrict__ rob_l)
{
    __shared__ unsigned short sA[64*64];
    const int tid = threadIdx.x;
    const int lane = tid & 63, wv = tid >> 6;
    const int rb = blockIdx.x * 64;
#pragma unroll
    for (int i = tid*16; i < 64*128; i += 256*16) {
        int r = i >> 7, off = i & 127;
        int grow = rb + r; if (grow >= NROW_) grow = NROW_ - 1;
        *(f32x4*)((char*)sA + r*128 + (off ^ ((r&7)<<4))) =
            *(const f32x4*)((const char*)ybuf + (size_t)grow*128 + off);
    }
    __syncthreads();
    const int lm = lane & 15, lk = lane >> 4;
    const int r0 = wv*16 + lm;
    bf16x8 Yf[2];
#pragma unroll
    for (int ks = 0; ks < 2; ++ks) {
        int kb = ks*64 + lk*16;
        Yf[ks] = *(const bf16x8*)((const char*)sA + r0*128 + (kb ^ ((r0&7)<<4)));
    }
    f32x4 acc2[4];
#pragma unroll
    for (int m = 0; m < 4; ++m) acc2[m] = *(const f32x4*)(l2b_l + m*16 + (lk<<2));
#pragma unroll
    for (int jb = 0; jb < 4; ++jb) {
#pragma unroll
        for (int mt = 0; mt < 4; ++mt) {
            bf16x8 A1[2];
#pragma unroll
            for (int ks = 0; ks < 2; ++ks)
                A1[ks] = *(const bf16x8*)(wL1P_l + (((jb*4 + mt)*2 + ks)*64 + lane)*8);
            f32x4 acc = *(const f32x4*)(l1b_l + jb*64 + mt*16 + (lk<<2));
            acc = MFMA16(A1[0], Yf[0], acc);
            acc = MFMA16(A1[1], Yf[1], acc);
            bf16x4 pk = pack4(gelu_f(acc[0]), gelu_f(acc[1]), gelu_f(acc[2]), gelu_f(acc[3]));
            int cb = mt*32 + (lk<<3);
            *(bf16x4*)((char*)sA + r0*128 + (cb ^ ((r0&7)<<4))) = pk;
        }
        bf16x8 Mf[2];
#pragma unroll
        for (int ks = 0; ks < 2; ++ks) {
            int kb = ks*64 + lk*16;
            Mf[ks] = *(const bf16x8*)((const char*)sA + r0*128 + (kb ^ ((r0&7)<<4)));
        }
#pragma unroll
        for (int mt2 = 0; mt2 < 4; ++mt2) {
            bf16x8 A2[2];
#pragma unroll
            for (int ks = 0; ks < 2; ++ks)
                A2[ks] = *(const bf16x8*)(wL2P_l + ((mt2*8 + jb*2 + ks)*64 + lane)*8);
            acc2[mt2] = MFMA16(A2[0], Mf[0], acc2[mt2]);
            acc2[mt2] = MFMA16(A2[1], Mf[1], acc2[mt2]);
        }
    }
    const int grow = rb + r0;
    const bool valid = grow < NROW_;
    const int growc = valid ? grow : (NROW_ - 1);
#pragma unroll
    for (int mt2 = 0; mt2 < 4; ++mt2) {
        f32x4 hv = *(const f32x4*)(hg + (size_t)growc*64 + mt2*16 + (lk<<2));
        f32x4 hn;
#pragma unroll
        for (int r = 0; r < 4; ++r) hn[r] = hv[r] + acc2[mt2][r];
        bf16x4 pk = pack4(hn[0], hn[1], hn[2], hn[3]);
        if (valid) {
            *(f32x4*)(hg + (size_t)grow*64 + mt2*16 + (lk<<2)) = hn;
            *(bf16x4*)((char*)ybuf + (size_t)grow*128 + (mt2*16 + (lk<<2))*2) = pk;
        }
        int cb = mt2*32 + (lk<<3);
        *(bf16x4*)((char*)sA + r0*128 + (cb ^ ((r0&7)<<4))) = pk;
    }
    bf16x8 Ro[2];
#pragma unroll
    for (int ks = 0; ks < 2; ++ks)
        Ro[ks] = *(const bf16x8*)(wROP_l + (ks*64 + lane)*8);
    f32x4 r4 = *(const f32x4*)(rob_l + (lk<<2));
    bf16x8 Hf[2];
#pragma unroll
    for (int ks = 0; ks < 2; ++ks) {
        int kb = ks*64 + lk*16;
        Hf[ks] = *(const bf16x8*)((const char*)sA + r0*128 + (kb ^ ((r0&7)<<4)));
    }
    r4 = MFMA16(Ro[0], Hf[0], r4);
    r4 = MFMA16(Ro[1], Hf[1], r4);
    if (valid) *(f32x4*)(rout + (size_t)grow*16 + (lk<<2)) = r4;
}

// ---------------------------------------------------------------------------
__global__ __launch_bounds__(256) void k_pool(
    const float* __restrict__ r0, const float* __restrict__ r1,
    const int* __restrict__ batch, float* __restrict__ out)
{
    int t = blockIdx.x * 256 + threadIdx.x;
    if (t >= N_ * 16) return;
    int n = t >> 4, j = t & 15;
    float s = 0.0f;
#pragma unroll
    for (int p = 0; p < O_; ++p)
        s += r0[(n*O_ + p)*16 + j] + r1[(n*O_ + p)*16 + j];
    atomicAdd(&out[batch[n]*16 + j], s * (1.0f/20.0f));
}

// ---------------------------------------------------------------------------
extern "C" void kernel_launch(void* const* d_in, const int* in_sizes, int n_in,
                              void* d_out, int out_size, void* d_ws, size_t ws_size,
                              hipStream_t stream)
{
    const float* x    = (const float*)d_in[0];
    const float* pos  = (const float*)d_in[1];
    const float* bw1  = (const float*)d_in[2];
    const float* bb1  = (const float*)d_in[3];
    const float* bw2  = (const float*)d_in[4];
    const float* bb2  = (const float*)d_in[5];
    const float* fw1  = (const float*)d_in[6];
    const float* fb1  = (const float*)d_in[7];
    const float* fw2  = (const float*)d_in[8];
    const float* fb2  = (const float*)d_in[9];
    const float* embw = (const float*)d_in[10];
    const float* ckw  = (const float*)d_in[11];
    const float* cfw  = (const float*)d_in[12];
    const float* cb   = (const float*)d_in[13];
    const float* ns   = (const float*)d_in[14];
    const float* nbp  = (const float*)d_in[15];
    const float* l1w  = (const float*)d_in[16];
    const float* l1b  = (const float*)d_in[17];
    const float* l2w  = (const float*)d_in[18];
    const float* l2b  = (const float*)d_in[19];
    const float* row  = (const float*)d_in[20];
    const float* rob  = (const float*)d_in[21];
    const int*   ei   = (const int*)d_in[22];
    const int*   batch= (const int*)d_in[23];
    float* out = (float*)d_out;

    char* w = (char*)d_ws;
    size_t off = 0;
    auto alloc = [&](size_t bytes) -> char* {
        char* p = w + off; off += (bytes + 255) / 256 * 256; return p;
    };
    float* ori    = (float*)alloc(32 * 4);
    float* fkg    = (float*)alloc(2 * 6400 * 4);
    unsigned short* wW1P = (unsigned short*)alloc(4*512*2);
    unsigned short* wW2P = (unsigned short*)alloc(8*512*2);
    unsigned short* wCKP = (unsigned short*)alloc(2*8*512*2);
    unsigned short* wL1P = (unsigned short*)alloc(2*32*512*2);
    unsigned short* wL2P = (unsigned short*)alloc(2*32*512*2);
    unsigned short* wROP = (unsigned short*)alloc(2*2*512*2);
    float* h      = (float*)alloc((size_t)N_ * 640 * 4);
    float* h1     = (float*)alloc((size_t)N_ * 640 * 4);
    unsigned short* y = (unsigned short*)alloc((size_t)NROW_ * 64 * 2);
    unsigned short* hbf0 = (unsigned short*)alloc((size_t)N_ * 64 * 2);
    float* rout0  = (float*)alloc((size_t)NROW_ * 16 * 4);
    float* rout1  = (float*)alloc((size_t)NROW_ * 16 * 4);
    float* crel   = (float*)alloc((size_t)E_ * 3 * 4);
    int*   counts = (int*)alloc((N_ + 1) * 4);
    int*   offs   = (int*)alloc((N_ + 1) * 4);
    int*   cursor = (int*)alloc((N_ + 1) * 4);
    int*   csend  = (int*)alloc((size_t)E_ * 4);
    int*   crecv  = (int*)alloc((size_t)E_ * 4);
    // optional kc1 buffer (102.4 MB) -- split path only if workspace allows
    unsigned short* kc1g = nullptr;
    if (ws_size >= off + (size_t)NITEM_ * 64 * 2 + 256)
        kc1g = (unsigned short*)alloc((size_t)NITEM_ * 64 * 2);

    hipMemsetAsync(h1, 0, (size_t)N_ * 640 * 4, stream);
    hipMemsetAsync(out, 0, (size_t)out_size * 4, stream);
    hipMemsetAsync(counts, 0, (N_ + 1) * 4, stream);

    k_pack<<<321, 256, 0, stream>>>(bw1, bw2, ckw, l1w, l2w, row, ori,
                                    wW1P, wW2P, wCKP, wL1P, wL2P, wROP);
    k_fibpre<<<25, 256, 0, stream>>>(fw1, fb1, fw2, fb2, cfw, fkg);
    k_embed<<<(N_ * 64 + 255) / 256, 256, 0, stream>>>(x, embw, h, hbf0);
    k_hist<<<(E_ + 255) / 256, 256, 0, stream>>>(ei, counts);
    k_scan<<<1, 1024, 0, stream>>>(counts, offs, cursor);
    k_scatter<<<(E_ + 255) / 256, 256, 0, stream>>>(ei, pos, cursor, csend, crecv, crel);

    for (int l = 0; l < 2; ++l) {
        if (l == 0) {
            if (kc1g)
                k_msg0dual<<<NITEM_ / 64, 64, 0, stream>>>(hbf0, h1, kc1g, csend, crecv,
                                                           crel, ori, wW1P, wW2P,
                                                           wCKP, wCKP + 4096, bb1, bb2);
            else
                k_msg<true><<<NITEM_ / 64, 64, 0, stream>>>(hbf0, h1, csend, crecv, crel, ori,
                                                            wW1P, wW2P, wCKP, bb1, bb2);
        } else {
            if (kc1g)
                k_msg1lite<<<NITEM_ / 64, 64, 0, stream>>>(kc1g, y, h1, csend, crecv);
            else
                k_msg<false><<<NITEM_ / 64, 64, 0, stream>>>(y, h1, csend, crecv, crel, ori,
                                                             wW1P, wW2P, wCKP + 4096, bb1, bb2);
        }
        k_fln<<<625, 256, 0, stream>>>(h1, fkg + l*6400, cb + l*64, ns + l*64, nbp + l*64, y,
                                       (l == 0) ? 1 : 0);
        k_mlp<<<(NROW_ + 63) / 64, 256, 0, stream>>>(y, h, (l == 0 ? rout0 : rout1),
                                                     wL1P + l*16384, l1b + l*256,
                                                     wL2P + l*16384, l2b + l*64,
                                                     wROP + l*1024, rob + l*16);
    }
    k_pool<<<(N_ * 16 + 255) / 256, 256, 0, stream>>>(rout0, rout1, batch, out);
}

// Round 10
// 406.144 us; speedup vs baseline: 24.4658x; 1.0215x over previous
//
#include <hip/hip_runtime.h>
#include <math.h>

#define N_   10000
#define E_   80000
#define O_   10
#define B_   16
#define OUT_ 16
#define NROW_ (N_*O_)    // 100000
#define NITEM_ (E_*O_)   // 800000

typedef __attribute__((ext_vector_type(8))) short bf16x8;
typedef __attribute__((ext_vector_type(4))) short bf16x4;
typedef __attribute__((ext_vector_type(4))) float f32x4;

#define MFMA16(a,b,c) __builtin_amdgcn_mfma_f32_16x16x32_bf16(a,b,c,0,0,0)

__device__ __forceinline__ float gelu_f(float x) {
    float u = fmaf(0.044715f, x * x, 1.0f);
    float e = __builtin_amdgcn_exp2f(2.3022083f * x * u);
    float r = __builtin_amdgcn_rcpf(e + 1.0f);
    return fmaf(-x, r, x);
}

__device__ __forceinline__ unsigned short f2bf(float f) {
    union { float f; unsigned int u; } v; v.f = f;
    unsigned int r = v.u + 0x7FFFu + ((v.u >> 16) & 1u);
    return (unsigned short)(r >> 16);
}
__device__ __forceinline__ float bf2f(unsigned short u) {
    union { unsigned int u; float f; } v; v.u = ((unsigned int)u) << 16;
    return v.f;
}
__device__ __forceinline__ unsigned int cvtpk(float lo, float hi) {
    unsigned int r;
    asm("v_cvt_pk_bf16_f32 %0, %1, %2" : "=v"(r) : "v"(lo), "v"(hi));
    return r;
}
__device__ __forceinline__ bf16x4 pack4(float a, float b, float c, float d) {
    union { unsigned int u[2]; bf16x4 v; } z;
    z.u[0] = cvtpk(a, b);
    z.u[1] = cvtpk(c, d);
    return z.v;
}

__device__ __forceinline__ void fib_vec(int idx, float& vx, float& vy, float& vz) {
    float i = (float)idx + 0.5f;
    float phi = acosf(1.0f - 2.0f * i / (float)O_);
    float theta = 3.14159265358979323846f * (1.0f + 2.2360679774997896964f) * i;
    float sp = sinf(phi);
    vx = cosf(theta) * sp; vy = sinf(theta) * sp; vz = cosf(phi);
}

// ---------------------------------------------------------------------------
// Parallel weight frag-pack (one thread per element) + orientations.
// ---------------------------------------------------------------------------
__global__ __launch_bounds__(256) void k_pack(
    const float* __restrict__ bw1, const float* __restrict__ bw2,
    const float* __restrict__ ckw, const float* __restrict__ l1w,
    const float* __restrict__ l2w, const float* __restrict__ row_w,
    float* __restrict__ orig,
    unsigned short* __restrict__ wW1P, unsigned short* __restrict__ wW2P,
    unsigned short* __restrict__ wCKP, unsigned short* __restrict__ wL1P,
    unsigned short* __restrict__ wL2P, unsigned short* __restrict__ wROP)
{
    const int g = blockIdx.x * 256 + threadIdx.x;
    if (g < 2048) {                                   // W1 (folded): M=64,K=32
        int idx = g;
        int t = idx >> 9, rem = idx & 511;
        int ln = rem >> 3, j = rem & 7;
        int row = t*16 + (ln & 15);
        int k = (ln >> 4)*8 + j;
        float s = 0.0f;
        if (k < 14) {
            const int moff[14] = {0,1,2,3,5,6,7,10,13,14,15,19,25,29};
            const int mcnt[14] = {1,1,1,2,1,1,3,3,1,1,4,6,4,1};
            const int mlist[30] = {0,1,2,3,4,5,6,7,8,10,9,11,12,13,14,
                                   15,16,18,22,17,19,20,23,24,26,21,25,27,28,29};
            for (int q = 0; q < mcnt[k]; ++q) s += bw1[mlist[moff[k]+q]*64 + row];
        }
        wW1P[idx] = f2bf(s);
    } else if (g < 6144) {                            // W2: M=64,K=64
        int idx = g - 2048;
        int t = idx >> 9, rem = idx & 511;
        int mt = t >> 1, ks = t & 1;
        int ln = rem >> 3, j = rem & 7;
        int row = mt*16 + (ln & 15);
        int k = ks*32 + (ln >> 4)*8 + j;
        wW2P[idx] = f2bf(bw2[k*64 + row]);
    } else if (g < 14336) {                           // CK[l]: M=64,K=64
        int idx = g - 6144;
        int l = idx >> 12, r2 = idx & 4095;
        int t = r2 >> 9, rem = r2 & 511;
        int mt = t >> 1, ks = t & 1;
        int ln = rem >> 3, j = rem & 7;
        int row = mt*16 + (ln & 15);
        int k = ks*32 + (ln >> 4)*8 + j;
        wCKP[idx] = f2bf(ckw[l*4096 + k*64 + row]);
    } else if (g < 47104) {                           // L1[l]: M=256,K=64
        int idx = g - 14336;
        int l = idx >> 14, r2 = idx & 16383;
        int t = r2 >> 9, rem = r2 & 511;
        int mt = t >> 1, ks = t & 1;
        int ln = rem >> 3, j = rem & 7;
        int row = mt*16 + (ln & 15);
        int k = ks*32 + (ln >> 4)*8 + j;
        wL1P[idx] = f2bf(l1w[l*16384 + k*256 + row]);
    } else if (g < 79872) {                           // L2[l]: M=64,K=256
        int idx = g - 47104;
        int l = idx >> 14, r2 = idx & 16383;
        int t = r2 >> 9, rem = r2 & 511;
        int mt2 = t >> 3, ksg = t & 7;
        int ln = rem >> 3, j = rem & 7;
        int row = mt2*16 + (ln & 15);
        int k = ksg*32 + (ln >> 4)*8 + j;
        wL2P[idx] = f2bf(l2w[l*16384 + k*64 + row]);
    } else if (g < 81920) {                           // RO[l]: M=16,K=64
        int idx = g - 79872;
        int l = idx >> 10, r2 = idx & 1023;
        int ks = r2 >> 9, rem = r2 & 511;
        int ln = rem >> 3, j = rem & 7;
        int row = ln & 15;
        int k = ks*32 + (ln >> 4)*8 + j;
        wROP[idx] = f2bf(row_w[l*1024 + k*16 + row]);
    } else if (g < 81920 + O_) {                      // orientations
        int o = g - 81920;
        float vx, vy, vz;
        fib_vec(o, vx, vy, vz);
        orig[o*3+0] = vx; orig[o*3+1] = vy; orig[o*3+2] = vz;
    }
}

// ---------------------------------------------------------------------------
// Fiber-basis precompute: one wave per orientation pair.
// ---------------------------------------------------------------------------
__global__ __launch_bounds__(256) void k_fibpre(
    const float* __restrict__ fw1, const float* __restrict__ fb1,
    const float* __restrict__ fw2, const float* __restrict__ fb2,
    const float* __restrict__ cfw, float* __restrict__ fkg)
{
    __shared__ float sRow[4][64];
    const int wv = threadIdx.x >> 6, lane = threadIdx.x & 63;
    const int pr = blockIdx.x * 4 + wv;
    if (pr >= 100) return;
    const int i = pr / O_, j = pr % O_;
    float ix, iy, iz, jx, jy, jz;
    fib_vec(i, ix, iy, iz);
    fib_vec(j, jx, jy, jz);
    float a = ix*jx + iy*jy + iz*jz;
    float a2 = a*a, a3 = a2*a, a4 = a3*a;
    float v = fb1[lane];
    v = fmaf(a,  fw1[0*64+lane], v);
    v = fmaf(a2, fw1[1*64+lane], v);
    v = fmaf(a3, fw1[2*64+lane], v);
    v = fmaf(a4, fw1[3*64+lane], v);
    sRow[wv][lane] = gelu_f(v);
    float acc = fb2[lane];
    for (int b = 0; b < 64; ++b) acc = fmaf(sRow[wv][b], fw2[b*64+lane], acc);
    sRow[wv][lane] = gelu_f(acc);
    for (int l = 0; l < 2; ++l) {
        float s = 0.0f;
        for (int b = 0; b < 64; ++b) s = fmaf(sRow[wv][b], cfw[l*4096 + b*64 + lane], s);
        fkg[l*6400 + pr*64 + lane] = s;
    }
}

// ---------------------------------------------------------------------------
__global__ __launch_bounds__(256) void k_embed(
    const float* __restrict__ x, const float* __restrict__ ew,
    float* __restrict__ hg, unsigned short* __restrict__ hbf0)
{
    int t = blockIdx.x * 256 + threadIdx.x;
    if (t >= N_ * 64) return;
    int n = t >> 6, c = t & 63;
    float v = 0.0f;
#pragma unroll
    for (int k = 0; k < 16; ++k) v = fmaf(x[n*16+k], ew[k*64+c], v);
    int base = n * 640 + c;
#pragma unroll
    for (int o = 0; o < O_; ++o) hg[base + o*64] = v;
    hbf0[t] = f2bf(v);
}

// ---------------------------------------------------------------------------
__global__ __launch_bounds__(256) void k_hist(const int* __restrict__ ei, int* __restrict__ counts)
{
    int e = blockIdx.x * 256 + threadIdx.x;
    if (e < E_) atomicAdd(&counts[ei[E_ + e]], 1);
}

__global__ __launch_bounds__(1024) void k_scan(
    const int* __restrict__ counts, int* __restrict__ offs, int* __restrict__ cursor)
{
    __shared__ int part[1024];
    int t = threadIdx.x;
    const int CH = 10;
    int base_i = t * CH;
    int s = 0;
#pragma unroll
    for (int i = 0; i < CH; ++i) { int idx = base_i + i; if (idx < N_) s += counts[idx]; }
    part[t] = s;
    __syncthreads();
    for (int off = 1; off < 1024; off <<= 1) {
        int v = (t >= off) ? part[t - off] : 0;
        __syncthreads();
        part[t] += v;
        __syncthreads();
    }
    int run = (t > 0) ? part[t - 1] : 0;
#pragma unroll
    for (int i = 0; i < CH; ++i) {
        int idx = base_i + i;
        if (idx < N_) { offs[idx] = run; cursor[idx] = run; run += counts[idx]; }
    }
    if (t == 1023) offs[N_] = run;
}

__global__ __launch_bounds__(256) void k_scatter(
    const int* __restrict__ ei, const float* __restrict__ pos,
    int* __restrict__ cursor, int* __restrict__ csend, int* __restrict__ crecv,
    float* __restrict__ crel)
{
    int e = blockIdx.x * 256 + threadIdx.x;
    if (e >= E_) return;
    int s = ei[e], r = ei[E_ + e];
    int slot = atomicAdd(&cursor[r], 1);
    csend[slot] = s;
    crecv[slot] = r;
    crel[slot*3+0] = pos[s*3+0] - pos[r*3+0];
    crel[slot*3+1] = pos[s*3+1] - pos[r*3+1];
    crel[slot*3+2] = pos[s*3+2] - pos[r*3+2];
}

// ---------------------------------------------------------------------------
// MFMA stage helpers (single-wave block: rows 0..63 of sData).
// ---------------------------------------------------------------------------
template<int KS>
__device__ __forceinline__ void loadB(
    const unsigned short* sData, int lane, bf16x8 Bf[4][KS])
{
    const int lm = lane & 15, lk = lane >> 4;
#pragma unroll
    for (int nt = 0; nt < 4; ++nt)
#pragma unroll
        for (int ks = 0; ks < KS; ++ks) {
            int r = nt*16 + lm;
            int kb = ks*64 + lk*16;
            Bf[nt][ks] = *(const bf16x8*)((const char*)sData + r*128 + (kb ^ ((r&7)<<4)));
        }
}

template<int KS, bool BIAS, bool GELU>
__device__ __forceinline__ void stageC(
    unsigned short* sData, const bf16x8 Bf[4][KS],
    const unsigned short* __restrict__ Wp, const float* __restrict__ bias, int lane)
{
    const int lm = lane & 15, lk = lane >> 4;
#pragma unroll
    for (int mt = 0; mt < 4; ++mt) {
        bf16x8 Af[KS];
#pragma unroll
        for (int ks = 0; ks < KS; ++ks)
            Af[ks] = *(const bf16x8*)(Wp + ((mt*KS + ks)*64 + lane)*8);
        f32x4 b4 = {0,0,0,0};
        if (BIAS) b4 = *(const f32x4*)(bias + mt*16 + (lk<<2));
#pragma unroll
        for (int nt = 0; nt < 4; ++nt) {
            f32x4 acc = b4;
#pragma unroll
            for (int ks = 0; ks < KS; ++ks) acc = MFMA16(Af[ks], Bf[nt][ks], acc);
            float v0 = acc[0], v1 = acc[1], v2 = acc[2], v3 = acc[3];
            if (GELU) { v0 = gelu_f(v0); v1 = gelu_f(v1); v2 = gelu_f(v2); v3 = gelu_f(v3); }
            bf16x4 pk = pack4(v0, v1, v2, v3);
            int rr = nt*16 + lm;
            int cb = mt*32 + (lk<<3);
            *(bf16x4*)((char*)sData + rr*128 + (cb ^ ((rr&7)<<4))) = pk;
        }
    }
}

// phase 0: per-item monomial features -> sData row tid
__device__ __forceinline__ void phase0(
    unsigned short* sData, int slot, int oo, const float* __restrict__ crel,
    const float* __restrict__ ori, int tid)
{
    float r0 = crel[slot*3+0], r1 = crel[slot*3+1], r2 = crel[slot*3+2];
    float o0 = ori[oo*3+0], o1 = ori[oo*3+1], o2 = ori[oo*3+2];
    float a = r0*o0 + r1*o1 + r2*o2;
    float p0 = fmaf(-a, o0, r0), p1 = fmaf(-a, o1, r1), p2 = fmaf(-a, o2, r2);
    float b = sqrtf(p0*p0 + p1*p1 + p2*p2);
    float a2 = a*a, b2 = b*b, ab = a*b;
    float m[14];
    m[0]=a; m[1]=b; m[2]=a2; m[3]=ab; m[4]=b2;
    m[5]=a2*a; m[6]=a2*b; m[7]=a*b2; m[8]=b2*b;
    m[9]=a2*a2; m[10]=a2*ab; m[11]=a2*b2; m[12]=ab*b2; m[13]=b2*b2;
    unsigned int pk[16];
#pragma unroll
    for (int j = 0; j < 7; ++j) pk[j] = cvtpk(m[2*j], m[2*j+1]);
#pragma unroll
    for (int j = 7; j < 16; ++j) pk[j] = 0;
#pragma unroll
    for (int q = 0; q < 4; ++q) {
        int cb = q*16;
        *(f32x4*)((char*)sData + tid*128 + (cb ^ ((tid&7)<<4))) = ((const f32x4*)pk)[q];
    }
}

// scatter tail: lane=channel; kc from LDS (or global for lite kernel)
#define SCATTER_BODY(KC_EXPR)                                                        \
    int prevr = __shfl_up(rcv, 1);                                                   \
    unsigned long long bmask = __ballot(lane > 0 && rcv != prevr);                   \
    float a0=0,a1c=0,a2c=0,a3c=0,a4c=0,a5c=0,a6c=0,a7c=0,a8c=0,a9c=0;                \
    int cur = __builtin_amdgcn_readfirstlane(rcv);                                   \
    int soi = item0 % 10;                                                            \
    _Pragma("unroll")                                                                \
    for (int ch = 0; ch < 4; ++ch) {                                                 \
        unsigned short hvu[16]; float kcv[16];                                       \
        _Pragma("unroll")                                                            \
        for (int j = 0; j < 16; ++j) {                                               \
            const int i = ch*16 + j;                                                 \
            hvu[j] = hb[__builtin_amdgcn_readlane(myaddr, i)];                       \
            kcv[j] = (KC_EXPR);                                                      \
        }                                                                            \
        _Pragma("unroll")                                                            \
        for (int j = 0; j < 16; ++j) {                                               \
            const int i = ch*16 + j;                                                 \
            if (bmask & (1ull << i)) { FLUSH_RUN(cur); cur = __builtin_amdgcn_readlane(rcv, i); } \
            float mv = kcv[j] * bf2f(hvu[j]);                                        \
            if      (soi == 0) a0  += mv;                                            \
            else if (soi == 1) a1c += mv;                                            \
            else if (soi == 2) a2c += mv;                                            \
            else if (soi == 3) a3c += mv;                                            \
            else if (soi == 4) a4c += mv;                                            \
            else if (soi == 5) a5c += mv;                                            \
            else if (soi == 6) a6c += mv;                                            \
            else if (soi == 7) a7c += mv;                                            \
            else if (soi == 8) a8c += mv;                                            \
            else               a9c += mv;                                            \
            soi = (soi == 9) ? 0 : soi + 1;                                          \
        }                                                                            \
    }                                                                                \
    FLUSH_RUN(cur);

#define FLUSH_RUN(R) { float* bp = h1g + (R)*640 + lane; \
    atomicAdd(bp+0,a0); atomicAdd(bp+64,a1c); atomicAdd(bp+128,a2c); atomicAdd(bp+192,a3c); \
    atomicAdd(bp+256,a4c); atomicAdd(bp+320,a5c); atomicAdd(bp+384,a6c); atomicAdd(bp+448,a7c); \
    atomicAdd(bp+512,a8c); atomicAdd(bp+576,a9c); \
    a0=a1c=a2c=a3c=a4c=a5c=a6c=a7c=a8c=a9c=0.0f; }

// ---------------------------------------------------------------------------
// Fallback full k_msg (1 wave/block, 8 KB LDS).  L0: gather hbf0[n][c].
// ---------------------------------------------------------------------------
template<bool L0>
__global__ __launch_bounds__(64) void k_msg(
    const unsigned short* __restrict__ hbf, float* __restrict__ h1g,
    const int* __restrict__ csend, const int* __restrict__ crecv,
    const float* __restrict__ crel, const float* __restrict__ ori,
    const unsigned short* __restrict__ wW1P, const unsigned short* __restrict__ wW2P,
    const unsigned short* __restrict__ wCKP_l,
    const float* __restrict__ bb1, const float* __restrict__ bb2)
{
    __shared__ unsigned short sData[64*64];
    const int lane = threadIdx.x;
    const int item0 = blockIdx.x * 64;
    const int item = item0 + lane;
    const int slot = item / 10;
    const int oo = item - slot * 10;
    const int snd = csend[slot];
    const int rcv = crecv[slot];
    phase0(sData, slot, oo, crel, ori, lane);
    {
        bf16x8 Bf1[4][1]; loadB<1>(sData, lane, Bf1);
        stageC<1, true, true>(sData, Bf1, wW1P, bb1, lane);
    }
    {
        bf16x8 Bf2[4][2]; loadB<2>(sData, lane, Bf2);
        stageC<2, true, true>(sData, Bf2, wW2P, bb2, lane);
    }
    {
        bf16x8 Bf3[4][2]; loadB<2>(sData, lane, Bf3);
        stageC<2, false, false>(sData, Bf3, wCKP_l, (const float*)0, lane);
    }
    const int myaddr = L0 ? (snd * 64) : ((snd * 10 + oo) * 64);
    const unsigned short* hb = hbf + lane;
    SCATTER_BODY(bf2f(*(const unsigned short*)((const char*)sData + i*128 + ((lane*2) ^ ((i&7)<<4)))))
}

// ---------------------------------------------------------------------------
// Layer-0 dual k_msg: shared stages 1-2, stage3 for BOTH layers; kc1 -> global
// (de-swizzled, coalesced 1KB stores), kc0 -> scatter with hbf0.
// ---------------------------------------------------------------------------
__global__ __launch_bounds__(64) void k_msg0dual(
    const unsigned short* __restrict__ hbf, float* __restrict__ h1g,
    unsigned short* __restrict__ kc1g,
    const int* __restrict__ csend, const int* __restrict__ crecv,
    const float* __restrict__ crel, const float* __restrict__ ori,
    const unsigned short* __restrict__ wW1P, const unsigned short* __restrict__ wW2P,
    const unsigned short* __restrict__ wCK0, const unsigned short* __restrict__ wCK1,
    const float* __restrict__ bb1, const float* __restrict__ bb2)
{
    __shared__ unsigned short sData[64*64];
    const int lane = threadIdx.x;
    const int item0 = blockIdx.x * 64;
    const int item = item0 + lane;
    const int slot = item / 10;
    const int oo = item - slot * 10;
    const int snd = csend[slot];
    const int rcv = crecv[slot];
    phase0(sData, slot, oo, crel, ori, lane);
    {
        bf16x8 Bf1[4][1]; loadB<1>(sData, lane, Bf1);
        stageC<1, true, true>(sData, Bf1, wW1P, bb1, lane);
    }
    {
        bf16x8 Bf2[4][2]; loadB<2>(sData, lane, Bf2);
        stageC<2, true, true>(sData, Bf2, wW2P, bb2, lane);
    }
    bf16x8 Bf3[4][2]; loadB<2>(sData, lane, Bf3);
    // stage3 layer 1 -> kc1g: de-swizzling copy, lane l copies bytes
    // [q*1024 + l*16, +16) of the wave's 8KB tile -> 1KB contiguous stores.
    stageC<2, false, false>(sData, Bf3, wCK1, (const float*)0, lane);
    {
        char* dst = (char*)kc1g + (size_t)item0 * 128;
#pragma unroll
        for (int q = 0; q < 8; ++q) {
            int g = q*1024 + lane*16;
            int row = g >> 7;
            int off = g & 127;
            f32x4 v = *(const f32x4*)((const char*)sData + row*128 + (off ^ ((row&7)<<4)));
            *(f32x4*)(dst + g) = v;
        }
    }
    // stage3 layer 0 -> scatter
    stageC<2, false, false>(sData, Bf3, wCK0, (const float*)0, lane);
    const int myaddr = snd * 64;
    const unsigned short* hb = hbf + lane;
    SCATTER_BODY(bf2f(*(const unsigned short*)((const char*)sData + i*128 + ((lane*2) ^ ((i&7)<<4)))))
}

// ---------------------------------------------------------------------------
// Layer-1 lite k_msg: precomputed kc1 (plain row-major) + gather + scatter.
// ---------------------------------------------------------------------------
__global__ __launch_bounds__(64) void k_msg1lite(
    const unsigned short* __restrict__ kc1g, const unsigned short* __restrict__ hbf,
    float* __restrict__ h1g,
    const int* __restrict__ csend, const int* __restrict__ crecv)
{
    const int lane = threadIdx.x;
    const int item0 = blockIdx.x * 64;
    const int item = item0 + lane;
    const int slot = item / 10;
    const int oo = item - slot * 10;
    const int snd = csend[slot];
    const int rcv = crecv[slot];
    const int myaddr = (snd * 10 + oo) * 64;
    const unsigned short* hb = hbf + lane;
    const char* kb = (const char*)kc1g + (size_t)item0 * 128;
    SCATTER_BODY(bf2f(*(const unsigned short*)(kb + (size_t)i*128 + lane*2)))
}
#undef FLUSH_RUN
#undef SCATTER_BODY

// ---------------------------------------------------------------------------
// Fused fiber conv + LayerNorm -> y bf16; optionally zero h1 after read.
// ---------------------------------------------------------------------------
__global__ __launch_bounds__(256) void k_fln(
    float* __restrict__ h1, const float* __restrict__ fkg,
    const float* __restrict__ cb, const float* __restrict__ ns,
    const float* __restrict__ nb, unsigned short* __restrict__ y, int zero_h1)
{
    __shared__ float sFK[6400];
    const int tid = threadIdx.x;
    for (int i = tid; i < 6400; i += 256) sFK[i] = fkg[i];
    __syncthreads();
    const int lane = tid & 63, wv = tid >> 6;
    float cbv = cb[lane], nsv = ns[lane], nbv = nb[lane];
    for (int g4 = blockIdx.x; g4 < N_/4; g4 += gridDim.x) {
        const int n = g4 * 4 + wv;
        float hr[10];
#pragma unroll
        for (int o = 0; o < O_; ++o) hr[o] = h1[n*640 + o*64 + lane];
        if (zero_h1) {
#pragma unroll
            for (int o = 0; o < O_; ++o) h1[n*640 + o*64 + lane] = 0.0f;
        }
#pragma unroll
        for (int p = 0; p < O_; ++p) {
            float v = 0.0f;
#pragma unroll
            for (int o = 0; o < O_; ++o) v = fmaf(hr[o], sFK[(p*O_+o)*64 + lane], v);
            v = v * 0.1f + cbv;
            float s = v, q = v*v;
#pragma unroll
            for (int d = 1; d < 64; d <<= 1) { s += __shfl_xor(s, d); q += __shfl_xor(q, d); }
            float mu = s * (1.0f/64.0f);
            float var = q * (1.0f/64.0f) - mu*mu;
            float rs = rsqrtf(var + 1e-6f);
            float yv = (v - mu) * rs * nsv + nbv;
            y[(n*O_ + p)*64 + lane] = f2bf(yv);
        }
    }
}

// ---------------------------------------------------------------------------
// MLP: 128 rows/block (nt=2 -> 2x A-frag reuse), frag-packed weights, readout
// stored.  Writes hn back into ybuf (bf16) in-place -> next layer's gather.
// ---------------------------------------------------------------------------
__global__ __launch_bounds__(256, 3) void k_mlp(
    unsigned short* ybuf, float* __restrict__ hg, float* __restrict__ rout,
    const unsigned short* __restrict__ wL1P_l, const float* __restrict__ l1b_l,
    const unsigned short* __restrict__ wL2P_l, const float* __restrict__ l2b_l,
    const unsigned short* __restrict__ wROP_l, const float* __restrict__ rob_l)
{
    __shared__ unsigned short sA[128*64];
    const int tid = threadIdx.x;
    const int lane = tid & 63, wv = tid >> 6;
    const int rb = blockIdx.x * 128;
#pragma unroll
    for (int i = tid*16; i < 128*128; i += 256*16) {
        int r = i >> 7, off = i & 127;
        int grow = rb + r; if (grow >= NROW_) grow = NROW_ - 1;
        *(f32x4*)((char*)sA + r*128 + (off ^ ((r&7)<<4))) =
            *(const f32x4*)((const char*)ybuf + (size_t)grow*128 + off);
    }
    __syncthreads();
    const int lm = lane & 15, lk = lane >> 4;
    // wave owns rows [wv*32, wv*32+32): nt=0,1 tiles of 16
    bf16x8 Yf[2][2];
#pragma unroll
    for (int nt = 0; nt < 2; ++nt)
#pragma unroll
        for (int ks = 0; ks < 2; ++ks) {
            int r = wv*32 + nt*16 + lm;
            int kb = ks*64 + lk*16;
            Yf[nt][ks] = *(const bf16x8*)((const char*)sA + r*128 + (kb ^ ((r&7)<<4)));
        }
    f32x4 acc2[4][2];
#pragma unroll
    for (int m = 0; m < 4; ++m) {
        f32x4 b2 = *(const f32x4*)(l2b_l + m*16 + (lk<<2));
#pragma unroll
        for (int nt = 0; nt < 2; ++nt) acc2[m][nt] = b2;
    }
#pragma unroll
    for (int jb = 0; jb < 4; ++jb) {
#pragma unroll
        for (int mt = 0; mt < 4; ++mt) {
            bf16x8 A1[2];
#pragma unroll
            for (int ks = 0; ks < 2; ++ks)
                A1[ks] = *(const bf16x8*)(wL1P_l + (((jb*4 + mt)*2 + ks)*64 + lane)*8);
            f32x4 b4 = *(const f32x4*)(l1b_l + jb*64 + mt*16 + (lk<<2));
#pragma unroll
            for (int nt = 0; nt < 2; ++nt) {
                f32x4 acc = b4;
                acc = MFMA16(A1[0], Yf[nt][0], acc);
                acc = MFMA16(A1[1], Yf[nt][1], acc);
                bf16x4 pk = pack4(gelu_f(acc[0]), gelu_f(acc[1]), gelu_f(acc[2]), gelu_f(acc[3]));
                int rr = wv*32 + nt*16 + lm;
                int cb = mt*32 + (lk<<3);
                *(bf16x4*)((char*)sA + rr*128 + (cb ^ ((rr&7)<<4))) = pk;
            }
        }
        bf16x8 Mf[2][2];
#pragma unroll
        for (int nt = 0; nt < 2; ++nt)
#pragma unroll
            for (int ks = 0; ks < 2; ++ks) {
                int r = wv*32 + nt*16 + lm;
                int kb = ks*64 + lk*16;
                Mf[nt][ks] = *(const bf16x8*)((const char*)sA + r*128 + (kb ^ ((r&7)<<4)));
            }
#pragma unroll
        for (int mt2 = 0; mt2 < 4; ++mt2) {
            bf16x8 A2[2];
#pragma unroll
            for (int ks = 0; ks < 2; ++ks)
                A2[ks] = *(const bf16x8*)(wL2P_l + ((mt2*8 + jb*2 + ks)*64 + lane)*8);
#pragma unroll
            for (int nt = 0; nt < 2; ++nt) {
                acc2[mt2][nt] = MFMA16(A2[0], Mf[nt][0], acc2[mt2][nt]);
                acc2[mt2][nt] = MFMA16(A2[1], Mf[nt][1], acc2[mt2][nt]);
            }
        }
    }
    // epilogue: residual into h (fp32) + hn bf16 to LDS and to ybuf
#pragma unroll
    for (int nt = 0; nt < 2; ++nt) {
        const int rloc = wv*32 + nt*16 + lm;
        const int grow = rb + rloc;
        const bool valid = grow < NROW_;
        const int growc = valid ? grow : (NROW_ - 1);
#pragma unroll
        for (int mt2 = 0; mt2 < 4; ++mt2) {
            f32x4 hv = *(const f32x4*)(hg + (size_t)growc*64 + mt2*16 + (lk<<2));
            f32x4 hn;
#pragma unroll
            for (int r = 0; r < 4; ++r) hn[r] = hv[r] + acc2[mt2][nt][r];
            bf16x4 pk = pack4(hn[0], hn[1], hn[2], hn[3]);
            if (valid) {
                *(f32x4*)(hg + (size_t)grow*64 + mt2*16 + (lk<<2)) = hn;
                *(bf16x4*)((char*)ybuf + (size_t)grow*128 + (mt2*16 + (lk<<2))*2) = pk;
            }
            int cb = mt2*32 + (lk<<3);
            *(bf16x4*)((char*)sA + rloc*128 + (cb ^ ((rloc&7)<<4))) = pk;
        }
    }
    // readout: ro^T hn -> store
    bf16x8 Ro[2];
#pragma unroll
    for (int ks = 0; ks < 2; ++ks)
        Ro[ks] = *(const bf16x8*)(wROP_l + (ks*64 + lane)*8);
    f32x4 rb4 = *(const f32x4*)(rob_l + (lk<<2));
#pragma unroll
    for (int nt = 0; nt < 2; ++nt) {
        const int rloc = wv*32 + nt*16 + lm;
        const int grow = rb + rloc;
        bf16x8 Hf[2];
#pragma unroll
        for (int ks = 0; ks < 2; ++ks) {
            int kb = ks*64 + lk*16;
            Hf[ks] = *(const bf16x8*)((const char*)sA + rloc*128 + (kb ^ ((rloc&7)<<4)));
        }
        f32x4 r4 = rb4;
        r4 = MFMA16(Ro[0], Hf[0], r4);
        r4 = MFMA16(Ro[1], Hf[1], r4);
        if (grow < NROW_) *(f32x4*)(rout + (size_t)grow*16 + (lk<<2)) = r4;
    }
}

// ---------------------------------------------------------------------------
__global__ __launch_bounds__(256) void k_pool(
    const float* __restrict__ r0, const float* __restrict__ r1,
    const int* __restrict__ batch, float* __restrict__ out)
{
    int t = blockIdx.x * 256 + threadIdx.x;
    if (t >= N_ * 16) return;
    int n = t >> 4, j = t & 15;
    float s = 0.0f;
#pragma unroll
    for (int p = 0; p < O_; ++p)
        s += r0[(n*O_ + p)*16 + j] + r1[(n*O_ + p)*16 + j];
    atomicAdd(&out[batch[n]*16 + j], s * (1.0f/20.0f));
}

// ---------------------------------------------------------------------------
extern "C" void kernel_launch(void* const* d_in, const int* in_sizes, int n_in,
                              void* d_out, int out_size, void* d_ws, size_t ws_size,
                              hipStream_t stream)
{
    const float* x    = (const float*)d_in[0];
    const float* pos  = (const float*)d_in[1];
    const float* bw1  = (const float*)d_in[2];
    const float* bb1  = (const float*)d_in[3];
    const float* bw2  = (const float*)d_in[4];
    const float* bb2  = (const float*)d_in[5];
    const float* fw1  = (const float*)d_in[6];
    const float* fb1  = (const float*)d_in[7];
    const float* fw2  = (const float*)d_in[8];
    const float* fb2  = (const float*)d_in[9];
    const float* embw = (const float*)d_in[10];
    const float* ckw  = (const float*)d_in[11];
    const float* cfw  = (const float*)d_in[12];
    const float* cb   = (const float*)d_in[13];
    const float* ns   = (const float*)d_in[14];
    const float* nbp  = (const float*)d_in[15];
    const float* l1w  = (const float*)d_in[16];
    const float* l1b  = (const float*)d_in[17];
    const float* l2w  = (const float*)d_in[18];
    const float* l2b  = (const float*)d_in[19];
    const float* row  = (const float*)d_in[20];
    const float* rob  = (const float*)d_in[21];
    const int*   ei   = (const int*)d_in[22];
    const int*   batch= (const int*)d_in[23];
    float* out = (float*)d_out;

    char* w = (char*)d_ws;
    size_t off = 0;
    auto alloc = [&](size_t bytes) -> char* {
        char* p = w + off; off += (bytes + 255) / 256 * 256; return p;
    };
    float* ori    = (float*)alloc(32 * 4);
    float* fkg    = (float*)alloc(2 * 6400 * 4);
    unsigned short* wW1P = (unsigned short*)alloc(4*512*2);
    unsigned short* wW2P = (unsigned short*)alloc(8*512*2);
    unsigned short* wCKP = (unsigned short*)alloc(2*8*512*2);
    unsigned short* wL1P = (unsigned short*)alloc(2*32*512*2);
    unsigned short* wL2P = (unsigned short*)alloc(2*32*512*2);
    unsigned short* wROP = (unsigned short*)alloc(2*2*512*2);
    float* h      = (float*)alloc((size_t)N_ * 640 * 4);
    float* h1     = (float*)alloc((size_t)N_ * 640 * 4);
    unsigned short* y = (unsigned short*)alloc((size_t)NROW_ * 64 * 2);
    unsigned short* hbf0 = (unsigned short*)alloc((size_t)N_ * 64 * 2);
    float* rout0  = (float*)alloc((size_t)NROW_ * 16 * 4);
    float* rout1  = (float*)alloc((size_t)NROW_ * 16 * 4);
    float* crel   = (float*)alloc((size_t)E_ * 3 * 4);
    int*   counts = (int*)alloc((N_ + 1) * 4);
    int*   offs   = (int*)alloc((N_ + 1) * 4);
    int*   cursor = (int*)alloc((N_ + 1) * 4);
    int*   csend  = (int*)alloc((size_t)E_ * 4);
    int*   crecv  = (int*)alloc((size_t)E_ * 4);
    // optional kc1 buffer (102.4 MB) -- split path only if workspace allows
    unsigned short* kc1g = nullptr;
    if (ws_size >= off + (size_t)NITEM_ * 64 * 2 + 256)
        kc1g = (unsigned short*)alloc((size_t)NITEM_ * 64 * 2);

    hipMemsetAsync(h1, 0, (size_t)N_ * 640 * 4, stream);
    hipMemsetAsync(out, 0, (size_t)out_size * 4, stream);
    hipMemsetAsync(counts, 0, (N_ + 1) * 4, stream);

    k_pack<<<321, 256, 0, stream>>>(bw1, bw2, ckw, l1w, l2w, row, ori,
                                    wW1P, wW2P, wCKP, wL1P, wL2P, wROP);
    k_fibpre<<<25, 256, 0, stream>>>(fw1, fb1, fw2, fb2, cfw, fkg);
    k_embed<<<(N_ * 64 + 255) / 256, 256, 0, stream>>>(x, embw, h, hbf0);
    k_hist<<<(E_ + 255) / 256, 256, 0, stream>>>(ei, counts);
    k_scan<<<1, 1024, 0, stream>>>(counts, offs, cursor);
    k_scatter<<<(E_ + 255) / 256, 256, 0, stream>>>(ei, pos, cursor, csend, crecv, crel);

    for (int l = 0; l < 2; ++l) {
        if (l == 0) {
            if (kc1g)
                k_msg0dual<<<NITEM_ / 64, 64, 0, stream>>>(hbf0, h1, kc1g, csend, crecv,
                                                           crel, ori, wW1P, wW2P,
                                                           wCKP, wCKP + 4096, bb1, bb2);
            else
                k_msg<true><<<NITEM_ / 64, 64, 0, stream>>>(hbf0, h1, csend, crecv, crel, ori,
                                                            wW1P, wW2P, wCKP, bb1, bb2);
        } else {
            if (kc1g)
                k_msg1lite<<<NITEM_ / 64, 64, 0, stream>>>(kc1g, y, h1, csend, crecv);
            else
                k_msg<false><<<NITEM_ / 64, 64, 0, stream>>>(y, h1, csend, crecv, crel, ori,
                                                             wW1P, wW2P, wCKP + 4096, bb1, bb2);
        }
        k_fln<<<625, 256, 0, stream>>>(h1, fkg + l*6400, cb + l*64, ns + l*64, nbp + l*64, y,
                                       (l == 0) ? 1 : 0);
        k_mlp<<<(NROW_ + 127) / 128, 256, 0, stream>>>(y, h, (l == 0 ? rout0 : rout1),
                                                       wL1P + l*16384, l1b + l*256,
                                                       wL2P + l*16384, l2b + l*64,
                                                       wROP + l*1024, rob + l*16);
    }
    k_pool<<<(N_ * 16 + 255) / 256, 256, 0, stream>>>(rout0, rout1, batch, out);
}

// Round 11
// 397.031 us; speedup vs baseline: 25.0274x; 1.0230x over previous
//
#include <hip/hip_runtime.h>
#include <math.h>

#define N_   10000
#define E_   80000
#define O_   10
#define B_   16
#define OUT_ 16
#define NROW_ (N_*O_)    // 100000
#define NITEM_ (E_*O_)   // 800000

typedef __attribute__((ext_vector_type(8))) short bf16x8;
typedef __attribute__((ext_vector_type(4))) short bf16x4;
typedef __attribute__((ext_vector_type(4))) float f32x4;

#define MFMA16(a,b,c) __builtin_amdgcn_mfma_f32_16x16x32_bf16(a,b,c,0,0,0)

__device__ __forceinline__ float gelu_f(float x) {
    float u = fmaf(0.044715f, x * x, 1.0f);
    float e = __builtin_amdgcn_exp2f(2.3022083f * x * u);
    float r = __builtin_amdgcn_rcpf(e + 1.0f);
    return fmaf(-x, r, x);
}

__device__ __forceinline__ unsigned short f2bf(float f) {
    union { float f; unsigned int u; } v; v.f = f;
    unsigned int r = v.u + 0x7FFFu + ((v.u >> 16) & 1u);
    return (unsigned short)(r >> 16);
}
__device__ __forceinline__ float bf2f(unsigned short u) {
    union { unsigned int u; float f; } v; v.u = ((unsigned int)u) << 16;
    return v.f;
}
__device__ __forceinline__ unsigned int cvtpk(float lo, float hi) {
    unsigned int r;
    asm("v_cvt_pk_bf16_f32 %0, %1, %2" : "=v"(r) : "v"(lo), "v"(hi));
    return r;
}
__device__ __forceinline__ bf16x4 pack4(float a, float b, float c, float d) {
    union { unsigned int u[2]; bf16x4 v; } z;
    z.u[0] = cvtpk(a, b);
    z.u[1] = cvtpk(c, d);
    return z.v;
}

__device__ __forceinline__ void fib_vec(int idx, float& vx, float& vy, float& vz) {
    float i = (float)idx + 0.5f;
    float phi = acosf(1.0f - 2.0f * i / (float)O_);
    float theta = 3.14159265358979323846f * (1.0f + 2.2360679774997896964f) * i;
    float sp = sinf(phi);
    vx = cosf(theta) * sp; vy = sinf(theta) * sp; vz = cosf(phi);
}

// ---------------------------------------------------------------------------
// Parallel weight frag-pack (one thread per element) + orientations.
// ---------------------------------------------------------------------------
__global__ __launch_bounds__(256) void k_pack(
    const float* __restrict__ bw1, const float* __restrict__ bw2,
    const float* __restrict__ ckw, const float* __restrict__ l1w,
    const float* __restrict__ l2w, const float* __restrict__ row_w,
    float* __restrict__ orig,
    unsigned short* __restrict__ wW1P, unsigned short* __restrict__ wW2P,
    unsigned short* __restrict__ wCKP, unsigned short* __restrict__ wL1P,
    unsigned short* __restrict__ wL2P, unsigned short* __restrict__ wROP)
{
    const int g = blockIdx.x * 256 + threadIdx.x;
    if (g < 2048) {                                   // W1 (folded): M=64,K=32
        int idx = g;
        int t = idx >> 9, rem = idx & 511;
        int ln = rem >> 3, j = rem & 7;
        int row = t*16 + (ln & 15);
        int k = (ln >> 4)*8 + j;
        float s = 0.0f;
        if (k < 14) {
            const int moff[14] = {0,1,2,3,5,6,7,10,13,14,15,19,25,29};
            const int mcnt[14] = {1,1,1,2,1,1,3,3,1,1,4,6,4,1};
            const int mlist[30] = {0,1,2,3,4,5,6,7,8,10,9,11,12,13,14,
                                   15,16,18,22,17,19,20,23,24,26,21,25,27,28,29};
            for (int q = 0; q < mcnt[k]; ++q) s += bw1[mlist[moff[k]+q]*64 + row];
        }
        wW1P[idx] = f2bf(s);
    } else if (g < 6144) {                            // W2: M=64,K=64
        int idx = g - 2048;
        int t = idx >> 9, rem = idx & 511;
        int mt = t >> 1, ks = t & 1;
        int ln = rem >> 3, j = rem & 7;
        int row = mt*16 + (ln & 15);
        int k = ks*32 + (ln >> 4)*8 + j;
        wW2P[idx] = f2bf(bw2[k*64 + row]);
    } else if (g < 14336) {                           // CK[l]: M=64,K=64
        int idx = g - 6144;
        int l = idx >> 12, r2 = idx & 4095;
        int t = r2 >> 9, rem = r2 & 511;
        int mt = t >> 1, ks = t & 1;
        int ln = rem >> 3, j = rem & 7;
        int row = mt*16 + (ln & 15);
        int k = ks*32 + (ln >> 4)*8 + j;
        wCKP[idx] = f2bf(ckw[l*4096 + k*64 + row]);
    } else if (g < 47104) {                           // L1[l]: M=256,K=64
        int idx = g - 14336;
        int l = idx >> 14, r2 = idx & 16383;
        int t = r2 >> 9, rem = r2 & 511;
        int mt = t >> 1, ks = t & 1;
        int ln = rem >> 3, j = rem & 7;
        int row = mt*16 + (ln & 15);
        int k = ks*32 + (ln >> 4)*8 + j;
        wL1P[idx] = f2bf(l1w[l*16384 + k*256 + row]);
    } else if (g < 79872) {                           // L2[l]: M=64,K=256
        int idx = g - 47104;
        int l = idx >> 14, r2 = idx & 16383;
        int t = r2 >> 9, rem = r2 & 511;
        int mt2 = t >> 3, ksg = t & 7;
        int ln = rem >> 3, j = rem & 7;
        int row = mt2*16 + (ln & 15);
        int k = ksg*32 + (ln >> 4)*8 + j;
        wL2P[idx] = f2bf(l2w[l*16384 + k*64 + row]);
    } else if (g < 81920) {                           // RO[l]: M=16,K=64
        int idx = g - 79872;
        int l = idx >> 10, r2 = idx & 1023;
        int ks = r2 >> 9, rem = r2 & 511;
        int ln = rem >> 3, j = rem & 7;
        int row = ln & 15;
        int k = ks*32 + (ln >> 4)*8 + j;
        wROP[idx] = f2bf(row_w[l*1024 + k*16 + row]);
    } else if (g < 81920 + O_) {                      // orientations
        int o = g - 81920;
        float vx, vy, vz;
        fib_vec(o, vx, vy, vz);
        orig[o*3+0] = vx; orig[o*3+1] = vy; orig[o*3+2] = vz;
    }
}

// ---------------------------------------------------------------------------
// Fiber-basis precompute: one wave per orientation pair.
// ---------------------------------------------------------------------------
__global__ __launch_bounds__(256) void k_fibpre(
    const float* __restrict__ fw1, const float* __restrict__ fb1,
    const float* __restrict__ fw2, const float* __restrict__ fb2,
    const float* __restrict__ cfw, float* __restrict__ fkg)
{
    __shared__ float sRow[4][64];
    const int wv = threadIdx.x >> 6, lane = threadIdx.x & 63;
    const int pr = blockIdx.x * 4 + wv;
    if (pr >= 100) return;
    const int i = pr / O_, j = pr % O_;
    float ix, iy, iz, jx, jy, jz;
    fib_vec(i, ix, iy, iz);
    fib_vec(j, jx, jy, jz);
    float a = ix*jx + iy*jy + iz*jz;
    float a2 = a*a, a3 = a2*a, a4 = a3*a;
    float v = fb1[lane];
    v = fmaf(a,  fw1[0*64+lane], v);
    v = fmaf(a2, fw1[1*64+lane], v);
    v = fmaf(a3, fw1[2*64+lane], v);
    v = fmaf(a4, fw1[3*64+lane], v);
    sRow[wv][lane] = gelu_f(v);
    float acc = fb2[lane];
    for (int b = 0; b < 64; ++b) acc = fmaf(sRow[wv][b], fw2[b*64+lane], acc);
    sRow[wv][lane] = gelu_f(acc);
    for (int l = 0; l < 2; ++l) {
        float s = 0.0f;
        for (int b = 0; b < 64; ++b) s = fmaf(sRow[wv][b], cfw[l*4096 + b*64 + lane], s);
        fkg[l*6400 + pr*64 + lane] = s;
    }
}

// ---------------------------------------------------------------------------
__global__ __launch_bounds__(256) void k_embed(
    const float* __restrict__ x, const float* __restrict__ ew,
    float* __restrict__ hg, unsigned short* __restrict__ hbf0)
{
    int t = blockIdx.x * 256 + threadIdx.x;
    if (t >= N_ * 64) return;
    int n = t >> 6, c = t & 63;
    float v = 0.0f;
#pragma unroll
    for (int k = 0; k < 16; ++k) v = fmaf(x[n*16+k], ew[k*64+c], v);
    int base = n * 640 + c;
#pragma unroll
    for (int o = 0; o < O_; ++o) hg[base + o*64] = v;
    hbf0[t] = f2bf(v);
}

// ---------------------------------------------------------------------------
__global__ __launch_bounds__(256) void k_hist(const int* __restrict__ ei, int* __restrict__ counts)
{
    int e = blockIdx.x * 256 + threadIdx.x;
    if (e < E_) atomicAdd(&counts[ei[E_ + e]], 1);
}

__global__ __launch_bounds__(1024) void k_scan(
    const int* __restrict__ counts, int* __restrict__ offs, int* __restrict__ cursor)
{
    __shared__ int part[1024];
    int t = threadIdx.x;
    const int CH = 10;
    int base_i = t * CH;
    int s = 0;
#pragma unroll
    for (int i = 0; i < CH; ++i) { int idx = base_i + i; if (idx < N_) s += counts[idx]; }
    part[t] = s;
    __syncthreads();
    for (int off = 1; off < 1024; off <<= 1) {
        int v = (t >= off) ? part[t - off] : 0;
        __syncthreads();
        part[t] += v;
        __syncthreads();
    }
    int run = (t > 0) ? part[t - 1] : 0;
#pragma unroll
    for (int i = 0; i < CH; ++i) {
        int idx = base_i + i;
        if (idx < N_) { offs[idx] = run; cursor[idx] = run; run += counts[idx]; }
    }
    if (t == 1023) offs[N_] = run;
}

__global__ __launch_bounds__(256) void k_scatter(
    const int* __restrict__ ei, const float* __restrict__ pos,
    int* __restrict__ cursor, int* __restrict__ csend, int* __restrict__ crecv,
    float* __restrict__ crel)
{
    int e = blockIdx.x * 256 + threadIdx.x;
    if (e >= E_) return;
    int s = ei[e], r = ei[E_ + e];
    int slot = atomicAdd(&cursor[r], 1);
    csend[slot] = s;
    crecv[slot] = r;
    crel[slot*3+0] = pos[s*3+0] - pos[r*3+0];
    crel[slot*3+1] = pos[s*3+1] - pos[r*3+1];
    crel[slot*3+2] = pos[s*3+2] - pos[r*3+2];
}

// ---------------------------------------------------------------------------
// MFMA stage helpers (single-wave block: rows 0..63 of sData).
// ---------------------------------------------------------------------------
template<int KS>
__device__ __forceinline__ void loadB(
    const unsigned short* sData, int lane, bf16x8 Bf[4][KS])
{
    const int lm = lane & 15, lk = lane >> 4;
#pragma unroll
    for (int nt = 0; nt < 4; ++nt)
#pragma unroll
        for (int ks = 0; ks < KS; ++ks) {
            int r = nt*16 + lm;
            int kb = ks*64 + lk*16;
            Bf[nt][ks] = *(const bf16x8*)((const char*)sData + r*128 + (kb ^ ((r&7)<<4)));
        }
}

template<int KS, bool BIAS, bool GELU>
__device__ __forceinline__ void stageC(
    unsigned short* sData, const bf16x8 Bf[4][KS],
    const unsigned short* __restrict__ Wp, const float* __restrict__ bias, int lane)
{
    const int lm = lane & 15, lk = lane >> 4;
#pragma unroll
    for (int mt = 0; mt < 4; ++mt) {
        bf16x8 Af[KS];
#pragma unroll
        for (int ks = 0; ks < KS; ++ks)
            Af[ks] = *(const bf16x8*)(Wp + ((mt*KS + ks)*64 + lane)*8);
        f32x4 b4 = {0,0,0,0};
        if (BIAS) b4 = *(const f32x4*)(bias + mt*16 + (lk<<2));
#pragma unroll
        for (int nt = 0; nt < 4; ++nt) {
            f32x4 acc = b4;
#pragma unroll
            for (int ks = 0; ks < KS; ++ks) acc = MFMA16(Af[ks], Bf[nt][ks], acc);
            float v0 = acc[0], v1 = acc[1], v2 = acc[2], v3 = acc[3];
            if (GELU) { v0 = gelu_f(v0); v1 = gelu_f(v1); v2 = gelu_f(v2); v3 = gelu_f(v3); }
            bf16x4 pk = pack4(v0, v1, v2, v3);
            int rr = nt*16 + lm;
            int cb = mt*32 + (lk<<3);
            *(bf16x4*)((char*)sData + rr*128 + (cb ^ ((rr&7)<<4))) = pk;
        }
    }
}

// phase 0: per-item monomial features -> sData row tid
__device__ __forceinline__ void phase0(
    unsigned short* sData, int slot, int oo, const float* __restrict__ crel,
    const float* __restrict__ ori, int tid)
{
    float r0 = crel[slot*3+0], r1 = crel[slot*3+1], r2 = crel[slot*3+2];
    float o0 = ori[oo*3+0], o1 = ori[oo*3+1], o2 = ori[oo*3+2];
    float a = r0*o0 + r1*o1 + r2*o2;
    float p0 = fmaf(-a, o0, r0), p1 = fmaf(-a, o1, r1), p2 = fmaf(-a, o2, r2);
    float b = sqrtf(p0*p0 + p1*p1 + p2*p2);
    float a2 = a*a, b2 = b*b, ab = a*b;
    float m[14];
    m[0]=a; m[1]=b; m[2]=a2; m[3]=ab; m[4]=b2;
    m[5]=a2*a; m[6]=a2*b; m[7]=a*b2; m[8]=b2*b;
    m[9]=a2*a2; m[10]=a2*ab; m[11]=a2*b2; m[12]=ab*b2; m[13]=b2*b2;
    unsigned int pk[16];
#pragma unroll
    for (int j = 0; j < 7; ++j) pk[j] = cvtpk(m[2*j], m[2*j+1]);
#pragma unroll
    for (int j = 7; j < 16; ++j) pk[j] = 0;
#pragma unroll
    for (int q = 0; q < 4; ++q) {
        int cb = q*16;
        *(f32x4*)((char*)sData + tid*128 + (cb ^ ((tid&7)<<4))) = ((const f32x4*)pk)[q];
    }
}

// scatter tail: lane=channel.  KC_EXPR(base_k, i) reads kc for item i; bases
// vb[8] are the 8 distinct per-lane swizzled offsets, so reads use immediate
// row offsets (removes per-item XOR address math).
#define SCATTER_BODY(KC_EXPR)                                                        \
    int prevr = __shfl_up(rcv, 1);                                                   \
    unsigned long long bmask = __ballot(lane > 0 && rcv != prevr);                   \
    float a0=0,a1c=0,a2c=0,a3c=0,a4c=0,a5c=0,a6c=0,a7c=0,a8c=0,a9c=0;                \
    int cur = __builtin_amdgcn_readfirstlane(rcv);                                   \
    int soi = item0 % 10;                                                            \
    _Pragma("unroll")                                                                \
    for (int ch = 0; ch < 4; ++ch) {                                                 \
        unsigned short hvu[16]; float kcv[16];                                       \
        _Pragma("unroll")                                                            \
        for (int j = 0; j < 16; ++j) {                                               \
            const int i = ch*16 + j;                                                 \
            hvu[j] = hb[__builtin_amdgcn_readlane(myaddr, i)];                       \
            kcv[j] = (KC_EXPR);                                                      \
        }                                                                            \
        _Pragma("unroll")                                                            \
        for (int j = 0; j < 16; ++j) {                                               \
            const int i = ch*16 + j;                                                 \
            if (bmask & (1ull << i)) { FLUSH_RUN(cur); cur = __builtin_amdgcn_readlane(rcv, i); } \
            float mv = kcv[j] * bf2f(hvu[j]);                                        \
            if      (soi == 0) a0  += mv;                                            \
            else if (soi == 1) a1c += mv;                                            \
            else if (soi == 2) a2c += mv;                                            \
            else if (soi == 3) a3c += mv;                                            \
            else if (soi == 4) a4c += mv;                                            \
            else if (soi == 5) a5c += mv;                                            \
            else if (soi == 6) a6c += mv;                                            \
            else if (soi == 7) a7c += mv;                                            \
            else if (soi == 8) a8c += mv;                                            \
            else               a9c += mv;                                            \
            soi = (soi == 9) ? 0 : soi + 1;                                          \
        }                                                                            \
    }                                                                                \
    FLUSH_RUN(cur);

#define FLUSH_RUN(R) { float* bp = h1g + (R)*640 + lane; \
    atomicAdd(bp+0,a0); atomicAdd(bp+64,a1c); atomicAdd(bp+128,a2c); atomicAdd(bp+192,a3c); \
    atomicAdd(bp+256,a4c); atomicAdd(bp+320,a5c); atomicAdd(bp+384,a6c); atomicAdd(bp+448,a7c); \
    atomicAdd(bp+512,a8c); atomicAdd(bp+576,a9c); \
    a0=a1c=a2c=a3c=a4c=a5c=a6c=a7c=a8c=a9c=0.0f; }

// ---------------------------------------------------------------------------
// Fallback full k_msg (1 wave/block, 8 KB LDS).  L0: gather hbf0[n][c].
// ---------------------------------------------------------------------------
template<bool L0>
__global__ __launch_bounds__(64) void k_msg(
    const unsigned short* __restrict__ hbf, float* __restrict__ h1g,
    const int* __restrict__ csend, const int* __restrict__ crecv,
    const float* __restrict__ crel, const float* __restrict__ ori,
    const unsigned short* __restrict__ wW1P, const unsigned short* __restrict__ wW2P,
    const unsigned short* __restrict__ wCKP_l,
    const float* __restrict__ bb1, const float* __restrict__ bb2)
{
    __shared__ unsigned short sData[64*64];
    const int lane = threadIdx.x;
    const int item0 = blockIdx.x * 64;
    const int item = item0 + lane;
    const int slot = item / 10;
    const int oo = item - slot * 10;
    const int snd = csend[slot];
    const int rcv = crecv[slot];
    phase0(sData, slot, oo, crel, ori, lane);
    {
        bf16x8 Bf1[4][1]; loadB<1>(sData, lane, Bf1);
        stageC<1, true, true>(sData, Bf1, wW1P, bb1, lane);
    }
    {
        bf16x8 Bf2[4][2]; loadB<2>(sData, lane, Bf2);
        stageC<2, true, true>(sData, Bf2, wW2P, bb2, lane);
    }
    {
        bf16x8 Bf3[4][2]; loadB<2>(sData, lane, Bf3);
        stageC<2, false, false>(sData, Bf3, wCKP_l, (const float*)0, lane);
    }
    const int myaddr = L0 ? (snd * 64) : ((snd * 10 + oo) * 64);
    const unsigned short* hb = hbf + lane;
    const char* vb[8];
#pragma unroll
    for (int k = 0; k < 8; ++k) vb[k] = (const char*)sData + ((lane*2) ^ (k<<4));
    SCATTER_BODY(bf2f(*(const unsigned short*)(vb[j&7] + i*128)))
}

// ---------------------------------------------------------------------------
// Layer-0 dual k_msg: shared stages 1-2, stage3 for BOTH layers; kc1 -> global
// (de-swizzled, coalesced 1KB stores), kc0 -> scatter with hbf0.
// ---------------------------------------------------------------------------
__global__ __launch_bounds__(64) void k_msg0dual(
    const unsigned short* __restrict__ hbf, float* __restrict__ h1g,
    unsigned short* __restrict__ kc1g,
    const int* __restrict__ csend, const int* __restrict__ crecv,
    const float* __restrict__ crel, const float* __restrict__ ori,
    const unsigned short* __restrict__ wW1P, const unsigned short* __restrict__ wW2P,
    const unsigned short* __restrict__ wCK0, const unsigned short* __restrict__ wCK1,
    const float* __restrict__ bb1, const float* __restrict__ bb2)
{
    __shared__ unsigned short sData[64*64];
    const int lane = threadIdx.x;
    const int item0 = blockIdx.x * 64;
    const int item = item0 + lane;
    const int slot = item / 10;
    const int oo = item - slot * 10;
    const int snd = csend[slot];
    const int rcv = crecv[slot];
    phase0(sData, slot, oo, crel, ori, lane);
    {
        bf16x8 Bf1[4][1]; loadB<1>(sData, lane, Bf1);
        stageC<1, true, true>(sData, Bf1, wW1P, bb1, lane);
    }
    {
        bf16x8 Bf2[4][2]; loadB<2>(sData, lane, Bf2);
        stageC<2, true, true>(sData, Bf2, wW2P, bb2, lane);
    }
    bf16x8 Bf3[4][2]; loadB<2>(sData, lane, Bf3);
    // stage3 layer 1 -> kc1g: de-swizzling copy, lane l copies bytes
    // [q*1024 + l*16, +16) of the wave's 8KB tile -> 1KB contiguous stores.
    stageC<2, false, false>(sData, Bf3, wCK1, (const float*)0, lane);
    {
        char* dst = (char*)kc1g + (size_t)item0 * 128;
#pragma unroll
        for (int q = 0; q < 8; ++q) {
            int g = q*1024 + lane*16;
            int row = g >> 7;
            int off = g & 127;
            f32x4 v = *(const f32x4*)((const char*)sData + row*128 + (off ^ ((row&7)<<4)));
            *(f32x4*)(dst + g) = v;
        }
    }
    // stage3 layer 0 -> scatter
    stageC<2, false, false>(sData, Bf3, wCK0, (const float*)0, lane);
    const int myaddr = snd * 64;
    const unsigned short* hb = hbf + lane;
    const char* vb[8];
#pragma unroll
    for (int k = 0; k < 8; ++k) vb[k] = (const char*)sData + ((lane*2) ^ (k<<4));
    SCATTER_BODY(bf2f(*(const unsigned short*)(vb[j&7] + i*128)))
}

// ---------------------------------------------------------------------------
// Layer-1 lite k_msg: precomputed kc1 (plain row-major) + gather + scatter.
// ---------------------------------------------------------------------------
__global__ __launch_bounds__(64) void k_msg1lite(
    const unsigned short* __restrict__ kc1g, const unsigned short* __restrict__ hbf,
    float* __restrict__ h1g,
    const int* __restrict__ csend, const int* __restrict__ crecv)
{
    const int lane = threadIdx.x;
    const int item0 = blockIdx.x * 64;
    const int item = item0 + lane;
    const int slot = item / 10;
    const int oo = item - slot * 10;
    const int snd = csend[slot];
    const int rcv = crecv[slot];
    const int myaddr = (snd * 10 + oo) * 64;
    const unsigned short* hb = hbf + lane;
    const char* kb = (const char*)kc1g + (size_t)item0 * 128 + lane*2;
    SCATTER_BODY(bf2f(*(const unsigned short*)(kb + (size_t)i*128)))
}
#undef FLUSH_RUN
#undef SCATTER_BODY

// ---------------------------------------------------------------------------
// Fused fiber conv + LayerNorm -> y bf16; optionally zero h1 after read.
// Exact grid: one 4-node tile per block.
// ---------------------------------------------------------------------------
__global__ __launch_bounds__(256) void k_fln(
    float* __restrict__ h1, const float* __restrict__ fkg,
    const float* __restrict__ cb, const float* __restrict__ ns,
    const float* __restrict__ nb, unsigned short* __restrict__ y, int zero_h1)
{
    __shared__ float sFK[6400];
    const int tid = threadIdx.x;
    for (int i = tid; i < 6400; i += 256) sFK[i] = fkg[i];
    __syncthreads();
    const int lane = tid & 63, wv = tid >> 6;
    float cbv = cb[lane], nsv = ns[lane], nbv = nb[lane];
    const int n = blockIdx.x * 4 + wv;
    float hr[10];
#pragma unroll
    for (int o = 0; o < O_; ++o) hr[o] = h1[n*640 + o*64 + lane];
    if (zero_h1) {
#pragma unroll
        for (int o = 0; o < O_; ++o) h1[n*640 + o*64 + lane] = 0.0f;
    }
#pragma unroll
    for (int p = 0; p < O_; ++p) {
        float v = 0.0f;
#pragma unroll
        for (int o = 0; o < O_; ++o) v = fmaf(hr[o], sFK[(p*O_+o)*64 + lane], v);
        v = v * 0.1f + cbv;
        float s = v, q = v*v;
#pragma unroll
        for (int d = 1; d < 64; d <<= 1) { s += __shfl_xor(s, d); q += __shfl_xor(q, d); }
        float mu = s * (1.0f/64.0f);
        float var = q * (1.0f/64.0f) - mu*mu;
        float rs = rsqrtf(var + 1e-6f);
        float yv = (v - mu) * rs * nsv + nbv;
        y[(n*O_ + p)*64 + lane] = f2bf(yv);
    }
}

// ---------------------------------------------------------------------------
// MLP: 128 rows/block (nt=2), frag-packed weights, readout stored.  LAST=0:
// write hn back to hg (fp32) and ybuf (bf16, next layer's gather); LAST=1:
// both dead -> skipped.
// ---------------------------------------------------------------------------
template<int LAST>
__global__ __launch_bounds__(256, 4) void k_mlp(
    unsigned short* ybuf, float* __restrict__ hg, float* __restrict__ rout,
    const unsigned short* __restrict__ wL1P_l, const float* __restrict__ l1b_l,
    const unsigned short* __restrict__ wL2P_l, const float* __restrict__ l2b_l,
    const unsigned short* __restrict__ wROP_l, const float* __restrict__ rob_l)
{
    __shared__ unsigned short sA[128*64];
    const int tid = threadIdx.x;
    const int lane = tid & 63, wv = tid >> 6;
    const int rb = blockIdx.x * 128;
#pragma unroll
    for (int i = tid*16; i < 128*128; i += 256*16) {
        int r = i >> 7, off = i & 127;
        int grow = rb + r; if (grow >= NROW_) grow = NROW_ - 1;
        *(f32x4*)((char*)sA + r*128 + (off ^ ((r&7)<<4))) =
            *(const f32x4*)((const char*)ybuf + (size_t)grow*128 + off);
    }
    __syncthreads();
    const int lm = lane & 15, lk = lane >> 4;
    bf16x8 Yf[2][2];
#pragma unroll
    for (int nt = 0; nt < 2; ++nt)
#pragma unroll
        for (int ks = 0; ks < 2; ++ks) {
            int r = wv*32 + nt*16 + lm;
            int kb = ks*64 + lk*16;
            Yf[nt][ks] = *(const bf16x8*)((const char*)sA + r*128 + (kb ^ ((r&7)<<4)));
        }
    f32x4 acc2[4][2];
#pragma unroll
    for (int m = 0; m < 4; ++m) {
        f32x4 b2 = *(const f32x4*)(l2b_l + m*16 + (lk<<2));
#pragma unroll
        for (int nt = 0; nt < 2; ++nt) acc2[m][nt] = b2;
    }
#pragma unroll
    for (int jb = 0; jb < 4; ++jb) {
#pragma unroll
        for (int mt = 0; mt < 4; ++mt) {
            bf16x8 A1[2];
#pragma unroll
            for (int ks = 0; ks < 2; ++ks)
                A1[ks] = *(const bf16x8*)(wL1P_l + (((jb*4 + mt)*2 + ks)*64 + lane)*8);
            f32x4 b4 = *(const f32x4*)(l1b_l + jb*64 + mt*16 + (lk<<2));
#pragma unroll
            for (int nt = 0; nt < 2; ++nt) {
                f32x4 acc = b4;
                acc = MFMA16(A1[0], Yf[nt][0], acc);
                acc = MFMA16(A1[1], Yf[nt][1], acc);
                bf16x4 pk = pack4(gelu_f(acc[0]), gelu_f(acc[1]), gelu_f(acc[2]), gelu_f(acc[3]));
                int rr = wv*32 + nt*16 + lm;
                int cb = mt*32 + (lk<<3);
                *(bf16x4*)((char*)sA + rr*128 + (cb ^ ((rr&7)<<4))) = pk;
            }
        }
        bf16x8 Mf[2][2];
#pragma unroll
        for (int nt = 0; nt < 2; ++nt)
#pragma unroll
            for (int ks = 0; ks < 2; ++ks) {
                int r = wv*32 + nt*16 + lm;
                int kb = ks*64 + lk*16;
                Mf[nt][ks] = *(const bf16x8*)((const char*)sA + r*128 + (kb ^ ((r&7)<<4)));
            }
#pragma unroll
        for (int mt2 = 0; mt2 < 4; ++mt2) {
            bf16x8 A2[2];
#pragma unroll
            for (int ks = 0; ks < 2; ++ks)
                A2[ks] = *(const bf16x8*)(wL2P_l + ((mt2*8 + jb*2 + ks)*64 + lane)*8);
#pragma unroll
            for (int nt = 0; nt < 2; ++nt) {
                acc2[mt2][nt] = MFMA16(A2[0], Mf[nt][0], acc2[mt2][nt]);
                acc2[mt2][nt] = MFMA16(A2[1], Mf[nt][1], acc2[mt2][nt]);
            }
        }
    }
    // epilogue: residual + hn stash
#pragma unroll
    for (int nt = 0; nt < 2; ++nt) {
        const int rloc = wv*32 + nt*16 + lm;
        const int grow = rb + rloc;
        const bool valid = grow < NROW_;
        const int growc = valid ? grow : (NROW_ - 1);
#pragma unroll
        for (int mt2 = 0; mt2 < 4; ++mt2) {
            f32x4 hv = *(const f32x4*)(hg + (size_t)growc*64 + mt2*16 + (lk<<2));
            f32x4 hn;
#pragma unroll
            for (int r = 0; r < 4; ++r) hn[r] = hv[r] + acc2[mt2][nt][r];
            bf16x4 pk = pack4(hn[0], hn[1], hn[2], hn[3]);
            if (!LAST && valid) {
                *(f32x4*)(hg + (size_t)grow*64 + mt2*16 + (lk<<2)) = hn;
                *(bf16x4*)((char*)ybuf + (size_t)grow*128 + (mt2*16 + (lk<<2))*2) = pk;
            }
            int cb = mt2*32 + (lk<<3);
            *(bf16x4*)((char*)sA + rloc*128 + (cb ^ ((rloc&7)<<4))) = pk;
        }
    }
    // readout: ro^T hn -> store
    bf16x8 Ro[2];
#pragma unroll
    for (int ks = 0; ks < 2; ++ks)
        Ro[ks] = *(const bf16x8*)(wROP_l + (ks*64 + lane)*8);
    f32x4 rb4 = *(const f32x4*)(rob_l + (lk<<2));
#pragma unroll
    for (int nt = 0; nt < 2; ++nt) {
        const int rloc = wv*32 + nt*16 + lm;
        const int grow = rb + rloc;
        bf16x8 Hf[2];
#pragma unroll
        for (int ks = 0; ks < 2; ++ks) {
            int kb = ks*64 + lk*16;
            Hf[ks] = *(const bf16x8*)((const char*)sA + rloc*128 + (kb ^ ((rloc&7)<<4)));
        }
        f32x4 r4 = rb4;
        r4 = MFMA16(Ro[0], Hf[0], r4);
        r4 = MFMA16(Ro[1], Hf[1], r4);
        if (grow < NROW_) *(f32x4*)(rout + (size_t)grow*16 + (lk<<2)) = r4;
    }
}

// ---------------------------------------------------------------------------
__global__ __launch_bounds__(256) void k_pool(
    const float* __restrict__ r0, const float* __restrict__ r1,
    const int* __restrict__ batch, float* __restrict__ out)
{
    int t = blockIdx.x * 256 + threadIdx.x;
    if (t >= N_ * 16) return;
    int n = t >> 4, j = t & 15;
    float s = 0.0f;
#pragma unroll
    for (int p = 0; p < O_; ++p)
        s += r0[(n*O_ + p)*16 + j] + r1[(n*O_ + p)*16 + j];
    atomicAdd(&out[batch[n]*16 + j], s * (1.0f/20.0f));
}

// ---------------------------------------------------------------------------
extern "C" void kernel_launch(void* const* d_in, const int* in_sizes, int n_in,
                              void* d_out, int out_size, void* d_ws, size_t ws_size,
                              hipStream_t stream)
{
    const float* x    = (const float*)d_in[0];
    const float* pos  = (const float*)d_in[1];
    const float* bw1  = (const float*)d_in[2];
    const float* bb1  = (const float*)d_in[3];
    const float* bw2  = (const float*)d_in[4];
    const float* bb2  = (const float*)d_in[5];
    const float* fw1  = (const float*)d_in[6];
    const float* fb1  = (const float*)d_in[7];
    const float* fw2  = (const float*)d_in[8];
    const float* fb2  = (const float*)d_in[9];
    const float* embw = (const float*)d_in[10];
    const float* ckw  = (const float*)d_in[11];
    const float* cfw  = (const float*)d_in[12];
    const float* cb   = (const float*)d_in[13];
    const float* ns   = (const float*)d_in[14];
    const float* nbp  = (const float*)d_in[15];
    const float* l1w  = (const float*)d_in[16];
    const float* l1b  = (const float*)d_in[17];
    const float* l2w  = (const float*)d_in[18];
    const float* l2b  = (const float*)d_in[19];
    const float* row  = (const float*)d_in[20];
    const float* rob  = (const float*)d_in[21];
    const int*   ei   = (const int*)d_in[22];
    const int*   batch= (const int*)d_in[23];
    float* out = (float*)d_out;

    char* w = (char*)d_ws;
    size_t off = 0;
    auto alloc = [&](size_t bytes) -> char* {
        char* p = w + off; off += (bytes + 255) / 256 * 256; return p;
    };
    float* ori    = (float*)alloc(32 * 4);
    float* fkg    = (float*)alloc(2 * 6400 * 4);
    unsigned short* wW1P = (unsigned short*)alloc(4*512*2);
    unsigned short* wW2P = (unsigned short*)alloc(8*512*2);
    unsigned short* wCKP = (unsigned short*)alloc(2*8*512*2);
    unsigned short* wL1P = (unsigned short*)alloc(2*32*512*2);
    unsigned short* wL2P = (unsigned short*)alloc(2*32*512*2);
    unsigned short* wROP = (unsigned short*)alloc(2*2*512*2);
    float* h      = (float*)alloc((size_t)N_ * 640 * 4);
    float* h1     = (float*)alloc((size_t)N_ * 640 * 4);
    unsigned short* y = (unsigned short*)alloc((size_t)NROW_ * 64 * 2);
    unsigned short* hbf0 = (unsigned short*)alloc((size_t)N_ * 64 * 2);
    float* rout0  = (float*)alloc((size_t)NROW_ * 16 * 4);
    float* rout1  = (float*)alloc((size_t)NROW_ * 16 * 4);
    float* crel   = (float*)alloc((size_t)E_ * 3 * 4);
    int*   counts = (int*)alloc((N_ + 1) * 4);
    int*   offs   = (int*)alloc((N_ + 1) * 4);
    int*   cursor = (int*)alloc((N_ + 1) * 4);
    int*   csend  = (int*)alloc((size_t)E_ * 4);
    int*   crecv  = (int*)alloc((size_t)E_ * 4);
    // optional kc1 buffer (102.4 MB) -- split path only if workspace allows
    unsigned short* kc1g = nullptr;
    if (ws_size >= off + (size_t)NITEM_ * 64 * 2 + 256)
        kc1g = (unsigned short*)alloc((size_t)NITEM_ * 64 * 2);

    hipMemsetAsync(h1, 0, (size_t)N_ * 640 * 4, stream);
    hipMemsetAsync(out, 0, (size_t)out_size * 4, stream);
    hipMemsetAsync(counts, 0, (N_ + 1) * 4, stream);

    k_pack<<<321, 256, 0, stream>>>(bw1, bw2, ckw, l1w, l2w, row, ori,
                                    wW1P, wW2P, wCKP, wL1P, wL2P, wROP);
    k_fibpre<<<25, 256, 0, stream>>>(fw1, fb1, fw2, fb2, cfw, fkg);
    k_embed<<<(N_ * 64 + 255) / 256, 256, 0, stream>>>(x, embw, h, hbf0);
    k_hist<<<(E_ + 255) / 256, 256, 0, stream>>>(ei, counts);
    k_scan<<<1, 1024, 0, stream>>>(counts, offs, cursor);
    k_scatter<<<(E_ + 255) / 256, 256, 0, stream>>>(ei, pos, cursor, csend, crecv, crel);

    for (int l = 0; l < 2; ++l) {
        if (l == 0) {
            if (kc1g)
                k_msg0dual<<<NITEM_ / 64, 64, 0, stream>>>(hbf0, h1, kc1g, csend, crecv,
                                                           crel, ori, wW1P, wW2P,
                                                           wCKP, wCKP + 4096, bb1, bb2);
            else
                k_msg<true><<<NITEM_ / 64, 64, 0, stream>>>(hbf0, h1, csend, crecv, crel, ori,
                                                            wW1P, wW2P, wCKP, bb1, bb2);
        } else {
            if (kc1g)
                k_msg1lite<<<NITEM_ / 64, 64, 0, stream>>>(kc1g, y, h1, csend, crecv);
            else
                k_msg<false><<<NITEM_ / 64, 64, 0, stream>>>(y, h1, csend, crecv, crel, ori,
                                                             wW1P, wW2P, wCKP + 4096, bb1, bb2);
        }
        k_fln<<<N_ / 4, 256, 0, stream>>>(h1, fkg + l*6400, cb + l*64, ns + l*64, nbp + l*64, y,
                                          (l == 0) ? 1 : 0);
        if (l == 0)
            k_mlp<0><<<(NROW_ + 127) / 128, 256, 0, stream>>>(y, h, rout0,
                                                              wL1P, l1b, wL2P, l2b,
                                                              wROP, rob);
        else
            k_mlp<1><<<(NROW_ + 127) / 128, 256, 0, stream>>>(y, h, rout1,
                                                              wL1P + 16384, l1b + 256,
                                                              wL2P + 16384, l2b + 64,
                                                              wROP + 1024, rob + 16);
    }
    k_pool<<<(N_ * 16 + 255) / 256, 256, 0, stream>>>(rout0, rout1, batch, out);
}